// Round 5
// baseline (1061.676 us; speedup 1.0000x reference)
//
#include <hip/hip_runtime.h>
#include <hip/hip_bf16.h>
#include <math.h>

#define N_NODES 50000
#define N_EDGES 800000
#define E_TOT   (N_EDGES + N_NODES)
#define N_GRAPHS 256
#define SLOPE 0.2f
#define NB_SCAN ((N_NODES + 255) / 256)
#define NPANEL 782            // ceil(50000/64)
#define WCOLS 768             // padded concatenated-W width

typedef __attribute__((ext_vector_type(8))) short s16x8;
typedef __attribute__((ext_vector_type(4))) float f32x4;
typedef unsigned short u16;

__device__ __forceinline__ u16 f2bf(float v) {
  unsigned u = __float_as_uint(v);
  unsigned r = (u + 0x7fffu + ((u >> 16) & 1u)) >> 16;
  return (u16)r;
}
__device__ __forceinline__ float bf2f(u16 b) {
  return __uint_as_float(((unsigned)b) << 16);
}

__device__ __forceinline__ void gl_lds16(const void* g, void* l) {
  __builtin_amdgcn_global_load_lds(
      (const __attribute__((address_space(1))) unsigned int*)g,
      (__attribute__((address_space(3))) unsigned int*)l, 16, 0, 0);
}

// ---- x -> panel-swizzled split-bf16 [p][kc=40][m=64][ki=8], zero-padded ----
__global__ void conv_x(const float* __restrict__ x, u16* __restrict__ Ah,
                       u16* __restrict__ Al) {
  int id = blockIdx.x * blockDim.x + threadIdx.x;
  const int total = NPANEL * 64 * 40;
  if (id >= total) return;
  int kc = id % 40;
  int m  = (id / 40) % 64;
  int p  = id / 2560;
  int n = p * 64 + m;
  s16x8 hv, lv;
#pragma unroll
  for (int i = 0; i < 8; ++i) {
    int k = kc * 8 + i;
    float v = (n < N_NODES && k < 300) ? x[(size_t)n * 300 + k] : 0.f;
    u16 hb = f2bf(v);
    hv[i] = (short)hb;
    lv[i] = (short)f2bf(v - bf2f(hb));
  }
  size_t ce = (((size_t)p * 40 + kc) * 64 + m) * 8;
  *(s16x8*)&Ah[ce] = hv;
  *(s16x8*)&Al[ce] = lv;
}

// ---- Wl,Wr -> concatenated padded split-bf16 [kc][WCOLS][8] ----------------
__global__ void conv_w(const float* __restrict__ Wl, const float* __restrict__ Wr,
                       u16* __restrict__ Wh, u16* __restrict__ Wlo,
                       int K, int C, int NL, int kcn) {
  int id = blockIdx.x * blockDim.x + threadIdx.x;
  if (id >= kcn * WCOLS) return;
  int n = id % WCOLS, kc = id / WCOLS;
  s16x8 hv, lv;
#pragma unroll
  for (int i = 0; i < 8; ++i) {
    int k = kc * 8 + i;
    float v = 0.f;
    if (k < K) {
      if (n < NL) { if (n < C) v = Wl[(size_t)k * C + n]; }
      else if (n < 2 * NL && (n - NL) < C) v = Wr[(size_t)k * C + (n - NL)];
    }
    u16 hb = f2bf(v);
    hv[i] = (short)hb;
    lv[i] = (short)f2bf(v - bf2f(hb));
  }
  size_t ce = (size_t)id * 8;
  *(s16x8*)&Wh[ce] = hv;
  *(s16x8*)&Wlo[ce] = lv;
}

// ---- zero pad rows 50000..50047 of H panels (kcn=16) -----------------------
// NOTE: H aliases the A0 buffers -> must launch AFTER layer-0 gemm_dual.
__global__ void zero_pad_H(u16* __restrict__ Hh, u16* __restrict__ Hl) {
  int t = blockIdx.x * blockDim.x + threadIdx.x;
  if (t >= 48 * 16) return;
  int m = 16 + (t >> 4), kc = t & 15;
  size_t ce = (((size_t)781 * 16 + kc) * 64 + m) * 8;
  s16x8 z = {0, 0, 0, 0, 0, 0, 0, 0};
  *(s16x8*)&Hh[ce] = z;
  *(s16x8*)&Hl[ce] = z;
}

// ---- dual-output split-bf16 MFMA GEMM: [xl|xr] = A @ [Wl|Wr] + bias --------
__global__ __launch_bounds__(256, 2) void gemm_dual(
    const u16* __restrict__ Ah, const u16* __restrict__ Al,
    const u16* __restrict__ Wh, const u16* __restrict__ Wlo,
    const float* __restrict__ biasl, const float* __restrict__ biasr,
    float* __restrict__ xl, float* __restrict__ xr,
    int Kp, int C, int NL) {
  __shared__ u16 As[2][4][64][8];
  __shared__ u16 Ws[2][4][256][8];
  const int tid = threadIdx.x, wv = tid >> 6, lane = tid & 63;
  const int p = blockIdx.x, n0 = blockIdx.y * 256;
  const int kcn = Kp >> 3, nk = Kp >> 5;
  const size_t abase0 = (size_t)p * kcn * 512;
  const int rsel = lane >> 4, rrow = lane & 15;
  f32x4 z4 = {0.f, 0.f, 0.f, 0.f};
  f32x4 acc[4][4];
#pragma unroll
  for (int a = 0; a < 4; ++a)
#pragma unroll
    for (int b = 0; b < 4; ++b) acc[a][b] = z4;

  for (int s = 0; s < nk; ++s) {
    const size_t abase = abase0 + (size_t)s * 2048;
    for (int q = wv; q < 40; q += 4) {
      const u16* g;
      u16* l;
      if (q < 8) {
        int h = q >> 2, qq = q & 3;
        g = (h ? Al : Ah) + abase + qq * 512;
        l = &As[h][0][0][0] + qq * 512;
      } else {
        int t2 = q - 8, h = t2 >> 4, j = t2 & 15;
        g = (h ? Wlo : Wh) + ((size_t)(s * 4 + (j >> 2)) * WCOLS + n0 + (j & 3) * 64) * 8;
        l = &Ws[h][0][0][0] + j * 512;
      }
      gl_lds16(g + lane * 8, l);
    }
    __syncthreads();
    s16x8 af[4][2], bf[4][2];
#pragma unroll
    for (int mt = 0; mt < 4; ++mt) {
      af[mt][0] = *(const s16x8*)&As[0][rsel][mt * 16 + rrow][0];
      af[mt][1] = *(const s16x8*)&As[1][rsel][mt * 16 + rrow][0];
    }
#pragma unroll
    for (int nt = 0; nt < 4; ++nt) {
      bf[nt][0] = *(const s16x8*)&Ws[0][rsel][wv * 64 + nt * 16 + rrow][0];
      bf[nt][1] = *(const s16x8*)&Ws[1][rsel][wv * 64 + nt * 16 + rrow][0];
    }
#pragma unroll
    for (int mt = 0; mt < 4; ++mt)
#pragma unroll
      for (int nt = 0; nt < 4; ++nt) {
        acc[mt][nt] = __builtin_amdgcn_mfma_f32_16x16x32_bf16(af[mt][1], bf[nt][0], acc[mt][nt], 0, 0, 0);
        acc[mt][nt] = __builtin_amdgcn_mfma_f32_16x16x32_bf16(af[mt][0], bf[nt][1], acc[mt][nt], 0, 0, 0);
        acc[mt][nt] = __builtin_amdgcn_mfma_f32_16x16x32_bf16(af[mt][0], bf[nt][0], acc[mt][nt], 0, 0, 0);
      }
    __syncthreads();
  }
#pragma unroll
  for (int mt = 0; mt < 4; ++mt) {
    int r0 = p * 64 + mt * 16 + rsel * 4;
#pragma unroll
    for (int nt = 0; nt < 4; ++nt) {
      int gc = n0 + wv * 64 + nt * 16 + rrow;
#pragma unroll
      for (int j = 0; j < 4; ++j) {
        int row = r0 + j;
        if (row >= N_NODES) continue;
        float v = acc[mt][nt][j];
        if (gc < NL) {
          if (gc < C) xl[(size_t)row * C + gc] = v + biasl[gc];
        } else {
          int c2 = gc - NL;
          if (c2 >= 0 && c2 < C) xr[(size_t)row * C + c2] = v + biasr[c2];
        }
      }
    }
  }
}

// ---------------- CSR build (once per launch) ---------------------------
__global__ void zero_ints(int* __restrict__ p, int n) {
  int i = blockIdx.x * blockDim.x + threadIdx.x;
  if (i < n) p[i] = 0;
}

__global__ void deg_count(const int* __restrict__ ei, int* __restrict__ deg) {
  int e = blockIdx.x * blockDim.x + threadIdx.x;
  if (e >= E_TOT) return;
  int d = (e < N_EDGES) ? ei[N_EDGES + e] : e - N_EDGES;
  atomicAdd(&deg[d], 1);
}

__global__ void scan1(const int* __restrict__ deg, int* __restrict__ rp,
                      int* __restrict__ bsum) {
  __shared__ int s[256];
  int i = blockIdx.x * 256 + threadIdx.x;
  int v = (i < N_NODES) ? deg[i] : 0;
  s[threadIdx.x] = v;
  __syncthreads();
  for (int off = 1; off < 256; off <<= 1) {
    int t = (threadIdx.x >= off) ? s[threadIdx.x - off] : 0;
    __syncthreads();
    s[threadIdx.x] += t;
    __syncthreads();
  }
  if (i < N_NODES) rp[i] = s[threadIdx.x] - v;
  if (threadIdx.x == 255) bsum[blockIdx.x] = s[255];
}

__global__ void scan2(int* __restrict__ bsum) {
  __shared__ int s[256];
  int v = (threadIdx.x < NB_SCAN) ? bsum[threadIdx.x] : 0;
  s[threadIdx.x] = v;
  __syncthreads();
  for (int off = 1; off < 256; off <<= 1) {
    int t = (threadIdx.x >= off) ? s[threadIdx.x - off] : 0;
    __syncthreads();
    s[threadIdx.x] += t;
    __syncthreads();
  }
  if (threadIdx.x < NB_SCAN) bsum[threadIdx.x] = s[threadIdx.x] - v;
}

__global__ void scan3(int* __restrict__ rp, const int* __restrict__ bsum,
                      int* __restrict__ cursor) {
  int i = blockIdx.x * 256 + threadIdx.x;
  if (i < N_NODES) {
    int v = rp[i] + bsum[blockIdx.x];
    rp[i] = v;
    cursor[i] = v;
  }
  if (i == 0) rp[N_NODES] = E_TOT;
}

__global__ void fill_csr(const int* __restrict__ ei, int* __restrict__ cursor,
                         int* __restrict__ csr_src) {
  int e = blockIdx.x * blockDim.x + threadIdx.x;
  if (e >= E_TOT) return;
  int s, d;
  if (e < N_EDGES) { s = ei[e]; d = ei[N_EDGES + e]; }
  else             { s = d = e - N_EDGES; }
  int pos = atomicAdd(&cursor[d], 1);
  csr_src[pos] = s;
}

// -------- fused GATv2 aggregation v2: lane-group per edge ----------------
// G lanes per edge-group, NG=64/G edges in flight, NCH channels per lane.
template <int C, int CS, int G, int NCH, int OUTB>
__global__ __launch_bounds__(256) void gat_fused2(
    const int* __restrict__ rowptr, const int* __restrict__ csr_src,
    const float* __restrict__ xl, const float* __restrict__ xr,
    const float* __restrict__ att, const float* __restrict__ bias,
    float* __restrict__ hout, u16* __restrict__ Hh, u16* __restrict__ Hl) {
  constexpr int NG = 64 / G;
  int wid = (int)((blockIdx.x * (size_t)blockDim.x + threadIdx.x) >> 6);
  int lane = threadIdx.x & 63;
  if (wid >= N_NODES) return;
  const int g = lane / G;        // edge-group id
  const int i = lane % G;        // position within group
  const int c0 = i * NCH;        // first channel this lane covers
  int beg = rowptr[wid], end = rowptr[wid + 1];

  float xri[NCH], attc[NCH], acc[NCH];
#pragma unroll
  for (int k4 = 0; k4 < NCH / 4; ++k4) {
    f32x4 t = *(const f32x4*)(xr + (size_t)wid * CS + c0 + k4 * 4);
#pragma unroll
    for (int j = 0; j < 4; ++j) xri[k4 * 4 + j] = t[j];
  }
#pragma unroll
  for (int k = 0; k < NCH; ++k) {
    int c = c0 + k;
    attc[k] = (c < C) ? att[c] : 0.f;
    acc[k] = 0.f;
  }

  float m = -INFINITY, d = 0.f;
  int deg = end - beg;
  int nit = (deg + NG - 1) / NG;
  for (int it = 0; it < nit; ++it) {
    int e = beg + it * NG + g;
    bool valid = e < end;
    int s = csr_src[valid ? e : beg];
    float xlv[NCH];
    const f32x4* pl = (const f32x4*)(xl + (size_t)s * CS + c0);
    float v = 0.f;
#pragma unroll
    for (int k4 = 0; k4 < NCH / 4; ++k4) {
      f32x4 t = pl[k4];
#pragma unroll
      for (int j = 0; j < 4; ++j) {
        float xv = t[j];
        xlv[k4 * 4 + j] = xv;
        float mm = xv + xri[k4 * 4 + j];
        float lr = mm > 0.f ? mm : SLOPE * mm;
        v += lr * attc[k4 * 4 + j];
      }
    }
#pragma unroll
    for (int off = 1; off < G; off <<= 1) v += __shfl_xor(v, off, 64);
    if (!valid) v = -INFINITY;
    float nm = fmaxf(m, v);
    float sc, w;
    if (nm == -INFINITY) { sc = 1.f; w = 0.f; }
    else { sc = __expf(m - nm); w = __expf(v - nm); }
    d = d * sc + w;
#pragma unroll
    for (int k = 0; k < NCH; ++k) acc[k] = acc[k] * sc + w * xlv[k];
    m = nm;
  }

  // merge NG per-group softmax partials (once per node)
  float M = m;
#pragma unroll
  for (int off = G; off < 64; off <<= 1) M = fmaxf(M, __shfl_xor(M, off, 64));
  float f = (m == -INFINITY) ? 0.f : __expf(m - M);
  float dd = d * f;
#pragma unroll
  for (int off = G; off < 64; off <<= 1) dd += __shfl_xor(dd, off, 64);
#pragma unroll
  for (int k = 0; k < NCH; ++k) {
    acc[k] *= f;
#pragma unroll
    for (int off = G; off < 64; off <<= 1) acc[k] += __shfl_xor(acc[k], off, 64);
  }
  float inv = 1.f / dd;

  if (g != 0) return;   // group 0 holds the full result
  if (OUTB) {
    int p = wid >> 6, mrow = wid & 63;
#pragma unroll
    for (int kk = 0; kk < NCH / 8; ++kk) {
      s16x8 hv, lv;
#pragma unroll
      for (int t = 0; t < 8; ++t) {
        int c = c0 + kk * 8 + t;
        float v = fmaxf(acc[kk * 8 + t] * inv + bias[c], 0.f);
        u16 hb = f2bf(v);
        hv[t] = (short)hb;
        lv[t] = (short)f2bf(v - bf2f(hb));
      }
      int kc = c0 / 8 + kk;
      size_t ce = (((size_t)p * (C / 8) + kc) * 64 + mrow) * 8;
      *(s16x8*)&Hh[ce] = hv;
      *(s16x8*)&Hl[ce] = lv;
    }
  } else {
#pragma unroll
    for (int k = 0; k < NCH; ++k) {
      int c = c0 + k;
      if (c < C) {
        float v = acc[k] * inv + bias[c];
        hout[(size_t)wid * C + c] = fmaxf(v, 0.f);
      }
    }
  }
}

// ------------- global mean pool (batch sorted) --------------------------
__device__ int lower_bound_dev(const int* a, int n, int v) {
  int lo = 0, hi = n;
  while (lo < hi) { int mid = (lo + hi) >> 1; if (a[mid] < v) lo = mid + 1; else hi = mid; }
  return lo;
}

__global__ void pool_mean(const float* __restrict__ h, const int* __restrict__ batch,
                          float* __restrict__ g, int C) {
  int gi = blockIdx.x;
  int start = lower_bound_dev(batch, N_NODES, gi);
  int end   = lower_bound_dev(batch, N_NODES, gi + 1);
  int cnt = end - start;
  float inv = 1.f / (float)(cnt > 0 ? cnt : 1);
  for (int c = threadIdx.x; c < C; c += blockDim.x) {
    float s = 0.f;
    for (int n = start; n < end; ++n) s += h[(size_t)n * C + c];
    g[(size_t)gi * C + c] = s * inv;
  }
}

// ------------- small per-graph FC ---------------------------------------
__global__ void fc_kernel(const float* __restrict__ g, const float* __restrict__ W,
                          const float* __restrict__ b, float* __restrict__ out,
                          int K, int N, int do_relu) {
  __shared__ float row[304];
  int gi = blockIdx.x;
  for (int k = threadIdx.x; k < K; k += blockDim.x) row[k] = g[(size_t)gi * K + k];
  __syncthreads();
  int c = threadIdx.x;
  if (c >= N) return;
  float s = b[c];
  for (int k = 0; k < K; ++k) s += row[k] * W[(size_t)k * N + c];
  if (do_relu) s = fmaxf(s, 0.f);
  out[(size_t)gi * N + c] = s;
}

extern "C" void kernel_launch(void* const* d_in, const int* in_sizes, int n_in,
                              void* d_out, int out_size, void* d_ws, size_t ws_size,
                              hipStream_t stream) {
  const float* x     = (const float*)d_in[0];
  const int*   ei    = (const int*)d_in[1];
  const int*   batch = (const int*)d_in[2];
  const float* Wl[4], *bl[4], *Wr[4], *br[4], *att[4], *bias[4];
  for (int l = 0; l < 4; ++l) {
    Wl[l]   = (const float*)d_in[3 + l * 6 + 0];
    bl[l]   = (const float*)d_in[3 + l * 6 + 1];
    Wr[l]   = (const float*)d_in[3 + l * 6 + 2];
    br[l]   = (const float*)d_in[3 + l * 6 + 3];
    att[l]  = (const float*)d_in[3 + l * 6 + 4];
    bias[l] = (const float*)d_in[3 + l * 6 + 5];
  }
  const float* fc1_W = (const float*)d_in[27];
  const float* fc1_b = (const float*)d_in[28];
  const float* fc2_W = (const float*)d_in[29];
  const float* fc2_b = (const float*)d_in[30];

  char* wsb = (char*)d_ws;
  size_t off = 0;
  auto alloc = [&](size_t bytes) {
    void* p = (void*)(wsb + off);
    off += (bytes + 63) & ~(size_t)63;
    return p;
  };
  // +128B pad: C=300 gat reads 20 channels past row end on the last node
  float* xl    = (float*)alloc((size_t)N_NODES * 300 * 4 + 128);
  float* xr    = (float*)alloc((size_t)N_NODES * 300 * 4 + 128);
  // A0 panels; aliased by H panels (after layer-0 gemm) and hbuf (after layer-3 gemm)
  u16* A0h = (u16*)alloc((size_t)NPANEL * 40 * 512 * 2);
  u16* A0l = (u16*)alloc((size_t)NPANEL * 40 * 512 * 2);
  u16* Hh = A0h;
  u16* Hl = A0l;
  float* hbuf = (float*)A0h;
  float* gpool = (float*)alloc((size_t)N_GRAPHS * 300 * 4);
  float* g1    = (float*)alloc((size_t)N_GRAPHS * 300 * 4);
  const int Kact[4] = {300, 128, 128, 128};
  const int Cdim[4] = {128, 128, 128, 300};
  const int NLv[4]  = {128, 128, 128, 304};
  const int Kpv[4]  = {320, 128, 128, 128};
  u16* Wh[4], *Wlo[4];
  for (int l = 0; l < 4; ++l) {
    int kcn = Kpv[l] >> 3;
    Wh[l]  = (u16*)alloc((size_t)kcn * WCOLS * 8 * 2);
    Wlo[l] = (u16*)alloc((size_t)kcn * WCOLS * 8 * 2);
  }
  int* deg     = (int*)alloc((size_t)N_NODES * 4);
  int* rowptr  = (int*)alloc((size_t)(N_NODES + 1) * 4);
  int* bsum    = (int*)alloc(256 * 4);
  int* cursor  = (int*)alloc((size_t)N_NODES * 4);
  int* csr_src = (int*)alloc((size_t)E_TOT * 4);

  // one-time conversions
  conv_x<<<(NPANEL * 64 * 40 + 255) / 256, 256, 0, stream>>>(x, A0h, A0l);
  for (int l = 0; l < 4; ++l) {
    int kcn = Kpv[l] >> 3;
    conv_w<<<(kcn * WCOLS + 255) / 256, 256, 0, stream>>>(
        Wl[l], Wr[l], Wh[l], Wlo[l], Kact[l], Cdim[l], NLv[l], kcn);
  }

  // CSR build
  zero_ints<<<(N_NODES + 255) / 256, 256, 0, stream>>>(deg, N_NODES);
  deg_count<<<(E_TOT + 255) / 256, 256, 0, stream>>>(ei, deg);
  scan1<<<NB_SCAN, 256, 0, stream>>>(deg, rowptr, bsum);
  scan2<<<1, 256, 0, stream>>>(bsum);
  scan3<<<NB_SCAN, 256, 0, stream>>>(rowptr, bsum, cursor);
  fill_csr<<<(E_TOT + 255) / 256, 256, 0, stream>>>(ei, cursor, csr_src);

  const int nwave_blocks = (N_NODES + 3) / 4;
  for (int l = 0; l < 4; ++l) {
    const u16* Ahs = (l == 0) ? A0h : Hh;
    const u16* Als = (l == 0) ? A0l : Hl;
    int ny = (2 * NLv[l] + 255) / 256;
    dim3 gg(NPANEL, ny);
    gemm_dual<<<gg, 256, 0, stream>>>(Ahs, Als, Wh[l], Wlo[l], bl[l], br[l],
                                      xl, xr, Kpv[l], Cdim[l], NLv[l]);
    if (l == 0) {
      zero_pad_H<<<3, 256, 0, stream>>>(Hh, Hl);
    }
    if (l < 3) {
      gat_fused2<128, 128, 8, 16, 1><<<nwave_blocks, 256, 0, stream>>>(
          rowptr, csr_src, xl, xr, att[l], bias[l], nullptr, Hh, Hl);
    } else {
      gat_fused2<300, 300, 16, 20, 0><<<nwave_blocks, 256, 0, stream>>>(
          rowptr, csr_src, xl, xr, att[l], bias[l], hbuf, nullptr, nullptr);
    }
  }
  pool_mean<<<N_GRAPHS, 256, 0, stream>>>(hbuf, batch, gpool, 300);
  fc_kernel<<<N_GRAPHS, 320, 0, stream>>>(gpool, fc1_W, fc1_b, g1, 300, 300, 1);
  fc_kernel<<<N_GRAPHS, 768, 0, stream>>>(g1, fc2_W, fc2_b, (float*)d_out, 300, 768, 0);
}

// Round 6
// 940.738 us; speedup vs baseline: 1.1286x; 1.1286x over previous
//
#include <hip/hip_runtime.h>
#include <hip/hip_bf16.h>
#include <math.h>

#define N_NODES 50000
#define N_EDGES 800000
#define E_TOT   (N_EDGES + N_NODES)
#define N_GRAPHS 256
#define SLOPE 0.2f
#define NB_SCAN ((N_NODES + 255) / 256)
#define NPANEL 782            // ceil(50000/64)
#define WCOLS 768             // padded concatenated-W width

typedef __attribute__((ext_vector_type(8))) short s16x8;
typedef __attribute__((ext_vector_type(4))) float f32x4;
typedef _Float16 f16x2 __attribute__((ext_vector_type(2)));
typedef unsigned short u16;

__device__ __forceinline__ u16 f2bf(float v) {
  unsigned u = __float_as_uint(v);
  unsigned r = (u + 0x7fffu + ((u >> 16) & 1u)) >> 16;
  return (u16)r;
}
__device__ __forceinline__ float bf2f(u16 b) {
  return __uint_as_float(((unsigned)b) << 16);
}

__device__ __forceinline__ void gl_lds16(const void* g, void* l) {
  __builtin_amdgcn_global_load_lds(
      (const __attribute__((address_space(1))) unsigned int*)g,
      (__attribute__((address_space(3))) unsigned int*)l, 16, 0, 0);
}

// ---- x -> panel-swizzled split-bf16 [p][kc=40][m=64][ki=8], zero-padded ----
__global__ void conv_x(const float* __restrict__ x, u16* __restrict__ Ah,
                       u16* __restrict__ Al) {
  int id = blockIdx.x * blockDim.x + threadIdx.x;
  const int total = NPANEL * 64 * 40;
  if (id >= total) return;
  int kc = id % 40;
  int m  = (id / 40) % 64;
  int p  = id / 2560;
  int n = p * 64 + m;
  s16x8 hv, lv;
#pragma unroll
  for (int i = 0; i < 8; ++i) {
    int k = kc * 8 + i;
    float v = (n < N_NODES && k < 300) ? x[(size_t)n * 300 + k] : 0.f;
    u16 hb = f2bf(v);
    hv[i] = (short)hb;
    lv[i] = (short)f2bf(v - bf2f(hb));
  }
  size_t ce = (((size_t)p * 40 + kc) * 64 + m) * 8;
  *(s16x8*)&Ah[ce] = hv;
  *(s16x8*)&Al[ce] = lv;
}

// ---- Wl,Wr -> concatenated padded split-bf16 [kc][WCOLS][8] ----------------
__global__ void conv_w(const float* __restrict__ Wl, const float* __restrict__ Wr,
                       u16* __restrict__ Wh, u16* __restrict__ Wlo,
                       int K, int C, int NL, int kcn) {
  int id = blockIdx.x * blockDim.x + threadIdx.x;
  if (id >= kcn * WCOLS) return;
  int n = id % WCOLS, kc = id / WCOLS;
  s16x8 hv, lv;
#pragma unroll
  for (int i = 0; i < 8; ++i) {
    int k = kc * 8 + i;
    float v = 0.f;
    if (k < K) {
      if (n < NL) { if (n < C) v = Wl[(size_t)k * C + n]; }
      else if (n < 2 * NL && (n - NL) < C) v = Wr[(size_t)k * C + (n - NL)];
    }
    u16 hb = f2bf(v);
    hv[i] = (short)hb;
    lv[i] = (short)f2bf(v - bf2f(hb));
  }
  size_t ce = (size_t)id * 8;
  *(s16x8*)&Wh[ce] = hv;
  *(s16x8*)&Wlo[ce] = lv;
}

// ---- att (fp32) -> padded f16x2 tables, 192 entries per layer --------------
__global__ void conv_att(const float* __restrict__ a0, const float* __restrict__ a1,
                         const float* __restrict__ a2, const float* __restrict__ a3,
                         f16x2* __restrict__ att_h) {
  int t = blockIdx.x * blockDim.x + threadIdx.x;
  if (t >= 4 * 192) return;
  int l = t / 192, i = t % 192;
  const float* a = (l == 0) ? a0 : (l == 1) ? a1 : (l == 2) ? a2 : a3;
  int C = (l == 3) ? 300 : 128;
  int c = 2 * i;
  f16x2 r;
  r[0] = (c < C) ? (_Float16)a[c] : (_Float16)0.f;
  r[1] = (c + 1 < C) ? (_Float16)a[c + 1] : (_Float16)0.f;
  att_h[t] = r;
}

// ---- zero pad rows 50000..50047 of H panels (kcn=16) -----------------------
// NOTE: H aliases the A0 buffers -> must launch AFTER layer-0 gemm_dual.
__global__ void zero_pad_H(u16* __restrict__ Hh, u16* __restrict__ Hl) {
  int t = blockIdx.x * blockDim.x + threadIdx.x;
  if (t >= 48 * 16) return;
  int m = 16 + (t >> 4), kc = t & 15;
  size_t ce = (((size_t)781 * 16 + kc) * 64 + m) * 8;
  s16x8 z = {0, 0, 0, 0, 0, 0, 0, 0};
  *(s16x8*)&Hh[ce] = z;
  *(s16x8*)&Hl[ce] = z;
}

// ---- dual-output split-bf16 MFMA GEMM -> fp16 xl/xr ------------------------
__global__ __launch_bounds__(256, 2) void gemm_dual(
    const u16* __restrict__ Ah, const u16* __restrict__ Al,
    const u16* __restrict__ Wh, const u16* __restrict__ Wlo,
    const float* __restrict__ biasl, const float* __restrict__ biasr,
    _Float16* __restrict__ xlh, _Float16* __restrict__ xrh,
    int Kp, int C, int NL, int CSg) {
  __shared__ u16 As[2][4][64][8];
  __shared__ u16 Ws[2][4][256][8];
  const int tid = threadIdx.x, wv = tid >> 6, lane = tid & 63;
  const int p = blockIdx.x, n0 = blockIdx.y * 256;
  const int kcn = Kp >> 3, nk = Kp >> 5;
  const size_t abase0 = (size_t)p * kcn * 512;
  const int rsel = lane >> 4, rrow = lane & 15;
  f32x4 z4 = {0.f, 0.f, 0.f, 0.f};
  f32x4 acc[4][4];
#pragma unroll
  for (int a = 0; a < 4; ++a)
#pragma unroll
    for (int b = 0; b < 4; ++b) acc[a][b] = z4;

  for (int s = 0; s < nk; ++s) {
    const size_t abase = abase0 + (size_t)s * 2048;
    for (int q = wv; q < 40; q += 4) {
      const u16* g;
      u16* l;
      if (q < 8) {
        int h = q >> 2, qq = q & 3;
        g = (h ? Al : Ah) + abase + qq * 512;
        l = &As[h][0][0][0] + qq * 512;
      } else {
        int t2 = q - 8, h = t2 >> 4, j = t2 & 15;
        g = (h ? Wlo : Wh) + ((size_t)(s * 4 + (j >> 2)) * WCOLS + n0 + (j & 3) * 64) * 8;
        l = &Ws[h][0][0][0] + j * 512;
      }
      gl_lds16(g + lane * 8, l);
    }
    __syncthreads();
    s16x8 af[4][2], bf[4][2];
#pragma unroll
    for (int mt = 0; mt < 4; ++mt) {
      af[mt][0] = *(const s16x8*)&As[0][rsel][mt * 16 + rrow][0];
      af[mt][1] = *(const s16x8*)&As[1][rsel][mt * 16 + rrow][0];
    }
#pragma unroll
    for (int nt = 0; nt < 4; ++nt) {
      bf[nt][0] = *(const s16x8*)&Ws[0][rsel][wv * 64 + nt * 16 + rrow][0];
      bf[nt][1] = *(const s16x8*)&Ws[1][rsel][wv * 64 + nt * 16 + rrow][0];
    }
#pragma unroll
    for (int mt = 0; mt < 4; ++mt)
#pragma unroll
      for (int nt = 0; nt < 4; ++nt) {
        acc[mt][nt] = __builtin_amdgcn_mfma_f32_16x16x32_bf16(af[mt][1], bf[nt][0], acc[mt][nt], 0, 0, 0);
        acc[mt][nt] = __builtin_amdgcn_mfma_f32_16x16x32_bf16(af[mt][0], bf[nt][1], acc[mt][nt], 0, 0, 0);
        acc[mt][nt] = __builtin_amdgcn_mfma_f32_16x16x32_bf16(af[mt][0], bf[nt][0], acc[mt][nt], 0, 0, 0);
      }
    __syncthreads();
  }
#pragma unroll
  for (int mt = 0; mt < 4; ++mt) {
    int r0 = p * 64 + mt * 16 + rsel * 4;
#pragma unroll
    for (int nt = 0; nt < 4; ++nt) {
      int gc = n0 + wv * 64 + nt * 16 + rrow;
#pragma unroll
      for (int j = 0; j < 4; ++j) {
        int row = r0 + j;
        if (row >= N_NODES) continue;
        float v = acc[mt][nt][j];
        if (gc < NL) {
          if (gc < C) xlh[(size_t)row * CSg + gc] = (_Float16)(v + biasl[gc]);
        } else {
          int c2 = gc - NL;
          if (c2 >= 0 && c2 < C) xrh[(size_t)row * CSg + c2] = (_Float16)(v + biasr[c2]);
        }
      }
    }
  }
}

// ---------------- CSR build (once per launch) ---------------------------
__global__ void zero_ints(int* __restrict__ p, int n) {
  int i = blockIdx.x * blockDim.x + threadIdx.x;
  if (i < n) p[i] = 0;
}

__global__ void deg_count(const int* __restrict__ ei, int* __restrict__ deg) {
  int e = blockIdx.x * blockDim.x + threadIdx.x;
  if (e >= E_TOT) return;
  int d = (e < N_EDGES) ? ei[N_EDGES + e] : e - N_EDGES;
  atomicAdd(&deg[d], 1);
}

__global__ void scan1(const int* __restrict__ deg, int* __restrict__ rp,
                      int* __restrict__ bsum) {
  __shared__ int s[256];
  int i = blockIdx.x * 256 + threadIdx.x;
  int v = (i < N_NODES) ? deg[i] : 0;
  s[threadIdx.x] = v;
  __syncthreads();
  for (int off = 1; off < 256; off <<= 1) {
    int t = (threadIdx.x >= off) ? s[threadIdx.x - off] : 0;
    __syncthreads();
    s[threadIdx.x] += t;
    __syncthreads();
  }
  if (i < N_NODES) rp[i] = s[threadIdx.x] - v;
  if (threadIdx.x == 255) bsum[blockIdx.x] = s[255];
}

__global__ void scan2(int* __restrict__ bsum) {
  __shared__ int s[256];
  int v = (threadIdx.x < NB_SCAN) ? bsum[threadIdx.x] : 0;
  s[threadIdx.x] = v;
  __syncthreads();
  for (int off = 1; off < 256; off <<= 1) {
    int t = (threadIdx.x >= off) ? s[threadIdx.x - off] : 0;
    __syncthreads();
    s[threadIdx.x] += t;
    __syncthreads();
  }
  if (threadIdx.x < NB_SCAN) bsum[threadIdx.x] = s[threadIdx.x] - v;
}

__global__ void scan3(int* __restrict__ rp, const int* __restrict__ bsum,
                      int* __restrict__ cursor) {
  int i = blockIdx.x * 256 + threadIdx.x;
  if (i < N_NODES) {
    int v = rp[i] + bsum[blockIdx.x];
    rp[i] = v;
    cursor[i] = v;
  }
  if (i == 0) rp[N_NODES] = E_TOT;
}

__global__ void fill_csr(const int* __restrict__ ei, int* __restrict__ cursor,
                         int* __restrict__ csr_src) {
  int e = blockIdx.x * blockDim.x + threadIdx.x;
  if (e >= E_TOT) return;
  int s, d;
  if (e < N_EDGES) { s = ei[e]; d = ei[N_EDGES + e]; }
  else             { s = d = e - N_EDGES; }
  int pos = atomicAdd(&cursor[d], 1);
  csr_src[pos] = s;
}

// -------- fused GATv2 aggregation v3: wave/node, fp16 gather, prefetch ---
template <int C, int CS, int NC2, int OUTB>
__global__ __launch_bounds__(256) void gat_fused3(
    const int* __restrict__ rowptr, const int* __restrict__ csr_src,
    const _Float16* __restrict__ xlh, const _Float16* __restrict__ xrh,
    const f16x2* __restrict__ att_h, const float* __restrict__ bias,
    float* __restrict__ hout, u16* __restrict__ Hh, u16* __restrict__ Hl) {
  int wid = (int)((blockIdx.x * (size_t)blockDim.x + threadIdx.x) >> 6);
  int lane = threadIdx.x & 63;
  if (wid >= N_NODES) return;
  int beg = rowptr[wid], end = rowptr[wid + 1];

  f16x2 xri[NC2], attc[NC2];
  float acc0[NC2], acc1[NC2];
#pragma unroll
  for (int j = 0; j < NC2; ++j) {
    int c = 2 * lane + j * 128;
    xri[j] = *(const f16x2*)&xrh[(size_t)wid * CS + c];
    attc[j] = att_h[lane + j * 64];
    acc0[j] = 0.f;
    acc1[j] = 0.f;
  }
  const f16x2 slope2 = {(_Float16)SLOPE, (_Float16)SLOPE};
  const f16x2 zero2 = {(_Float16)0.f, (_Float16)0.f};

  float m = -INFINITY, d = 0.f;
  int s = csr_src[beg];
  f16x2 nxt[NC2];
#pragma unroll
  for (int j = 0; j < NC2; ++j)
    nxt[j] = *(const f16x2*)&xlh[(size_t)s * CS + 2 * lane + j * 128];

  for (int e = beg; e < end; ++e) {
    f16x2 cur[NC2];
#pragma unroll
    for (int j = 0; j < NC2; ++j) cur[j] = nxt[j];
    if (e + 1 < end) {
      s = csr_src[e + 1];
#pragma unroll
      for (int j = 0; j < NC2; ++j)
        nxt[j] = *(const f16x2*)&xlh[(size_t)s * CS + 2 * lane + j * 128];
    }
    float v = 0.f;
#pragma unroll
    for (int j = 0; j < NC2; ++j) {
      f16x2 m2 = cur[j] + xri[j];
      f16x2 mx2 = __builtin_elementwise_max(m2, zero2);
      f16x2 mn2 = m2 - mx2;                 // min(m,0)
      f16x2 lr2 = mx2 + slope2 * mn2;       // leaky_relu
#if __has_builtin(__builtin_amdgcn_fdot2)
      v = __builtin_amdgcn_fdot2(lr2, attc[j], v, false);
#else
      v += (float)lr2[0] * (float)attc[j][0] + (float)lr2[1] * (float)attc[j][1];
#endif
    }
#pragma unroll
    for (int off = 1; off < 64; off <<= 1) v += __shfl_xor(v, off, 64);
    float nm = fmaxf(m, v);
    float sc = __expf(m - nm);   // 0 on first edge
    float w = __expf(v - nm);
    d = d * sc + w;
#pragma unroll
    for (int j = 0; j < NC2; ++j) {
      acc0[j] = acc0[j] * sc + w * (float)cur[j][0];
      acc1[j] = acc1[j] * sc + w * (float)cur[j][1];
    }
    m = nm;
  }
  float inv = 1.f / d;

  if (OUTB) {
    // C=128: lane holds channels 2l, 2l+1 -> split-bf16 H panels
    float v0 = fmaxf(acc0[0] * inv + bias[2 * lane], 0.f);
    float v1 = fmaxf(acc1[0] * inv + bias[2 * lane + 1], 0.f);
    u16 hb0 = f2bf(v0), hb1 = f2bf(v1);
    u16 lb0 = f2bf(v0 - bf2f(hb0)), lb1 = f2bf(v1 - bf2f(hb1));
    int p = wid >> 6, mrow = wid & 63;
    int kc = lane >> 2, ki = (lane & 3) * 2;
    size_t ce = (((size_t)p * 16 + kc) * 64 + mrow) * 8 + ki;
    *(unsigned*)&Hh[ce] = (unsigned)hb0 | ((unsigned)hb1 << 16);
    *(unsigned*)&Hl[ce] = (unsigned)lb0 | ((unsigned)lb1 << 16);
  } else {
#pragma unroll
    for (int j = 0; j < NC2; ++j) {
      int c = 2 * lane + j * 128;
      if (c < C)     hout[(size_t)wid * C + c]     = fmaxf(acc0[j] * inv + bias[c], 0.f);
      if (c + 1 < C) hout[(size_t)wid * C + c + 1] = fmaxf(acc1[j] * inv + bias[c + 1], 0.f);
    }
  }
}

// ------------- global mean pool (batch sorted) --------------------------
__device__ int lower_bound_dev(const int* a, int n, int v) {
  int lo = 0, hi = n;
  while (lo < hi) { int mid = (lo + hi) >> 1; if (a[mid] < v) lo = mid + 1; else hi = mid; }
  return lo;
}

__global__ void pool_mean(const float* __restrict__ h, const int* __restrict__ batch,
                          float* __restrict__ g, int C) {
  int gi = blockIdx.x;
  int start = lower_bound_dev(batch, N_NODES, gi);
  int end   = lower_bound_dev(batch, N_NODES, gi + 1);
  int cnt = end - start;
  float inv = 1.f / (float)(cnt > 0 ? cnt : 1);
  for (int c = threadIdx.x; c < C; c += blockDim.x) {
    float s = 0.f;
    for (int n = start; n < end; ++n) s += h[(size_t)n * C + c];
    g[(size_t)gi * C + c] = s * inv;
  }
}

// ------------- small per-graph FC ---------------------------------------
__global__ void fc_kernel(const float* __restrict__ g, const float* __restrict__ W,
                          const float* __restrict__ b, float* __restrict__ out,
                          int K, int N, int do_relu) {
  __shared__ float row[304];
  int gi = blockIdx.x;
  for (int k = threadIdx.x; k < K; k += blockDim.x) row[k] = g[(size_t)gi * K + k];
  __syncthreads();
  int c = threadIdx.x;
  if (c >= N) return;
  float s = b[c];
  for (int k = 0; k < K; ++k) s += row[k] * W[(size_t)k * N + c];
  if (do_relu) s = fmaxf(s, 0.f);
  out[(size_t)gi * N + c] = s;
}

extern "C" void kernel_launch(void* const* d_in, const int* in_sizes, int n_in,
                              void* d_out, int out_size, void* d_ws, size_t ws_size,
                              hipStream_t stream) {
  const float* x     = (const float*)d_in[0];
  const int*   ei    = (const int*)d_in[1];
  const int*   batch = (const int*)d_in[2];
  const float* Wl[4], *bl[4], *Wr[4], *br[4], *att[4], *bias[4];
  for (int l = 0; l < 4; ++l) {
    Wl[l]   = (const float*)d_in[3 + l * 6 + 0];
    bl[l]   = (const float*)d_in[3 + l * 6 + 1];
    Wr[l]   = (const float*)d_in[3 + l * 6 + 2];
    br[l]   = (const float*)d_in[3 + l * 6 + 3];
    att[l]  = (const float*)d_in[3 + l * 6 + 4];
    bias[l] = (const float*)d_in[3 + l * 6 + 5];
  }
  const float* fc1_W = (const float*)d_in[27];
  const float* fc1_b = (const float*)d_in[28];
  const float* fc2_W = (const float*)d_in[29];
  const float* fc2_b = (const float*)d_in[30];

  char* wsb = (char*)d_ws;
  size_t off = 0;
  auto alloc = [&](size_t bytes) {
    void* p = (void*)(wsb + off);
    off += (bytes + 63) & ~(size_t)63;
    return p;
  };
  // fp16 xl/xr, stride up to 304; +512B pad for C=300 over-read (c up to 383)
  _Float16* xlh = (_Float16*)alloc((size_t)N_NODES * 304 * 2 + 512);
  _Float16* xrh = (_Float16*)alloc((size_t)N_NODES * 304 * 2 + 512);
  // A0 panels; aliased by H panels (after layer-0 gemm) and hbuf (after layer-3 gemm)
  u16* A0h = (u16*)alloc((size_t)NPANEL * 40 * 512 * 2);
  u16* A0l = (u16*)alloc((size_t)NPANEL * 40 * 512 * 2);
  u16* Hh = A0h;
  u16* Hl = A0l;
  float* hbuf = (float*)A0h;
  float* gpool = (float*)alloc((size_t)N_GRAPHS * 300 * 4);
  float* g1    = (float*)alloc((size_t)N_GRAPHS * 300 * 4);
  f16x2* att_h = (f16x2*)alloc((size_t)4 * 192 * 4);
  const int Kact[4] = {300, 128, 128, 128};
  const int Cdim[4] = {128, 128, 128, 300};
  const int NLv[4]  = {128, 128, 128, 304};
  const int Kpv[4]  = {320, 128, 128, 128};
  const int CSg[4]  = {128, 128, 128, 304};
  u16* Wh[4], *Wlo[4];
  for (int l = 0; l < 4; ++l) {
    int kcn = Kpv[l] >> 3;
    Wh[l]  = (u16*)alloc((size_t)kcn * WCOLS * 8 * 2);
    Wlo[l] = (u16*)alloc((size_t)kcn * WCOLS * 8 * 2);
  }
  int* deg     = (int*)alloc((size_t)N_NODES * 4);
  int* rowptr  = (int*)alloc((size_t)(N_NODES + 1) * 4);
  int* bsum    = (int*)alloc(256 * 4);
  int* cursor  = (int*)alloc((size_t)N_NODES * 4);
  int* csr_src = (int*)alloc((size_t)E_TOT * 4);

  // one-time conversions
  conv_x<<<(NPANEL * 64 * 40 + 255) / 256, 256, 0, stream>>>(x, A0h, A0l);
  for (int l = 0; l < 4; ++l) {
    int kcn = Kpv[l] >> 3;
    conv_w<<<(kcn * WCOLS + 255) / 256, 256, 0, stream>>>(
        Wl[l], Wr[l], Wh[l], Wlo[l], Kact[l], Cdim[l], NLv[l], kcn);
  }
  conv_att<<<3, 256, 0, stream>>>(att[0], att[1], att[2], att[3], att_h);

  // CSR build
  zero_ints<<<(N_NODES + 255) / 256, 256, 0, stream>>>(deg, N_NODES);
  deg_count<<<(E_TOT + 255) / 256, 256, 0, stream>>>(ei, deg);
  scan1<<<NB_SCAN, 256, 0, stream>>>(deg, rowptr, bsum);
  scan2<<<1, 256, 0, stream>>>(bsum);
  scan3<<<NB_SCAN, 256, 0, stream>>>(rowptr, bsum, cursor);
  fill_csr<<<(E_TOT + 255) / 256, 256, 0, stream>>>(ei, cursor, csr_src);

  const int nwave_blocks = (N_NODES + 3) / 4;
  for (int l = 0; l < 4; ++l) {
    const u16* Ahs = (l == 0) ? A0h : Hh;
    const u16* Als = (l == 0) ? A0l : Hl;
    int ny = (2 * NLv[l] + 255) / 256;
    dim3 gg(NPANEL, ny);
    gemm_dual<<<gg, 256, 0, stream>>>(Ahs, Als, Wh[l], Wlo[l], bl[l], br[l],
                                      xlh, xrh, Kpv[l], Cdim[l], NLv[l], CSg[l]);
    if (l == 0) {
      zero_pad_H<<<3, 256, 0, stream>>>(Hh, Hl);
    }
    if (l < 3) {
      gat_fused3<128, 128, 1, 1><<<nwave_blocks, 256, 0, stream>>>(
          rowptr, csr_src, xlh, xrh, att_h + l * 192, bias[l], nullptr, Hh, Hl);
    } else {
      gat_fused3<300, 304, 3, 0><<<nwave_blocks, 256, 0, stream>>>(
          rowptr, csr_src, xlh, xrh, att_h + l * 192, bias[l], hbuf, nullptr, nullptr);
    }
  }
  pool_mean<<<N_GRAPHS, 256, 0, stream>>>(hbuf, batch, gpool, 300);
  fc_kernel<<<N_GRAPHS, 320, 0, stream>>>(gpool, fc1_W, fc1_b, g1, 300, 300, 1);
  fc_kernel<<<N_GRAPHS, 768, 0, stream>>>(g1, fc2_W, fc2_b, (float*)d_out, 300, 768, 0);
}

// Round 7
// 720.950 us; speedup vs baseline: 1.4726x; 1.3049x over previous
//
#include <hip/hip_runtime.h>
#include <hip/hip_bf16.h>
#include <math.h>

#define N_NODES 50000
#define N_EDGES 800000
#define E_TOT   (N_EDGES + N_NODES)
#define N_GRAPHS 256
#define SLOPE 0.2f
#define NB_SCAN ((N_NODES + 255) / 256)
#define NPANEL 782            // ceil(50000/64)
#define WCOLS 768             // padded concatenated-W width

typedef __attribute__((ext_vector_type(8))) short s16x8;
typedef __attribute__((ext_vector_type(4))) float f32x4;
typedef _Float16 f16x2 __attribute__((ext_vector_type(2)));
typedef _Float16 f16x4 __attribute__((ext_vector_type(4)));
typedef _Float16 f16x8 __attribute__((ext_vector_type(8)));
typedef unsigned short u16;

__device__ __forceinline__ u16 f2bf(float v) {
  unsigned u = __float_as_uint(v);
  unsigned r = (u + 0x7fffu + ((u >> 16) & 1u)) >> 16;
  return (u16)r;
}
__device__ __forceinline__ float bf2f(u16 b) {
  return __uint_as_float(((unsigned)b) << 16);
}

__device__ __forceinline__ void gl_lds16(const void* g, void* l) {
  __builtin_amdgcn_global_load_lds(
      (const __attribute__((address_space(1))) unsigned int*)g,
      (__attribute__((address_space(3))) unsigned int*)l, 16, 0, 0);
}

// ---- x -> panel-swizzled split-bf16 [p][kc=40][m=64][ki=8], zero-padded ----
__global__ void conv_x(const float* __restrict__ x, u16* __restrict__ Ah,
                       u16* __restrict__ Al) {
  int id = blockIdx.x * blockDim.x + threadIdx.x;
  const int total = NPANEL * 64 * 40;
  if (id >= total) return;
  int kc = id % 40;
  int m  = (id / 40) % 64;
  int p  = id / 2560;
  int n = p * 64 + m;
  s16x8 hv, lv;
#pragma unroll
  for (int i = 0; i < 8; ++i) {
    int k = kc * 8 + i;
    float v = (n < N_NODES && k < 300) ? x[(size_t)n * 300 + k] : 0.f;
    u16 hb = f2bf(v);
    hv[i] = (short)hb;
    lv[i] = (short)f2bf(v - bf2f(hb));
  }
  size_t ce = (((size_t)p * 40 + kc) * 64 + m) * 8;
  *(s16x8*)&Ah[ce] = hv;
  *(s16x8*)&Al[ce] = lv;
}

// ---- Wl,Wr -> concatenated padded split-bf16 [kc][WCOLS][8] ----------------
__global__ void conv_w(const float* __restrict__ Wl, const float* __restrict__ Wr,
                       u16* __restrict__ Wh, u16* __restrict__ Wlo,
                       int K, int C, int NL, int kcn) {
  int id = blockIdx.x * blockDim.x + threadIdx.x;
  if (id >= kcn * WCOLS) return;
  int n = id % WCOLS, kc = id / WCOLS;
  s16x8 hv, lv;
#pragma unroll
  for (int i = 0; i < 8; ++i) {
    int k = kc * 8 + i;
    float v = 0.f;
    if (k < K) {
      if (n < NL) { if (n < C) v = Wl[(size_t)k * C + n]; }
      else if (n < 2 * NL && (n - NL) < C) v = Wr[(size_t)k * C + (n - NL)];
    }
    u16 hb = f2bf(v);
    hv[i] = (short)hb;
    lv[i] = (short)f2bf(v - bf2f(hb));
  }
  size_t ce = (size_t)id * 8;
  *(s16x8*)&Wh[ce] = hv;
  *(s16x8*)&Wlo[ce] = lv;
}

// ---- att (fp32) -> padded f16x2 tables, 192 entries per layer --------------
__global__ void conv_att(const float* __restrict__ a0, const float* __restrict__ a1,
                         const float* __restrict__ a2, const float* __restrict__ a3,
                         f16x2* __restrict__ att_h) {
  int t = blockIdx.x * blockDim.x + threadIdx.x;
  if (t >= 4 * 192) return;
  int l = t / 192, i = t % 192;
  const float* a = (l == 0) ? a0 : (l == 1) ? a1 : (l == 2) ? a2 : a3;
  int C = (l == 3) ? 300 : 128;
  int c = 2 * i;
  f16x2 r;
  r[0] = (c < C) ? (_Float16)a[c] : (_Float16)0.f;
  r[1] = (c + 1 < C) ? (_Float16)a[c + 1] : (_Float16)0.f;
  att_h[t] = r;
}

// ---- zero pad rows 50000..50047 of H panels (kcn=16) -----------------------
__global__ void zero_pad_H(u16* __restrict__ Hh, u16* __restrict__ Hl) {
  int t = blockIdx.x * blockDim.x + threadIdx.x;
  if (t >= 48 * 16) return;
  int m = 16 + (t >> 4), kc = t & 15;
  size_t ce = (((size_t)781 * 16 + kc) * 64 + m) * 8;
  s16x8 z = {0, 0, 0, 0, 0, 0, 0, 0};
  *(s16x8*)&Hh[ce] = z;
  *(s16x8*)&Hl[ce] = z;
}

// ---- zero stale cols 300..319 of the stride-320 layer-3 xl/xr buffers ------
__global__ void zero_xl_pad(_Float16* __restrict__ xlh, _Float16* __restrict__ xrh) {
  int t = blockIdx.x * blockDim.x + threadIdx.x;
  if (t >= N_NODES * 20) return;
  int r = t / 20, k = t % 20;
  size_t o = (size_t)r * 320 + 300 + k;
  xlh[o] = (_Float16)0.f;
  xrh[o] = (_Float16)0.f;
}

// ---- dual-output split-bf16 MFMA GEMM -> fp16 xl/xr ------------------------
__global__ __launch_bounds__(256, 2) void gemm_dual(
    const u16* __restrict__ Ah, const u16* __restrict__ Al,
    const u16* __restrict__ Wh, const u16* __restrict__ Wlo,
    const float* __restrict__ biasl, const float* __restrict__ biasr,
    _Float16* __restrict__ xlh, _Float16* __restrict__ xrh,
    int Kp, int C, int NL, int CSg) {
  __shared__ u16 As[2][4][64][8];
  __shared__ u16 Ws[2][4][256][8];
  const int tid = threadIdx.x, wv = tid >> 6, lane = tid & 63;
  const int p = blockIdx.x, n0 = blockIdx.y * 256;
  const int kcn = Kp >> 3, nk = Kp >> 5;
  const size_t abase0 = (size_t)p * kcn * 512;
  const int rsel = lane >> 4, rrow = lane & 15;
  f32x4 z4 = {0.f, 0.f, 0.f, 0.f};
  f32x4 acc[4][4];
#pragma unroll
  for (int a = 0; a < 4; ++a)
#pragma unroll
    for (int b = 0; b < 4; ++b) acc[a][b] = z4;

  for (int s = 0; s < nk; ++s) {
    const size_t abase = abase0 + (size_t)s * 2048;
    for (int q = wv; q < 40; q += 4) {
      const u16* g;
      u16* l;
      if (q < 8) {
        int h = q >> 2, qq = q & 3;
        g = (h ? Al : Ah) + abase + qq * 512;
        l = &As[h][0][0][0] + qq * 512;
      } else {
        int t2 = q - 8, h = t2 >> 4, j = t2 & 15;
        g = (h ? Wlo : Wh) + ((size_t)(s * 4 + (j >> 2)) * WCOLS + n0 + (j & 3) * 64) * 8;
        l = &Ws[h][0][0][0] + j * 512;
      }
      gl_lds16(g + lane * 8, l);
    }
    __syncthreads();
    s16x8 af[4][2], bf[4][2];
#pragma unroll
    for (int mt = 0; mt < 4; ++mt) {
      af[mt][0] = *(const s16x8*)&As[0][rsel][mt * 16 + rrow][0];
      af[mt][1] = *(const s16x8*)&As[1][rsel][mt * 16 + rrow][0];
    }
#pragma unroll
    for (int nt = 0; nt < 4; ++nt) {
      bf[nt][0] = *(const s16x8*)&Ws[0][rsel][wv * 64 + nt * 16 + rrow][0];
      bf[nt][1] = *(const s16x8*)&Ws[1][rsel][wv * 64 + nt * 16 + rrow][0];
    }
#pragma unroll
    for (int mt = 0; mt < 4; ++mt)
#pragma unroll
      for (int nt = 0; nt < 4; ++nt) {
        acc[mt][nt] = __builtin_amdgcn_mfma_f32_16x16x32_bf16(af[mt][1], bf[nt][0], acc[mt][nt], 0, 0, 0);
        acc[mt][nt] = __builtin_amdgcn_mfma_f32_16x16x32_bf16(af[mt][0], bf[nt][1], acc[mt][nt], 0, 0, 0);
        acc[mt][nt] = __builtin_amdgcn_mfma_f32_16x16x32_bf16(af[mt][0], bf[nt][0], acc[mt][nt], 0, 0, 0);
      }
    __syncthreads();
  }
#pragma unroll
  for (int mt = 0; mt < 4; ++mt) {
    int r0 = p * 64 + mt * 16 + rsel * 4;
#pragma unroll
    for (int nt = 0; nt < 4; ++nt) {
      int gc = n0 + wv * 64 + nt * 16 + rrow;
#pragma unroll
      for (int j = 0; j < 4; ++j) {
        int row = r0 + j;
        if (row >= N_NODES) continue;
        float v = acc[mt][nt][j];
        if (gc < NL) {
          if (gc < C) xlh[(size_t)row * CSg + gc] = (_Float16)(v + biasl[gc]);
        } else {
          int c2 = gc - NL;
          if (c2 >= 0 && c2 < C) xrh[(size_t)row * CSg + c2] = (_Float16)(v + biasr[c2]);
        }
      }
    }
  }
}

// ---------------- CSR build (once per launch) ---------------------------
__global__ void zero_ints(int* __restrict__ p, int n) {
  int i = blockIdx.x * blockDim.x + threadIdx.x;
  if (i < n) p[i] = 0;
}

__global__ void deg_count(const int* __restrict__ ei, int* __restrict__ deg) {
  int e = blockIdx.x * blockDim.x + threadIdx.x;
  if (e >= E_TOT) return;
  int d = (e < N_EDGES) ? ei[N_EDGES + e] : e - N_EDGES;
  atomicAdd(&deg[d], 1);
}

__global__ void scan1(const int* __restrict__ deg, int* __restrict__ rp,
                      int* __restrict__ bsum) {
  __shared__ int s[256];
  int i = blockIdx.x * 256 + threadIdx.x;
  int v = (i < N_NODES) ? deg[i] : 0;
  s[threadIdx.x] = v;
  __syncthreads();
  for (int off = 1; off < 256; off <<= 1) {
    int t = (threadIdx.x >= off) ? s[threadIdx.x - off] : 0;
    __syncthreads();
    s[threadIdx.x] += t;
    __syncthreads();
  }
  if (i < N_NODES) rp[i] = s[threadIdx.x] - v;
  if (threadIdx.x == 255) bsum[blockIdx.x] = s[255];
}

__global__ void scan2(int* __restrict__ bsum) {
  __shared__ int s[256];
  int v = (threadIdx.x < NB_SCAN) ? bsum[threadIdx.x] : 0;
  s[threadIdx.x] = v;
  __syncthreads();
  for (int off = 1; off < 256; off <<= 1) {
    int t = (threadIdx.x >= off) ? s[threadIdx.x - off] : 0;
    __syncthreads();
    s[threadIdx.x] += t;
    __syncthreads();
  }
  if (threadIdx.x < NB_SCAN) bsum[threadIdx.x] = s[threadIdx.x] - v;
}

__global__ void scan3(int* __restrict__ rp, const int* __restrict__ bsum,
                      int* __restrict__ cursor) {
  int i = blockIdx.x * 256 + threadIdx.x;
  if (i < N_NODES) {
    int v = rp[i] + bsum[blockIdx.x];
    rp[i] = v;
    cursor[i] = v;
  }
  if (i == 0) rp[N_NODES] = E_TOT;
}

__global__ void fill_csr(const int* __restrict__ ei, int* __restrict__ cursor,
                         int* __restrict__ csr_src) {
  int e = blockIdx.x * blockDim.x + threadIdx.x;
  if (e >= E_TOT) return;
  int s, d;
  if (e < N_EDGES) { s = ei[e]; d = ei[N_EDGES + e]; }
  else             { s = d = e - N_EDGES; }
  int pos = atomicAdd(&cursor[d], 1);
  csr_src[pos] = s;
}

// ---- row loader: ND f16x2 regs from a (8B-aligned) fp16 row slice ----------
template <int ND>
__device__ __forceinline__ void load_row(f16x2* dst, const _Float16* p) {
  if constexpr (ND == 4) {
    f16x8 t = *(const f16x8*)p;   // 16B aligned for CS=128 layout
#pragma unroll
    for (int j = 0; j < 4; ++j) {
      f16x2 r; r[0] = t[2 * j]; r[1] = t[2 * j + 1]; dst[j] = r;
    }
  } else {
#pragma unroll
    for (int q = 0; q < ND / 2; ++q) {
      f16x4 t = *(const f16x4*)(p + 4 * q);   // 8B aligned
      f16x2 a; a[0] = t[0]; a[1] = t[1]; dst[2 * q] = a;
      f16x2 b; b[0] = t[2]; b[1] = t[3]; dst[2 * q + 1] = b;
    }
  }
}

// -------- fused GATv2 aggregation v4: 16 lanes/edge, 4 edges in flight,
// deferred-max softmax (no online rescale), packed-f16 math ----------------
template <int C, int CS, int NCH, int OUTB>
__global__ __launch_bounds__(256) void gat_fused4(
    const int* __restrict__ rowptr, const int* __restrict__ csr_src,
    const _Float16* __restrict__ xlh, const _Float16* __restrict__ xrh,
    const f16x2* __restrict__ att_h, const float* __restrict__ bias,
    float* __restrict__ hout, u16* __restrict__ Hh, u16* __restrict__ Hl) {
  constexpr int ND = NCH / 2;
  int wid = (int)((blockIdx.x * (size_t)blockDim.x + threadIdx.x) >> 6);
  int lane = threadIdx.x & 63;
  if (wid >= N_NODES) return;
  const int g = lane >> 4, li = lane & 15;
  const int c0 = li * NCH;
  int beg = rowptr[wid], end = rowptr[wid + 1];

  f16x2 xri[ND], attc[ND];
  load_row<ND>(xri, xrh + (size_t)wid * CS + c0);
#pragma unroll
  for (int j = 0; j < ND; ++j) attc[j] = att_h[(c0 >> 1) + j];

  float acc[NCH];
#pragma unroll
  for (int k = 0; k < NCH; ++k) acc[k] = 0.f;
  float dsum = 0.f;
  const f16x2 slope2 = {(_Float16)SLOPE, (_Float16)SLOPE};
  const f16x2 zero2 = {(_Float16)0.f, (_Float16)0.f};

  int e = beg + g;
  f16x2 nxt[ND];
  {
    int s = csr_src[e < end ? e : end - 1];
    load_row<ND>(nxt, xlh + (size_t)s * CS + c0);
  }
  int nit = (end - beg + 3) >> 2;
  for (int it = 0; it < nit; ++it) {
    f16x2 cur[ND];
#pragma unroll
    for (int j = 0; j < ND; ++j) cur[j] = nxt[j];
    bool valid = e < end;
    if (beg + (it + 1) * 4 < end) {        // wave-uniform
      int en = e + 4;
      int s = csr_src[en < end ? en : end - 1];
      load_row<ND>(nxt, xlh + (size_t)s * CS + c0);
    }
    float v = 0.f;
#pragma unroll
    for (int j = 0; j < ND; ++j) {
      f16x2 m2 = cur[j] + xri[j];
      f16x2 mx = __builtin_elementwise_max(m2, zero2);
      f16x2 mn = __builtin_elementwise_min(m2, zero2);
      f16x2 lr = mx + slope2 * mn;         // leaky_relu
#if __has_builtin(__builtin_amdgcn_fdot2)
      v = __builtin_amdgcn_fdot2(lr, attc[j], v, false);
#else
      v += (float)lr[0] * (float)attc[j][0] + (float)lr[1] * (float)attc[j][1];
#endif
    }
    v += __shfl_xor(v, 1);
    v += __shfl_xor(v, 2);
    v += __shfl_xor(v, 4);
    v += __shfl_xor(v, 8);
    float w = valid ? __expf(v) : 0.f;     // deferred max: |v| small, fp32-safe
    dsum += w;
#pragma unroll
    for (int j = 0; j < ND; ++j) {
      acc[2 * j]     += w * (float)cur[j][0];   // v_fma_mix
      acc[2 * j + 1] += w * (float)cur[j][1];
    }
    e += 4;
  }
  // merge the 4 edge-groups (channel map identical across groups)
#pragma unroll
  for (int k = 0; k < NCH; ++k) {
    acc[k] += __shfl_xor(acc[k], 16);
    acc[k] += __shfl_xor(acc[k], 32);
  }
  dsum += __shfl_xor(dsum, 16);
  dsum += __shfl_xor(dsum, 32);
  if (g != 0) return;
  float inv = 1.f / dsum;
  if (OUTB) {
    s16x8 hv, lv;
#pragma unroll
    for (int k = 0; k < 8; ++k) {
      float vv = fmaxf(acc[k] * inv + bias[c0 + k], 0.f);
      u16 hb = f2bf(vv);
      hv[k] = (short)hb;
      lv[k] = (short)f2bf(vv - bf2f(hb));
    }
    int p = wid >> 6, mrow = wid & 63;
    size_t ce = (((size_t)p * 16 + li) * 64 + mrow) * 8;
    *(s16x8*)&Hh[ce] = hv;
    *(s16x8*)&Hl[ce] = lv;
  } else {
#pragma unroll
    for (int k = 0; k < NCH; ++k) {
      int c = c0 + k;
      if (c < C) hout[(size_t)wid * C + c] = fmaxf(acc[k] * inv + bias[c], 0.f);
    }
  }
}

// ------------- global mean pool (batch sorted) --------------------------
__device__ int lower_bound_dev(const int* a, int n, int v) {
  int lo = 0, hi = n;
  while (lo < hi) { int mid = (lo + hi) >> 1; if (a[mid] < v) lo = mid + 1; else hi = mid; }
  return lo;
}

__global__ void pool_mean(const float* __restrict__ h, const int* __restrict__ batch,
                          float* __restrict__ g, int C) {
  int gi = blockIdx.x;
  int start = lower_bound_dev(batch, N_NODES, gi);
  int end   = lower_bound_dev(batch, N_NODES, gi + 1);
  int cnt = end - start;
  float inv = 1.f / (float)(cnt > 0 ? cnt : 1);
  for (int c = threadIdx.x; c < C; c += blockDim.x) {
    float s = 0.f;
    for (int n = start; n < end; ++n) s += h[(size_t)n * C + c];
    g[(size_t)gi * C + c] = s * inv;
  }
}

// ------------- small per-graph FC ---------------------------------------
__global__ void fc_kernel(const float* __restrict__ g, const float* __restrict__ W,
                          const float* __restrict__ b, float* __restrict__ out,
                          int K, int N, int do_relu) {
  __shared__ float row[304];
  int gi = blockIdx.x;
  for (int k = threadIdx.x; k < K; k += blockDim.x) row[k] = g[(size_t)gi * K + k];
  __syncthreads();
  int c = threadIdx.x;
  if (c >= N) return;
  float s = b[c];
  for (int k = 0; k < K; ++k) s += row[k] * W[(size_t)k * N + c];
  if (do_relu) s = fmaxf(s, 0.f);
  out[(size_t)gi * N + c] = s;
}

extern "C" void kernel_launch(void* const* d_in, const int* in_sizes, int n_in,
                              void* d_out, int out_size, void* d_ws, size_t ws_size,
                              hipStream_t stream) {
  const float* x     = (const float*)d_in[0];
  const int*   ei    = (const int*)d_in[1];
  const int*   batch = (const int*)d_in[2];
  const float* Wl[4], *bl[4], *Wr[4], *br[4], *att[4], *bias[4];
  for (int l = 0; l < 4; ++l) {
    Wl[l]   = (const float*)d_in[3 + l * 6 + 0];
    bl[l]   = (const float*)d_in[3 + l * 6 + 1];
    Wr[l]   = (const float*)d_in[3 + l * 6 + 2];
    br[l]   = (const float*)d_in[3 + l * 6 + 3];
    att[l]  = (const float*)d_in[3 + l * 6 + 4];
    bias[l] = (const float*)d_in[3 + l * 6 + 5];
  }
  const float* fc1_W = (const float*)d_in[27];
  const float* fc1_b = (const float*)d_in[28];
  const float* fc2_W = (const float*)d_in[29];
  const float* fc2_b = (const float*)d_in[30];

  char* wsb = (char*)d_ws;
  size_t off = 0;
  auto alloc = [&](size_t bytes) {
    void* p = (void*)(wsb + off);
    off += (bytes + 63) & ~(size_t)63;
    return p;
  };
  // fp16 xl/xr, stride up to 320 (layer 3); layers 0-2 use stride 128
  _Float16* xlh = (_Float16*)alloc((size_t)N_NODES * 320 * 2);
  _Float16* xrh = (_Float16*)alloc((size_t)N_NODES * 320 * 2);
  // A0 panels; aliased by H panels (after layer-0 gemm) and hbuf (after layer-3 gemm)
  u16* A0h = (u16*)alloc((size_t)NPANEL * 40 * 512 * 2);
  u16* A0l = (u16*)alloc((size_t)NPANEL * 40 * 512 * 2);
  u16* Hh = A0h;
  u16* Hl = A0l;
  float* hbuf = (float*)A0h;
  float* gpool = (float*)alloc((size_t)N_GRAPHS * 300 * 4);
  float* g1    = (float*)alloc((size_t)N_GRAPHS * 300 * 4);
  f16x2* att_h = (f16x2*)alloc((size_t)4 * 192 * 4);
  const int Kact[4] = {300, 128, 128, 128};
  const int Cdim[4] = {128, 128, 128, 300};
  const int NLv[4]  = {128, 128, 128, 304};
  const int Kpv[4]  = {320, 128, 128, 128};
  const int CSg[4]  = {128, 128, 128, 320};
  u16* Wh[4], *Wlo[4];
  for (int l = 0; l < 4; ++l) {
    int kcn = Kpv[l] >> 3;
    Wh[l]  = (u16*)alloc((size_t)kcn * WCOLS * 8 * 2);
    Wlo[l] = (u16*)alloc((size_t)kcn * WCOLS * 8 * 2);
  }
  int* deg     = (int*)alloc((size_t)N_NODES * 4);
  int* rowptr  = (int*)alloc((size_t)(N_NODES + 1) * 4);
  int* bsum    = (int*)alloc(256 * 4);
  int* cursor  = (int*)alloc((size_t)N_NODES * 4);
  int* csr_src = (int*)alloc((size_t)E_TOT * 4);

  // one-time conversions
  conv_x<<<(NPANEL * 64 * 40 + 255) / 256, 256, 0, stream>>>(x, A0h, A0l);
  for (int l = 0; l < 4; ++l) {
    int kcn = Kpv[l] >> 3;
    conv_w<<<(kcn * WCOLS + 255) / 256, 256, 0, stream>>>(
        Wl[l], Wr[l], Wh[l], Wlo[l], Kact[l], Cdim[l], NLv[l], kcn);
  }
  conv_att<<<3, 256, 0, stream>>>(att[0], att[1], att[2], att[3], att_h);

  // CSR build
  zero_ints<<<(N_NODES + 255) / 256, 256, 0, stream>>>(deg, N_NODES);
  deg_count<<<(E_TOT + 255) / 256, 256, 0, stream>>>(ei, deg);
  scan1<<<NB_SCAN, 256, 0, stream>>>(deg, rowptr, bsum);
  scan2<<<1, 256, 0, stream>>>(bsum);
  scan3<<<NB_SCAN, 256, 0, stream>>>(rowptr, bsum, cursor);
  fill_csr<<<(E_TOT + 255) / 256, 256, 0, stream>>>(ei, cursor, csr_src);

  const int nwave_blocks = (N_NODES + 3) / 4;
  for (int l = 0; l < 4; ++l) {
    const u16* Ahs = (l == 0) ? A0h : Hh;
    const u16* Als = (l == 0) ? A0l : Hl;
    int ny = (2 * NLv[l] + 255) / 256;
    dim3 gg(NPANEL, ny);
    gemm_dual<<<gg, 256, 0, stream>>>(Ahs, Als, Wh[l], Wlo[l], bl[l], br[l],
                                      xlh, xrh, Kpv[l], Cdim[l], NLv[l], CSg[l]);
    if (l == 0) {
      zero_pad_H<<<3, 256, 0, stream>>>(Hh, Hl);
    }
    if (l < 3) {
      gat_fused4<128, 128, 8, 1><<<nwave_blocks, 256, 0, stream>>>(
          rowptr, csr_src, xlh, xrh, att_h + l * 192, bias[l], nullptr, Hh, Hl);
    } else {
      // zero stale cols 300..319 of stride-320 rows (never written by gemm)
      zero_xl_pad<<<(N_NODES * 20 + 255) / 256, 256, 0, stream>>>(xlh, xrh);
      gat_fused4<300, 320, 20, 0><<<nwave_blocks, 256, 0, stream>>>(
          rowptr, csr_src, xlh, xrh, att_h + l * 192, bias[l], hbuf, nullptr, nullptr);
    }
  }
  pool_mean<<<N_GRAPHS, 256, 0, stream>>>(hbuf, batch, gpool, 300);
  fc_kernel<<<N_GRAPHS, 320, 0, stream>>>(gpool, fc1_W, fc1_b, g1, 300, 300, 1);
  fc_kernel<<<N_GRAPHS, 768, 0, stream>>>(g1, fc2_W, fc2_b, (float*)d_out, 300, 768, 0);
}

// Round 8
// 646.500 us; speedup vs baseline: 1.6422x; 1.1152x over previous
//
#include <hip/hip_runtime.h>
#include <hip/hip_bf16.h>
#include <math.h>

#define N_NODES 50000
#define N_EDGES 800000
#define E_TOT   (N_EDGES + N_NODES)
#define N_GRAPHS 256
#define SLOPE 0.2f
#define NB_SCAN ((N_NODES + 255) / 256)
#define NPANEL 782            // ceil(50000/64)
#define WCOLS 768             // padded concatenated-W width
#define POOL_SPLIT 8

typedef __attribute__((ext_vector_type(8))) short s16x8;
typedef __attribute__((ext_vector_type(4))) float f32x4;
typedef _Float16 f16x2 __attribute__((ext_vector_type(2)));
typedef _Float16 f16x4 __attribute__((ext_vector_type(4)));
typedef _Float16 f16x8 __attribute__((ext_vector_type(8)));
typedef unsigned short u16;

__device__ __forceinline__ u16 f2bf(float v) {
  unsigned u = __float_as_uint(v);
  unsigned r = (u + 0x7fffu + ((u >> 16) & 1u)) >> 16;
  return (u16)r;
}
__device__ __forceinline__ float bf2f(u16 b) {
  return __uint_as_float(((unsigned)b) << 16);
}

__device__ __forceinline__ void gl_lds16(const void* g, void* l) {
  __builtin_amdgcn_global_load_lds(
      (const __attribute__((address_space(1))) unsigned int*)g,
      (__attribute__((address_space(3))) unsigned int*)l, 16, 0, 0);
}

// ---- x -> panel-swizzled split-bf16 [p][kc=40][m=64][ki=8], zero-padded ----
__global__ void conv_x(const float* __restrict__ x, u16* __restrict__ Ah,
                       u16* __restrict__ Al) {
  int id = blockIdx.x * blockDim.x + threadIdx.x;
  const int total = NPANEL * 64 * 40;
  if (id >= total) return;
  int kc = id % 40;
  int m  = (id / 40) % 64;
  int p  = id / 2560;
  int n = p * 64 + m;
  s16x8 hv, lv;
#pragma unroll
  for (int i = 0; i < 8; ++i) {
    int k = kc * 8 + i;
    float v = (n < N_NODES && k < 300) ? x[(size_t)n * 300 + k] : 0.f;
    u16 hb = f2bf(v);
    hv[i] = (short)hb;
    lv[i] = (short)f2bf(v - bf2f(hb));
  }
  size_t ce = (((size_t)p * 40 + kc) * 64 + m) * 8;
  *(s16x8*)&Ah[ce] = hv;
  *(s16x8*)&Al[ce] = lv;
}

// ---- Wl,Wr -> concatenated padded split-bf16 [kc][WCOLS][8] ----------------
__global__ void conv_w(const float* __restrict__ Wl, const float* __restrict__ Wr,
                       u16* __restrict__ Wh, u16* __restrict__ Wlo,
                       int K, int C, int NL, int kcn) {
  int id = blockIdx.x * blockDim.x + threadIdx.x;
  if (id >= kcn * WCOLS) return;
  int n = id % WCOLS, kc = id / WCOLS;
  s16x8 hv, lv;
#pragma unroll
  for (int i = 0; i < 8; ++i) {
    int k = kc * 8 + i;
    float v = 0.f;
    if (k < K) {
      if (n < NL) { if (n < C) v = Wl[(size_t)k * C + n]; }
      else if (n < 2 * NL && (n - NL) < C) v = Wr[(size_t)k * C + (n - NL)];
    }
    u16 hb = f2bf(v);
    hv[i] = (short)hb;
    lv[i] = (short)f2bf(v - bf2f(hb));
  }
  size_t ce = (size_t)id * 8;
  *(s16x8*)&Wh[ce] = hv;
  *(s16x8*)&Wlo[ce] = lv;
}

// ---- att (fp32) -> padded f16x2 tables, 192 entries per layer --------------
__global__ void conv_att(const float* __restrict__ a0, const float* __restrict__ a1,
                         const float* __restrict__ a2, const float* __restrict__ a3,
                         f16x2* __restrict__ att_h) {
  int t = blockIdx.x * blockDim.x + threadIdx.x;
  if (t >= 4 * 192) return;
  int l = t / 192, i = t % 192;
  const float* a = (l == 0) ? a0 : (l == 1) ? a1 : (l == 2) ? a2 : a3;
  int C = (l == 3) ? 300 : 128;
  int c = 2 * i;
  f16x2 r;
  r[0] = (c < C) ? (_Float16)a[c] : (_Float16)0.f;
  r[1] = (c + 1 < C) ? (_Float16)a[c + 1] : (_Float16)0.f;
  att_h[t] = r;
}

// ---- zero pad rows 50000..50047 of H panels (kcn=16) -----------------------
__global__ void zero_pad_H(u16* __restrict__ Hh, u16* __restrict__ Hl) {
  int t = blockIdx.x * blockDim.x + threadIdx.x;
  if (t >= 48 * 16) return;
  int m = 16 + (t >> 4), kc = t & 15;
  size_t ce = (((size_t)781 * 16 + kc) * 64 + m) * 8;
  s16x8 z = {0, 0, 0, 0, 0, 0, 0, 0};
  *(s16x8*)&Hh[ce] = z;
  *(s16x8*)&Hl[ce] = z;
}

// ---- zero stale cols 300..319 of the stride-320 layer-3 xl/xr buffers ------
__global__ void zero_xl_pad(_Float16* __restrict__ xlh, _Float16* __restrict__ xrh) {
  int t = blockIdx.x * blockDim.x + threadIdx.x;
  if (t >= N_NODES * 20) return;
  int r = t / 20, k = t % 20;
  size_t o = (size_t)r * 320 + 300 + k;
  xlh[o] = (_Float16)0.f;
  xrh[o] = (_Float16)0.f;
}

// ---- dual-output split-bf16 MFMA GEMM -> fp16 xl/xr ------------------------
__global__ __launch_bounds__(256, 2) void gemm_dual(
    const u16* __restrict__ Ah, const u16* __restrict__ Al,
    const u16* __restrict__ Wh, const u16* __restrict__ Wlo,
    const float* __restrict__ biasl, const float* __restrict__ biasr,
    _Float16* __restrict__ xlh, _Float16* __restrict__ xrh,
    int Kp, int C, int NL, int CSg) {
  __shared__ u16 As[2][4][64][8];
  __shared__ u16 Ws[2][4][256][8];
  const int tid = threadIdx.x, wv = tid >> 6, lane = tid & 63;
  const int p = blockIdx.x, n0 = blockIdx.y * 256;
  const int kcn = Kp >> 3, nk = Kp >> 5;
  const size_t abase0 = (size_t)p * kcn * 512;
  const int rsel = lane >> 4, rrow = lane & 15;
  f32x4 z4 = {0.f, 0.f, 0.f, 0.f};
  f32x4 acc[4][4];
#pragma unroll
  for (int a = 0; a < 4; ++a)
#pragma unroll
    for (int b = 0; b < 4; ++b) acc[a][b] = z4;

  for (int s = 0; s < nk; ++s) {
    const size_t abase = abase0 + (size_t)s * 2048;
    for (int q = wv; q < 40; q += 4) {
      const u16* g;
      u16* l;
      if (q < 8) {
        int h = q >> 2, qq = q & 3;
        g = (h ? Al : Ah) + abase + qq * 512;
        l = &As[h][0][0][0] + qq * 512;
      } else {
        int t2 = q - 8, h = t2 >> 4, j = t2 & 15;
        g = (h ? Wlo : Wh) + ((size_t)(s * 4 + (j >> 2)) * WCOLS + n0 + (j & 3) * 64) * 8;
        l = &Ws[h][0][0][0] + j * 512;
      }
      gl_lds16(g + lane * 8, l);
    }
    __syncthreads();
    s16x8 af[4][2], bf[4][2];
#pragma unroll
    for (int mt = 0; mt < 4; ++mt) {
      af[mt][0] = *(const s16x8*)&As[0][rsel][mt * 16 + rrow][0];
      af[mt][1] = *(const s16x8*)&As[1][rsel][mt * 16 + rrow][0];
    }
#pragma unroll
    for (int nt = 0; nt < 4; ++nt) {
      bf[nt][0] = *(const s16x8*)&Ws[0][rsel][wv * 64 + nt * 16 + rrow][0];
      bf[nt][1] = *(const s16x8*)&Ws[1][rsel][wv * 64 + nt * 16 + rrow][0];
    }
#pragma unroll
    for (int mt = 0; mt < 4; ++mt)
#pragma unroll
      for (int nt = 0; nt < 4; ++nt) {
        acc[mt][nt] = __builtin_amdgcn_mfma_f32_16x16x32_bf16(af[mt][1], bf[nt][0], acc[mt][nt], 0, 0, 0);
        acc[mt][nt] = __builtin_amdgcn_mfma_f32_16x16x32_bf16(af[mt][0], bf[nt][1], acc[mt][nt], 0, 0, 0);
        acc[mt][nt] = __builtin_amdgcn_mfma_f32_16x16x32_bf16(af[mt][0], bf[nt][0], acc[mt][nt], 0, 0, 0);
      }
    __syncthreads();
  }
#pragma unroll
  for (int mt = 0; mt < 4; ++mt) {
    int r0 = p * 64 + mt * 16 + rsel * 4;
#pragma unroll
    for (int nt = 0; nt < 4; ++nt) {
      int gc = n0 + wv * 64 + nt * 16 + rrow;
#pragma unroll
      for (int j = 0; j < 4; ++j) {
        int row = r0 + j;
        if (row >= N_NODES) continue;
        float v = acc[mt][nt][j];
        if (gc < NL) {
          if (gc < C) xlh[(size_t)row * CSg + gc] = (_Float16)(v + biasl[gc]);
        } else {
          int c2 = gc - NL;
          if (c2 >= 0 && c2 < C) xrh[(size_t)row * CSg + c2] = (_Float16)(v + biasr[c2]);
        }
      }
    }
  }
}

// ---------------- CSR build (once per launch) ---------------------------
__global__ void zero_ints(int* __restrict__ p, int n) {
  int i = blockIdx.x * blockDim.x + threadIdx.x;
  if (i < n) p[i] = 0;
}

__global__ void deg_count(const int* __restrict__ ei, int* __restrict__ deg) {
  int e = blockIdx.x * blockDim.x + threadIdx.x;
  if (e >= E_TOT) return;
  int d = (e < N_EDGES) ? ei[N_EDGES + e] : e - N_EDGES;
  atomicAdd(&deg[d], 1);
}

__global__ void scan1(const int* __restrict__ deg, int* __restrict__ rp,
                      int* __restrict__ bsum) {
  __shared__ int s[256];
  int i = blockIdx.x * 256 + threadIdx.x;
  int v = (i < N_NODES) ? deg[i] : 0;
  s[threadIdx.x] = v;
  __syncthreads();
  for (int off = 1; off < 256; off <<= 1) {
    int t = (threadIdx.x >= off) ? s[threadIdx.x - off] : 0;
    __syncthreads();
    s[threadIdx.x] += t;
    __syncthreads();
  }
  if (i < N_NODES) rp[i] = s[threadIdx.x] - v;
  if (threadIdx.x == 255) bsum[blockIdx.x] = s[255];
}

__global__ void scan2(int* __restrict__ bsum) {
  __shared__ int s[256];
  int v = (threadIdx.x < NB_SCAN) ? bsum[threadIdx.x] : 0;
  s[threadIdx.x] = v;
  __syncthreads();
  for (int off = 1; off < 256; off <<= 1) {
    int t = (threadIdx.x >= off) ? s[threadIdx.x - off] : 0;
    __syncthreads();
    s[threadIdx.x] += t;
    __syncthreads();
  }
  if (threadIdx.x < NB_SCAN) bsum[threadIdx.x] = s[threadIdx.x] - v;
}

__global__ void scan3(int* __restrict__ rp, const int* __restrict__ bsum,
                      int* __restrict__ cursor) {
  int i = blockIdx.x * 256 + threadIdx.x;
  if (i < N_NODES) {
    int v = rp[i] + bsum[blockIdx.x];
    rp[i] = v;
    cursor[i] = v;
  }
  if (i == 0) rp[N_NODES] = E_TOT;
}

__global__ void fill_csr(const int* __restrict__ ei, int* __restrict__ cursor,
                         int* __restrict__ csr_src) {
  int e = blockIdx.x * blockDim.x + threadIdx.x;
  if (e >= E_TOT) return;
  int s, d;
  if (e < N_EDGES) { s = ei[e]; d = ei[N_EDGES + e]; }
  else             { s = d = e - N_EDGES; }
  int pos = atomicAdd(&cursor[d], 1);
  csr_src[pos] = s;
}

// ---- row loader: ND f16x2 regs from a (8B-aligned) fp16 row slice ----------
template <int ND>
__device__ __forceinline__ void load_row(f16x2* dst, const _Float16* p) {
  if constexpr (ND == 4) {
    f16x8 t = *(const f16x8*)p;   // 16B aligned for CS=128 layout
#pragma unroll
    for (int j = 0; j < 4; ++j) {
      f16x2 r; r[0] = t[2 * j]; r[1] = t[2 * j + 1]; dst[j] = r;
    }
  } else {
#pragma unroll
    for (int q = 0; q < ND / 2; ++q) {
      f16x4 t = *(const f16x4*)(p + 4 * q);   // 8B aligned
      f16x2 a; a[0] = t[0]; a[1] = t[1]; dst[2 * q] = a;
      f16x2 b; b[0] = t[2]; b[1] = t[3]; dst[2 * q + 1] = b;
    }
  }
}

// -------- fused GATv2 aggregation v4: 16 lanes/edge, 4 edges in flight,
// deferred-max softmax (no online rescale), packed-f16 math ----------------
template <int C, int CS, int NCH, int OUTB>
__global__ __launch_bounds__(256) void gat_fused4(
    const int* __restrict__ rowptr, const int* __restrict__ csr_src,
    const _Float16* __restrict__ xlh, const _Float16* __restrict__ xrh,
    const f16x2* __restrict__ att_h, const float* __restrict__ bias,
    float* __restrict__ hout, u16* __restrict__ Hh, u16* __restrict__ Hl) {
  constexpr int ND = NCH / 2;
  int wid = (int)((blockIdx.x * (size_t)blockDim.x + threadIdx.x) >> 6);
  int lane = threadIdx.x & 63;
  if (wid >= N_NODES) return;
  const int g = lane >> 4, li = lane & 15;
  const int c0 = li * NCH;
  int beg = rowptr[wid], end = rowptr[wid + 1];

  f16x2 xri[ND], attc[ND];
  load_row<ND>(xri, xrh + (size_t)wid * CS + c0);
#pragma unroll
  for (int j = 0; j < ND; ++j) attc[j] = att_h[(c0 >> 1) + j];

  float acc[NCH];
#pragma unroll
  for (int k = 0; k < NCH; ++k) acc[k] = 0.f;
  float dsum = 0.f;
  const f16x2 slope2 = {(_Float16)SLOPE, (_Float16)SLOPE};
  const f16x2 zero2 = {(_Float16)0.f, (_Float16)0.f};

  int e = beg + g;
  f16x2 nxt[ND];
  {
    int s = csr_src[e < end ? e : end - 1];
    load_row<ND>(nxt, xlh + (size_t)s * CS + c0);
  }
  int nit = (end - beg + 3) >> 2;
  for (int it = 0; it < nit; ++it) {
    f16x2 cur[ND];
#pragma unroll
    for (int j = 0; j < ND; ++j) cur[j] = nxt[j];
    bool valid = e < end;
    if (beg + (it + 1) * 4 < end) {        // wave-uniform
      int en = e + 4;
      int s = csr_src[en < end ? en : end - 1];
      load_row<ND>(nxt, xlh + (size_t)s * CS + c0);
    }
    float v = 0.f;
#pragma unroll
    for (int j = 0; j < ND; ++j) {
      f16x2 m2 = cur[j] + xri[j];
      f16x2 mx = __builtin_elementwise_max(m2, zero2);
      f16x2 mn = __builtin_elementwise_min(m2, zero2);
      f16x2 lr = mx + slope2 * mn;         // leaky_relu
#if __has_builtin(__builtin_amdgcn_fdot2)
      v = __builtin_amdgcn_fdot2(lr, attc[j], v, false);
#else
      v += (float)lr[0] * (float)attc[j][0] + (float)lr[1] * (float)attc[j][1];
#endif
    }
    v += __shfl_xor(v, 1);
    v += __shfl_xor(v, 2);
    v += __shfl_xor(v, 4);
    v += __shfl_xor(v, 8);
    float w = valid ? __expf(v) : 0.f;     // deferred max: |v| small, fp32-safe
    dsum += w;
#pragma unroll
    for (int j = 0; j < ND; ++j) {
      acc[2 * j]     += w * (float)cur[j][0];   // v_fma_mix
      acc[2 * j + 1] += w * (float)cur[j][1];
    }
    e += 4;
  }
  // merge the 4 edge-groups (channel map identical across groups)
#pragma unroll
  for (int k = 0; k < NCH; ++k) {
    acc[k] += __shfl_xor(acc[k], 16);
    acc[k] += __shfl_xor(acc[k], 32);
  }
  dsum += __shfl_xor(dsum, 16);
  dsum += __shfl_xor(dsum, 32);
  if (g != 0) return;
  float inv = 1.f / dsum;
  if (OUTB) {
    s16x8 hv, lv;
#pragma unroll
    for (int k = 0; k < 8; ++k) {
      float vv = fmaxf(acc[k] * inv + bias[c0 + k], 0.f);
      u16 hb = f2bf(vv);
      hv[k] = (short)hb;
      lv[k] = (short)f2bf(vv - bf2f(hb));
    }
    int p = wid >> 6, mrow = wid & 63;
    size_t ce = (((size_t)p * 16 + li) * 64 + mrow) * 8;
    *(s16x8*)&Hh[ce] = hv;
    *(s16x8*)&Hl[ce] = lv;
  } else {
#pragma unroll
    for (int k = 0; k < NCH; ++k) {
      int c = c0 + k;
      if (c < C) hout[(size_t)wid * C + c] = fmaxf(acc[k] * inv + bias[c], 0.f);
    }
  }
}

// ------------- global mean pool (batch sorted), split + unrolled --------
__device__ int lower_bound_dev(const int* a, int n, int v) {
  int lo = 0, hi = n;
  while (lo < hi) { int mid = (lo + hi) >> 1; if (a[mid] < v) lo = mid + 1; else hi = mid; }
  return lo;
}

__global__ void pool_sum(const float* __restrict__ h, const int* __restrict__ batch,
                         float* __restrict__ gsum) {
  int gi = blockIdx.x;
  int sp = blockIdx.y;
  int c = threadIdx.x;
  if (c >= 300) return;
  int start = lower_bound_dev(batch, N_NODES, gi);
  int end   = lower_bound_dev(batch, N_NODES, gi + 1);
  int len = end - start;
  int chunk = (len + POOL_SPLIT - 1) / POOL_SPLIT;
  int a = start + sp * chunk;
  int b = a + chunk; if (b > end) b = end;
  if (a >= b) return;
  float s0 = 0.f, s1 = 0.f, s2 = 0.f, s3 = 0.f;
  int n = a;
  for (; n + 3 < b; n += 4) {
    s0 += h[(size_t)n * 300 + c];
    s1 += h[(size_t)(n + 1) * 300 + c];
    s2 += h[(size_t)(n + 2) * 300 + c];
    s3 += h[(size_t)(n + 3) * 300 + c];
  }
  for (; n < b; ++n) s0 += h[(size_t)n * 300 + c];
  atomicAdd(&gsum[(size_t)gi * 300 + c], (s0 + s1) + (s2 + s3));
}

__global__ void pool_final(float* __restrict__ gsum, const int* __restrict__ batch) {
  int t = blockIdx.x * blockDim.x + threadIdx.x;
  if (t >= N_GRAPHS * 300) return;
  int gi = t / 300;
  int start = lower_bound_dev(batch, N_NODES, gi);
  int end   = lower_bound_dev(batch, N_NODES, gi + 1);
  int cnt = end - start;
  gsum[t] = gsum[t] / (float)(cnt > 0 ? cnt : 1);
}

// ------------- small per-graph FC ---------------------------------------
__global__ void fc_kernel(const float* __restrict__ g, const float* __restrict__ W,
                          const float* __restrict__ b, float* __restrict__ out,
                          int K, int N, int do_relu) {
  __shared__ float row[304];
  int gi = blockIdx.x;
  for (int k = threadIdx.x; k < K; k += blockDim.x) row[k] = g[(size_t)gi * K + k];
  __syncthreads();
  int c = threadIdx.x;
  if (c >= N) return;
  float s = b[c];
  for (int k = 0; k < K; ++k) s += row[k] * W[(size_t)k * N + c];
  if (do_relu) s = fmaxf(s, 0.f);
  out[(size_t)gi * N + c] = s;
}

extern "C" void kernel_launch(void* const* d_in, const int* in_sizes, int n_in,
                              void* d_out, int out_size, void* d_ws, size_t ws_size,
                              hipStream_t stream) {
  const float* x     = (const float*)d_in[0];
  const int*   ei    = (const int*)d_in[1];
  const int*   batch = (const int*)d_in[2];
  const float* Wl[4], *bl[4], *Wr[4], *br[4], *att[4], *bias[4];
  for (int l = 0; l < 4; ++l) {
    Wl[l]   = (const float*)d_in[3 + l * 6 + 0];
    bl[l]   = (const float*)d_in[3 + l * 6 + 1];
    Wr[l]   = (const float*)d_in[3 + l * 6 + 2];
    br[l]   = (const float*)d_in[3 + l * 6 + 3];
    att[l]  = (const float*)d_in[3 + l * 6 + 4];
    bias[l] = (const float*)d_in[3 + l * 6 + 5];
  }
  const float* fc1_W = (const float*)d_in[27];
  const float* fc1_b = (const float*)d_in[28];
  const float* fc2_W = (const float*)d_in[29];
  const float* fc2_b = (const float*)d_in[30];

  char* wsb = (char*)d_ws;
  size_t off = 0;
  auto alloc = [&](size_t bytes) {
    void* p = (void*)(wsb + off);
    off += (bytes + 63) & ~(size_t)63;
    return p;
  };
  // fp16 xl/xr, stride up to 320 (layer 3); layers 0-2 use stride 128
  _Float16* xlh = (_Float16*)alloc((size_t)N_NODES * 320 * 2);
  _Float16* xrh = (_Float16*)alloc((size_t)N_NODES * 320 * 2);
  // A0 panels; aliased by H panels (after layer-0 gemm) and hbuf (after layer-3 gemm)
  u16* A0h = (u16*)alloc((size_t)NPANEL * 40 * 512 * 2);
  u16* A0l = (u16*)alloc((size_t)NPANEL * 40 * 512 * 2);
  u16* Hh = A0h;
  u16* Hl = A0l;
  float* hbuf = (float*)A0h;
  float* gpool = (float*)alloc((size_t)N_GRAPHS * 300 * 4);
  float* g1    = (float*)alloc((size_t)N_GRAPHS * 300 * 4);
  f16x2* att_h = (f16x2*)alloc((size_t)4 * 192 * 4);
  const int Kact[4] = {300, 128, 128, 128};
  const int Cdim[4] = {128, 128, 128, 300};
  const int NLv[4]  = {128, 128, 128, 304};
  const int Kpv[4]  = {320, 128, 128, 128};
  const int CSg[4]  = {128, 128, 128, 320};
  u16* Wh[4], *Wlo[4];
  for (int l = 0; l < 4; ++l) {
    int kcn = Kpv[l] >> 3;
    Wh[l]  = (u16*)alloc((size_t)kcn * WCOLS * 8 * 2);
    Wlo[l] = (u16*)alloc((size_t)kcn * WCOLS * 8 * 2);
  }
  int* deg     = (int*)alloc((size_t)N_NODES * 4);
  int* rowptr  = (int*)alloc((size_t)(N_NODES + 1) * 4);
  int* bsum    = (int*)alloc(256 * 4);
  int* cursor  = (int*)alloc((size_t)N_NODES * 4);
  int* csr_src = (int*)alloc((size_t)E_TOT * 4);

  // one-time conversions
  conv_x<<<(NPANEL * 64 * 40 + 255) / 256, 256, 0, stream>>>(x, A0h, A0l);
  for (int l = 0; l < 4; ++l) {
    int kcn = Kpv[l] >> 3;
    conv_w<<<(kcn * WCOLS + 255) / 256, 256, 0, stream>>>(
        Wl[l], Wr[l], Wh[l], Wlo[l], Kact[l], Cdim[l], NLv[l], kcn);
  }
  conv_att<<<3, 256, 0, stream>>>(att[0], att[1], att[2], att[3], att_h);

  // CSR build
  zero_ints<<<(N_NODES + 255) / 256, 256, 0, stream>>>(deg, N_NODES);
  deg_count<<<(E_TOT + 255) / 256, 256, 0, stream>>>(ei, deg);
  scan1<<<NB_SCAN, 256, 0, stream>>>(deg, rowptr, bsum);
  scan2<<<1, 256, 0, stream>>>(bsum);
  scan3<<<NB_SCAN, 256, 0, stream>>>(rowptr, bsum, cursor);
  fill_csr<<<(E_TOT + 255) / 256, 256, 0, stream>>>(ei, cursor, csr_src);
  // zero the pool accumulator early (fp32 zero == all-zero bits)
  zero_ints<<<(N_GRAPHS * 300 + 255) / 256, 256, 0, stream>>>((int*)gpool, N_GRAPHS * 300);

  const int nwave_blocks = (N_NODES + 3) / 4;
  for (int l = 0; l < 4; ++l) {
    const u16* Ahs = (l == 0) ? A0h : Hh;
    const u16* Als = (l == 0) ? A0l : Hl;
    int ny = (2 * NLv[l] + 255) / 256;
    dim3 gg(NPANEL, ny);
    gemm_dual<<<gg, 256, 0, stream>>>(Ahs, Als, Wh[l], Wlo[l], bl[l], br[l],
                                      xlh, xrh, Kpv[l], Cdim[l], NLv[l], CSg[l]);
    if (l == 0) {
      zero_pad_H<<<3, 256, 0, stream>>>(Hh, Hl);
    }
    if (l < 3) {
      gat_fused4<128, 128, 8, 1><<<nwave_blocks, 256, 0, stream>>>(
          rowptr, csr_src, xlh, xrh, att_h + l * 192, bias[l], nullptr, Hh, Hl);
    } else {
      // zero stale cols 300..319 of stride-320 rows (never written by gemm)
      zero_xl_pad<<<(N_NODES * 20 + 255) / 256, 256, 0, stream>>>(xlh, xrh);
      gat_fused4<300, 320, 20, 0><<<nwave_blocks, 256, 0, stream>>>(
          rowptr, csr_src, xlh, xrh, att_h + l * 192, bias[l], hbuf, nullptr, nullptr);
    }
  }
  {
    dim3 pg(N_GRAPHS, POOL_SPLIT);
    pool_sum<<<pg, 320, 0, stream>>>(hbuf, batch, gpool);
    pool_final<<<(N_GRAPHS * 300 + 255) / 256, 256, 0, stream>>>(gpool, batch);
  }
  fc_kernel<<<N_GRAPHS, 320, 0, stream>>>(gpool, fc1_W, fc1_b, g1, 300, 300, 1);
  fc_kernel<<<N_GRAPHS, 768, 0, stream>>>(g1, fc2_W, fc2_b, (float*)d_out, 300, 768, 0);
}

// Round 9
// 596.272 us; speedup vs baseline: 1.7805x; 1.0842x over previous
//
#include <hip/hip_runtime.h>
#include <hip/hip_bf16.h>
#include <math.h>

#define N_NODES 50000
#define N_EDGES 800000
#define E_TOT   (N_EDGES + N_NODES)
#define N_GRAPHS 256
#define SLOPE 0.2f
#define NB_SCAN ((N_NODES + 255) / 256)
#define NPANEL 782            // ceil(50000/64)
#define WCOLS 768             // padded concatenated-W width
#define POOL_SPLIT 8

typedef __attribute__((ext_vector_type(4))) float f32x4;
typedef _Float16 f16x2 __attribute__((ext_vector_type(2)));
typedef _Float16 f16x4 __attribute__((ext_vector_type(4)));
typedef _Float16 f16x8 __attribute__((ext_vector_type(8)));

__device__ __forceinline__ void gl_lds16(const void* g, void* l) {
  __builtin_amdgcn_global_load_lds(
      (const __attribute__((address_space(1))) unsigned int*)g,
      (__attribute__((address_space(3))) unsigned int*)l, 16, 0, 0);
}

// ---- x -> panel-swizzled fp16 [p][kc=40][m=64][ki=8], zero-padded ----------
__global__ void conv_x(const float* __restrict__ x, _Float16* __restrict__ A) {
  int id = blockIdx.x * blockDim.x + threadIdx.x;
  const int total = NPANEL * 64 * 40;
  if (id >= total) return;
  int kc = id % 40;
  int m  = (id / 40) % 64;
  int p  = id / 2560;
  int n = p * 64 + m;
  f16x8 hv;
#pragma unroll
  for (int i = 0; i < 8; ++i) {
    int k = kc * 8 + i;
    float v = (n < N_NODES && k < 300) ? x[(size_t)n * 300 + k] : 0.f;
    hv[i] = (_Float16)v;
  }
  size_t ce = (((size_t)p * 40 + kc) * 64 + m) * 8;
  *(f16x8*)&A[ce] = hv;
}

// ---- Wl,Wr -> concatenated padded fp16 [kc][WCOLS][8] ----------------------
__global__ void conv_w(const float* __restrict__ Wl, const float* __restrict__ Wr,
                       _Float16* __restrict__ W, int K, int C, int NL, int kcn) {
  int id = blockIdx.x * blockDim.x + threadIdx.x;
  if (id >= kcn * WCOLS) return;
  int n = id % WCOLS, kc = id / WCOLS;
  f16x8 hv;
#pragma unroll
  for (int i = 0; i < 8; ++i) {
    int k = kc * 8 + i;
    float v = 0.f;
    if (k < K) {
      if (n < NL) { if (n < C) v = Wl[(size_t)k * C + n]; }
      else if (n < 2 * NL && (n - NL) < C) v = Wr[(size_t)k * C + (n - NL)];
    }
    hv[i] = (_Float16)v;
  }
  *(f16x8*)&W[(size_t)id * 8] = hv;
}

// ---- att (fp32) -> padded f16x2 tables, 192 entries per layer --------------
__global__ void conv_att(const float* __restrict__ a0, const float* __restrict__ a1,
                         const float* __restrict__ a2, const float* __restrict__ a3,
                         f16x2* __restrict__ att_h) {
  int t = blockIdx.x * blockDim.x + threadIdx.x;
  if (t >= 4 * 192) return;
  int l = t / 192, i = t % 192;
  const float* a = (l == 0) ? a0 : (l == 1) ? a1 : (l == 2) ? a2 : a3;
  int C = (l == 3) ? 300 : 128;
  int c = 2 * i;
  f16x2 r;
  r[0] = (c < C) ? (_Float16)a[c] : (_Float16)0.f;
  r[1] = (c + 1 < C) ? (_Float16)a[c + 1] : (_Float16)0.f;
  att_h[t] = r;
}

// ---- zero pad rows 50000..50047 of H panels (kcn=16) -----------------------
__global__ void zero_pad_H(_Float16* __restrict__ H) {
  int t = blockIdx.x * blockDim.x + threadIdx.x;
  if (t >= 48 * 16) return;
  int m = 16 + (t >> 4), kc = t & 15;
  size_t ce = (((size_t)781 * 16 + kc) * 64 + m) * 8;
  f16x8 z = {};
  *(f16x8*)&H[ce] = z;
}

// ---- zero stale cols 300..319 of the stride-320 layer-3 xl/xr buffers ------
__global__ void zero_xl_pad(_Float16* __restrict__ xlh, _Float16* __restrict__ xrh) {
  int t = blockIdx.x * blockDim.x + threadIdx.x;
  if (t >= N_NODES * 20) return;
  int r = t / 20, k = t % 20;
  size_t o = (size_t)r * 320 + 300 + k;
  xlh[o] = (_Float16)0.f;
  xrh[o] = (_Float16)0.f;
}

// ---- dual-output fp16 MFMA GEMM: [xl|xr] = A @ [Wl|Wr] + bias --------------
__global__ __launch_bounds__(256, 2) void gemm_dual(
    const _Float16* __restrict__ A, const _Float16* __restrict__ W,
    const float* __restrict__ biasl, const float* __restrict__ biasr,
    _Float16* __restrict__ xlh, _Float16* __restrict__ xrh,
    int Kp, int C, int NL, int CSg) {
  __shared__ _Float16 As[4][64][8];     // 4 KB
  __shared__ _Float16 Ws[4][256][8];    // 16 KB
  const int tid = threadIdx.x, wv = tid >> 6, lane = tid & 63;
  const int p = blockIdx.x, n0 = blockIdx.y * 256;
  const int kcn = Kp >> 3, nk = Kp >> 5;
  const size_t abase0 = (size_t)p * kcn * 512;
  const int rsel = lane >> 4, rrow = lane & 15;
  f32x4 z4 = {0.f, 0.f, 0.f, 0.f};
  f32x4 acc[4][4];
#pragma unroll
  for (int a = 0; a < 4; ++a)
#pragma unroll
    for (int b = 0; b < 4; ++b) acc[a][b] = z4;

  for (int s = 0; s < nk; ++s) {
    const size_t abase = abase0 + (size_t)s * 2048;
    for (int q = wv; q < 20; q += 4) {
      const _Float16* g;
      _Float16* l;
      if (q < 4) {
        g = A + abase + q * 512;
        l = &As[0][0][0] + q * 512;
      } else {
        int j = q - 4;                 // 0..15: row j>>2, col-block j&3
        g = W + ((size_t)(s * 4 + (j >> 2)) * WCOLS + n0 + (j & 3) * 64) * 8;
        l = &Ws[0][0][0] + j * 512;
      }
      gl_lds16(g + lane * 8, l);
    }
    __syncthreads();
    f16x8 af[4], bf[4];
#pragma unroll
    for (int mt = 0; mt < 4; ++mt)
      af[mt] = *(const f16x8*)&As[rsel][mt * 16 + rrow][0];
#pragma unroll
    for (int nt = 0; nt < 4; ++nt)
      bf[nt] = *(const f16x8*)&Ws[rsel][wv * 64 + nt * 16 + rrow][0];
#pragma unroll
    for (int mt = 0; mt < 4; ++mt)
#pragma unroll
      for (int nt = 0; nt < 4; ++nt)
        acc[mt][nt] = __builtin_amdgcn_mfma_f32_16x16x32_f16(af[mt], bf[nt], acc[mt][nt], 0, 0, 0);
    __syncthreads();
  }
#pragma unroll
  for (int mt = 0; mt < 4; ++mt) {
    int r0 = p * 64 + mt * 16 + rsel * 4;
#pragma unroll
    for (int nt = 0; nt < 4; ++nt) {
      int gc = n0 + wv * 64 + nt * 16 + rrow;
#pragma unroll
      for (int j = 0; j < 4; ++j) {
        int row = r0 + j;
        if (row >= N_NODES) continue;
        float v = acc[mt][nt][j];
        if (gc < NL) {
          if (gc < C) xlh[(size_t)row * CSg + gc] = (_Float16)(v + biasl[gc]);
        } else {
          int c2 = gc - NL;
          if (c2 >= 0 && c2 < C) xrh[(size_t)row * CSg + c2] = (_Float16)(v + biasr[c2]);
        }
      }
    }
  }
}

// ---------------- CSR build (once per launch) ---------------------------
__global__ void zero_ints(int* __restrict__ p, int n) {
  int i = blockIdx.x * blockDim.x + threadIdx.x;
  if (i < n) p[i] = 0;
}

__global__ void deg_count(const int* __restrict__ ei, int* __restrict__ deg) {
  int e = blockIdx.x * blockDim.x + threadIdx.x;
  if (e >= E_TOT) return;
  int d = (e < N_EDGES) ? ei[N_EDGES + e] : e - N_EDGES;
  atomicAdd(&deg[d], 1);
}

__global__ void scan1(const int* __restrict__ deg, int* __restrict__ rp,
                      int* __restrict__ bsum) {
  __shared__ int s[256];
  int i = blockIdx.x * 256 + threadIdx.x;
  int v = (i < N_NODES) ? deg[i] : 0;
  s[threadIdx.x] = v;
  __syncthreads();
  for (int off = 1; off < 256; off <<= 1) {
    int t = (threadIdx.x >= off) ? s[threadIdx.x - off] : 0;
    __syncthreads();
    s[threadIdx.x] += t;
    __syncthreads();
  }
  if (i < N_NODES) rp[i] = s[threadIdx.x] - v;
  if (threadIdx.x == 255) bsum[blockIdx.x] = s[255];
}

__global__ void scan2(int* __restrict__ bsum) {
  __shared__ int s[256];
  int v = (threadIdx.x < NB_SCAN) ? bsum[threadIdx.x] : 0;
  s[threadIdx.x] = v;
  __syncthreads();
  for (int off = 1; off < 256; off <<= 1) {
    int t = (threadIdx.x >= off) ? s[threadIdx.x - off] : 0;
    __syncthreads();
    s[threadIdx.x] += t;
    __syncthreads();
  }
  if (threadIdx.x < NB_SCAN) bsum[threadIdx.x] = s[threadIdx.x] - v;
}

__global__ void scan3(int* __restrict__ rp, const int* __restrict__ bsum,
                      int* __restrict__ cursor) {
  int i = blockIdx.x * 256 + threadIdx.x;
  if (i < N_NODES) {
    int v = rp[i] + bsum[blockIdx.x];
    rp[i] = v;
    cursor[i] = v;
  }
  if (i == 0) rp[N_NODES] = E_TOT;
}

__global__ void fill_csr(const int* __restrict__ ei, int* __restrict__ cursor,
                         int* __restrict__ csr_src) {
  int e = blockIdx.x * blockDim.x + threadIdx.x;
  if (e >= E_TOT) return;
  int s, d;
  if (e < N_EDGES) { s = ei[e]; d = ei[N_EDGES + e]; }
  else             { s = d = e - N_EDGES; }
  int pos = atomicAdd(&cursor[d], 1);
  csr_src[pos] = s;
}

// ---- row loader: ND f16x2 regs from a (8B-aligned) fp16 row slice ----------
template <int ND>
__device__ __forceinline__ void load_row(f16x2* dst, const _Float16* p) {
  if constexpr (ND == 4) {
    f16x8 t = *(const f16x8*)p;   // 16B aligned for CS=128 layout
#pragma unroll
    for (int j = 0; j < 4; ++j) {
      f16x2 r; r[0] = t[2 * j]; r[1] = t[2 * j + 1]; dst[j] = r;
    }
  } else {
#pragma unroll
    for (int q = 0; q < ND / 2; ++q) {
      f16x4 t = *(const f16x4*)(p + 4 * q);   // 8B aligned
      f16x2 a; a[0] = t[0]; a[1] = t[1]; dst[2 * q] = a;
      f16x2 b; b[0] = t[2]; b[1] = t[3]; dst[2 * q + 1] = b;
    }
  }
}

// -------- fused GATv2 aggregation v4: 16 lanes/edge, 4 edges in flight,
// deferred-max softmax (no online rescale), packed-f16 math ----------------
template <int C, int CS, int NCH, int OUTB>
__global__ __launch_bounds__(256) void gat_fused4(
    const int* __restrict__ rowptr, const int* __restrict__ csr_src,
    const _Float16* __restrict__ xlh, const _Float16* __restrict__ xrh,
    const f16x2* __restrict__ att_h, const float* __restrict__ bias,
    float* __restrict__ hout, _Float16* __restrict__ Hp) {
  constexpr int ND = NCH / 2;
  int wid = (int)((blockIdx.x * (size_t)blockDim.x + threadIdx.x) >> 6);
  int lane = threadIdx.x & 63;
  if (wid >= N_NODES) return;
  const int g = lane >> 4, li = lane & 15;
  const int c0 = li * NCH;
  int beg = rowptr[wid], end = rowptr[wid + 1];

  f16x2 xri[ND], attc[ND];
  load_row<ND>(xri, xrh + (size_t)wid * CS + c0);
#pragma unroll
  for (int j = 0; j < ND; ++j) attc[j] = att_h[(c0 >> 1) + j];

  float acc[NCH];
#pragma unroll
  for (int k = 0; k < NCH; ++k) acc[k] = 0.f;
  float dsum = 0.f;
  const f16x2 slope2 = {(_Float16)SLOPE, (_Float16)SLOPE};
  const f16x2 zero2 = {(_Float16)0.f, (_Float16)0.f};

  int e = beg + g;
  f16x2 nxt[ND];
  {
    int s = csr_src[e < end ? e : end - 1];
    load_row<ND>(nxt, xlh + (size_t)s * CS + c0);
  }
  int nit = (end - beg + 3) >> 2;
  for (int it = 0; it < nit; ++it) {
    f16x2 cur[ND];
#pragma unroll
    for (int j = 0; j < ND; ++j) cur[j] = nxt[j];
    bool valid = e < end;
    if (beg + (it + 1) * 4 < end) {        // wave-uniform
      int en = e + 4;
      int s = csr_src[en < end ? en : end - 1];
      load_row<ND>(nxt, xlh + (size_t)s * CS + c0);
    }
    float v = 0.f;
#pragma unroll
    for (int j = 0; j < ND; ++j) {
      f16x2 m2 = cur[j] + xri[j];
      f16x2 mx = __builtin_elementwise_max(m2, zero2);
      f16x2 mn = __builtin_elementwise_min(m2, zero2);
      f16x2 lr = mx + slope2 * mn;         // leaky_relu
#if __has_builtin(__builtin_amdgcn_fdot2)
      v = __builtin_amdgcn_fdot2(lr, attc[j], v, false);
#else
      v += (float)lr[0] * (float)attc[j][0] + (float)lr[1] * (float)attc[j][1];
#endif
    }
    v += __shfl_xor(v, 1);
    v += __shfl_xor(v, 2);
    v += __shfl_xor(v, 4);
    v += __shfl_xor(v, 8);
    float w = valid ? __expf(v) : 0.f;     // deferred max: |v| small, fp32-safe
    dsum += w;
#pragma unroll
    for (int j = 0; j < ND; ++j) {
      acc[2 * j]     += w * (float)cur[j][0];   // v_fma_mix
      acc[2 * j + 1] += w * (float)cur[j][1];
    }
    e += 4;
  }
  // merge the 4 edge-groups (channel map identical across groups)
#pragma unroll
  for (int k = 0; k < NCH; ++k) {
    acc[k] += __shfl_xor(acc[k], 16);
    acc[k] += __shfl_xor(acc[k], 32);
  }
  dsum += __shfl_xor(dsum, 16);
  dsum += __shfl_xor(dsum, 32);
  if (g != 0) return;
  float inv = 1.f / dsum;
  if (OUTB) {
    f16x8 hv;
#pragma unroll
    for (int k = 0; k < 8; ++k) {
      float vv = fmaxf(acc[k] * inv + bias[c0 + k], 0.f);
      hv[k] = (_Float16)vv;
    }
    int p = wid >> 6, mrow = wid & 63;
    size_t ce = (((size_t)p * 16 + li) * 64 + mrow) * 8;
    *(f16x8*)&Hp[ce] = hv;
  } else {
#pragma unroll
    for (int k = 0; k < NCH; ++k) {
      int c = c0 + k;
      if (c < C) hout[(size_t)wid * C + c] = fmaxf(acc[k] * inv + bias[c], 0.f);
    }
  }
}

// ------------- global mean pool (batch sorted), split + unrolled --------
__device__ int lower_bound_dev(const int* a, int n, int v) {
  int lo = 0, hi = n;
  while (lo < hi) { int mid = (lo + hi) >> 1; if (a[mid] < v) lo = mid + 1; else hi = mid; }
  return lo;
}

__global__ void pool_sum(const float* __restrict__ h, const int* __restrict__ batch,
                         float* __restrict__ gsum) {
  int gi = blockIdx.x;
  int sp = blockIdx.y;
  int c = threadIdx.x;
  if (c >= 300) return;
  int start = lower_bound_dev(batch, N_NODES, gi);
  int end   = lower_bound_dev(batch, N_NODES, gi + 1);
  int len = end - start;
  int chunk = (len + POOL_SPLIT - 1) / POOL_SPLIT;
  int a = start + sp * chunk;
  int b = a + chunk; if (b > end) b = end;
  if (a >= b) return;
  float s0 = 0.f, s1 = 0.f, s2 = 0.f, s3 = 0.f;
  int n = a;
  for (; n + 3 < b; n += 4) {
    s0 += h[(size_t)n * 300 + c];
    s1 += h[(size_t)(n + 1) * 300 + c];
    s2 += h[(size_t)(n + 2) * 300 + c];
    s3 += h[(size_t)(n + 3) * 300 + c];
  }
  for (; n < b; ++n) s0 += h[(size_t)n * 300 + c];
  atomicAdd(&gsum[(size_t)gi * 300 + c], (s0 + s1) + (s2 + s3));
}

__global__ void pool_final(float* __restrict__ gsum, const int* __restrict__ batch) {
  int t = blockIdx.x * blockDim.x + threadIdx.x;
  if (t >= N_GRAPHS * 300) return;
  int gi = t / 300;
  int start = lower_bound_dev(batch, N_NODES, gi);
  int end   = lower_bound_dev(batch, N_NODES, gi + 1);
  int cnt = end - start;
  gsum[t] = gsum[t] / (float)(cnt > 0 ? cnt : 1);
}

// ------------- small per-graph FC ---------------------------------------
__global__ void fc_kernel(const float* __restrict__ g, const float* __restrict__ W,
                          const float* __restrict__ b, float* __restrict__ out,
                          int K, int N, int do_relu) {
  __shared__ float row[304];
  int gi = blockIdx.x;
  for (int k = threadIdx.x; k < K; k += blockDim.x) row[k] = g[(size_t)gi * K + k];
  __syncthreads();
  int c = threadIdx.x;
  if (c >= N) return;
  float s = b[c];
  for (int k = 0; k < K; ++k) s += row[k] * W[(size_t)k * N + c];
  if (do_relu) s = fmaxf(s, 0.f);
  out[(size_t)gi * N + c] = s;
}

extern "C" void kernel_launch(void* const* d_in, const int* in_sizes, int n_in,
                              void* d_out, int out_size, void* d_ws, size_t ws_size,
                              hipStream_t stream) {
  const float* x     = (const float*)d_in[0];
  const int*   ei    = (const int*)d_in[1];
  const int*   batch = (const int*)d_in[2];
  const float* Wl[4], *bl[4], *Wr[4], *br[4], *att[4], *bias[4];
  for (int l = 0; l < 4; ++l) {
    Wl[l]   = (const float*)d_in[3 + l * 6 + 0];
    bl[l]   = (const float*)d_in[3 + l * 6 + 1];
    Wr[l]   = (const float*)d_in[3 + l * 6 + 2];
    br[l]   = (const float*)d_in[3 + l * 6 + 3];
    att[l]  = (const float*)d_in[3 + l * 6 + 4];
    bias[l] = (const float*)d_in[3 + l * 6 + 5];
  }
  const float* fc1_W = (const float*)d_in[27];
  const float* fc1_b = (const float*)d_in[28];
  const float* fc2_W = (const float*)d_in[29];
  const float* fc2_b = (const float*)d_in[30];

  char* wsb = (char*)d_ws;
  size_t off = 0;
  auto alloc = [&](size_t bytes) {
    void* p = (void*)(wsb + off);
    off += (bytes + 63) & ~(size_t)63;
    return p;
  };
  // fp16 xl/xr, stride up to 320 (layer 3); layers 0-2 use stride 128
  _Float16* xlh = (_Float16*)alloc((size_t)N_NODES * 320 * 2);
  _Float16* xrh = (_Float16*)alloc((size_t)N_NODES * 320 * 2);
  _Float16* A0  = (_Float16*)alloc((size_t)NPANEL * 40 * 512 * 2);  // 32 MB
  _Float16* Hp  = (_Float16*)alloc((size_t)NPANEL * 16 * 512 * 2);  // 12.8 MB
  float* hbuf   = (float*)alloc((size_t)N_NODES * 300 * 4);         // 60 MB
  float* gpool  = (float*)alloc((size_t)N_GRAPHS * 300 * 4);
  float* g1     = (float*)alloc((size_t)N_GRAPHS * 300 * 4);
  f16x2* att_h  = (f16x2*)alloc((size_t)4 * 192 * 4);
  const int Kact[4] = {300, 128, 128, 128};
  const int Cdim[4] = {128, 128, 128, 300};
  const int NLv[4]  = {128, 128, 128, 304};
  const int Kpv[4]  = {320, 128, 128, 128};
  const int CSg[4]  = {128, 128, 128, 320};
  _Float16* Wp[4];
  for (int l = 0; l < 4; ++l) {
    int kcn = Kpv[l] >> 3;
    Wp[l] = (_Float16*)alloc((size_t)kcn * WCOLS * 8 * 2);
  }
  int* deg     = (int*)alloc((size_t)N_NODES * 4);
  int* rowptr  = (int*)alloc((size_t)(N_NODES + 1) * 4);
  int* bsum    = (int*)alloc(256 * 4);
  int* cursor  = (int*)alloc((size_t)N_NODES * 4);
  int* csr_src = (int*)alloc((size_t)E_TOT * 4);

  // one-time conversions
  conv_x<<<(NPANEL * 64 * 40 + 255) / 256, 256, 0, stream>>>(x, A0);
  for (int l = 0; l < 4; ++l) {
    int kcn = Kpv[l] >> 3;
    conv_w<<<(kcn * WCOLS + 255) / 256, 256, 0, stream>>>(
        Wl[l], Wr[l], Wp[l], Kact[l], Cdim[l], NLv[l], kcn);
  }
  conv_att<<<3, 256, 0, stream>>>(att[0], att[1], att[2], att[3], att_h);
  zero_pad_H<<<3, 256, 0, stream>>>(Hp);

  // CSR build
  zero_ints<<<(N_NODES + 255) / 256, 256, 0, stream>>>(deg, N_NODES);
  deg_count<<<(E_TOT + 255) / 256, 256, 0, stream>>>(ei, deg);
  scan1<<<NB_SCAN, 256, 0, stream>>>(deg, rowptr, bsum);
  scan2<<<1, 256, 0, stream>>>(bsum);
  scan3<<<NB_SCAN, 256, 0, stream>>>(rowptr, bsum, cursor);
  fill_csr<<<(E_TOT + 255) / 256, 256, 0, stream>>>(ei, cursor, csr_src);
  // zero the pool accumulator early (fp32 zero == all-zero bits)
  zero_ints<<<(N_GRAPHS * 300 + 255) / 256, 256, 0, stream>>>((int*)gpool, N_GRAPHS * 300);

  const int nwave_blocks = (N_NODES + 3) / 4;
  for (int l = 0; l < 4; ++l) {
    const _Float16* Ain = (l == 0) ? A0 : Hp;
    int ny = (2 * NLv[l] + 255) / 256;
    dim3 gg(NPANEL, ny);
    gemm_dual<<<gg, 256, 0, stream>>>(Ain, Wp[l], bl[l], br[l],
                                      xlh, xrh, Kpv[l], Cdim[l], NLv[l], CSg[l]);
    if (l < 3) {
      gat_fused4<128, 128, 8, 1><<<nwave_blocks, 256, 0, stream>>>(
          rowptr, csr_src, xlh, xrh, att_h + l * 192, bias[l], nullptr, Hp);
    } else {
      // zero stale cols 300..319 of stride-320 rows (never written by gemm)
      zero_xl_pad<<<(N_NODES * 20 + 255) / 256, 256, 0, stream>>>(xlh, xrh);
      gat_fused4<300, 320, 20, 0><<<nwave_blocks, 256, 0, stream>>>(
          rowptr, csr_src, xlh, xrh, att_h + l * 192, bias[l], hbuf, nullptr);
    }
  }
  {
    dim3 pg(N_GRAPHS, POOL_SPLIT);
    pool_sum<<<pg, 320, 0, stream>>>(hbuf, batch, gpool);
    pool_final<<<(N_GRAPHS * 300 + 255) / 256, 256, 0, stream>>>(gpool, batch);
  }
  fc_kernel<<<N_GRAPHS, 320, 0, stream>>>(gpool, fc1_W, fc1_b, g1, 300, 300, 1);
  fc_kernel<<<N_GRAPHS, 768, 0, stream>>>(g1, fc2_W, fc2_b, (float*)d_out, 300, 768, 0);
}

// Round 10
// 587.816 us; speedup vs baseline: 1.8061x; 1.0144x over previous
//
#include <hip/hip_runtime.h>
#include <hip/hip_bf16.h>
#include <math.h>

#define N_NODES 50000
#define N_EDGES 800000
#define E_TOT   (N_EDGES + N_NODES)
#define N_GRAPHS 256
#define SLOPE 0.2f
#define NB_SCAN ((N_NODES + 255) / 256)
#define NPANEL 782            // ceil(50000/64)
#define WCOLS 768             // padded concatenated-W width
#define POOL_SPLIT 8
#define HSTRIDE 304           // fp16 h row stride (608B, 16B-aligned)

typedef __attribute__((ext_vector_type(4))) float f32x4;
typedef _Float16 f16x2 __attribute__((ext_vector_type(2)));
typedef _Float16 f16x4 __attribute__((ext_vector_type(4)));
typedef _Float16 f16x8 __attribute__((ext_vector_type(8)));

__device__ __forceinline__ void gl_lds16(const void* g, void* l) {
  __builtin_amdgcn_global_load_lds(
      (const __attribute__((address_space(1))) unsigned int*)g,
      (__attribute__((address_space(3))) unsigned int*)l, 16, 0, 0);
}

// ---- x -> panel-swizzled fp16 [p][kc=40][m=64][ki=8], zero-padded ----------
__global__ void conv_x(const float* __restrict__ x, _Float16* __restrict__ A) {
  int id = blockIdx.x * blockDim.x + threadIdx.x;
  const int total = NPANEL * 64 * 40;
  if (id >= total) return;
  int kc = id % 40;
  int m  = (id / 40) % 64;
  int p  = id / 2560;
  int n = p * 64 + m;
  f16x8 hv;
#pragma unroll
  for (int i = 0; i < 8; ++i) {
    int k = kc * 8 + i;
    float v = (n < N_NODES && k < 300) ? x[(size_t)n * 300 + k] : 0.f;
    hv[i] = (_Float16)v;
  }
  size_t ce = (((size_t)p * 40 + kc) * 64 + m) * 8;
  *(f16x8*)&A[ce] = hv;
}

// ---- Wl,Wr -> concatenated padded fp16 [kc][WCOLS][8] ----------------------
__global__ void conv_w(const float* __restrict__ Wl, const float* __restrict__ Wr,
                       _Float16* __restrict__ W, int K, int C, int NL, int kcn) {
  int id = blockIdx.x * blockDim.x + threadIdx.x;
  if (id >= kcn * WCOLS) return;
  int n = id % WCOLS, kc = id / WCOLS;
  f16x8 hv;
#pragma unroll
  for (int i = 0; i < 8; ++i) {
    int k = kc * 8 + i;
    float v = 0.f;
    if (k < K) {
      if (n < NL) { if (n < C) v = Wl[(size_t)k * C + n]; }
      else if (n < 2 * NL && (n - NL) < C) v = Wr[(size_t)k * C + (n - NL)];
    }
    hv[i] = (_Float16)v;
  }
  *(f16x8*)&W[(size_t)id * 8] = hv;
}

// ---- att (fp32) -> padded f16x2 tables, 192 entries per layer --------------
__global__ void conv_att(const float* __restrict__ a0, const float* __restrict__ a1,
                         const float* __restrict__ a2, const float* __restrict__ a3,
                         f16x2* __restrict__ att_h) {
  int t = blockIdx.x * blockDim.x + threadIdx.x;
  if (t >= 4 * 192) return;
  int l = t / 192, i = t % 192;
  const float* a = (l == 0) ? a0 : (l == 1) ? a1 : (l == 2) ? a2 : a3;
  int C = (l == 3) ? 300 : 128;
  int c = 2 * i;
  f16x2 r;
  r[0] = (c < C) ? (_Float16)a[c] : (_Float16)0.f;
  r[1] = (c + 1 < C) ? (_Float16)a[c + 1] : (_Float16)0.f;
  att_h[t] = r;
}

// ---- zero pad rows 50000..50047 of H panels (kcn=16) -----------------------
__global__ void zero_pad_H(_Float16* __restrict__ H) {
  int t = blockIdx.x * blockDim.x + threadIdx.x;
  if (t >= 48 * 16) return;
  int m = 16 + (t >> 4), kc = t & 15;
  size_t ce = (((size_t)781 * 16 + kc) * 64 + m) * 8;
  f16x8 z = {};
  *(f16x8*)&H[ce] = z;
}

// ---- zero stale cols 300..319 of the stride-320 layer-3 xl/xr buffers ------
__global__ void zero_xl_pad(_Float16* __restrict__ xlh, _Float16* __restrict__ xrh) {
  int t = blockIdx.x * blockDim.x + threadIdx.x;
  if (t >= N_NODES * 20) return;
  int r = t / 20, k = t % 20;
  size_t o = (size_t)r * 320 + 300 + k;
  xlh[o] = (_Float16)0.f;
  xrh[o] = (_Float16)0.f;
}

// ---- dual-output fp16 MFMA GEMM: [xl|xr] = A @ [Wl|Wr] + bias --------------
__global__ __launch_bounds__(256, 2) void gemm_dual(
    const _Float16* __restrict__ A, const _Float16* __restrict__ W,
    const float* __restrict__ biasl, const float* __restrict__ biasr,
    _Float16* __restrict__ xlh, _Float16* __restrict__ xrh,
    int Kp, int C, int NL, int CSg) {
  __shared__ _Float16 As[4][64][8];     // 4 KB
  __shared__ _Float16 Ws[4][256][8];    // 16 KB
  const int tid = threadIdx.x, wv = tid >> 6, lane = tid & 63;
  const int p = blockIdx.x, n0 = blockIdx.y * 256;
  const int kcn = Kp >> 3, nk = Kp >> 5;
  const size_t abase0 = (size_t)p * kcn * 512;
  const int rsel = lane >> 4, rrow = lane & 15;
  f32x4 z4 = {0.f, 0.f, 0.f, 0.f};
  f32x4 acc[4][4];
#pragma unroll
  for (int a = 0; a < 4; ++a)
#pragma unroll
    for (int b = 0; b < 4; ++b) acc[a][b] = z4;

  for (int s = 0; s < nk; ++s) {
    const size_t abase = abase0 + (size_t)s * 2048;
    for (int q = wv; q < 20; q += 4) {
      const _Float16* g;
      _Float16* l;
      if (q < 4) {
        g = A + abase + q * 512;
        l = &As[0][0][0] + q * 512;
      } else {
        int j = q - 4;                 // 0..15: row j>>2, col-block j&3
        g = W + ((size_t)(s * 4 + (j >> 2)) * WCOLS + n0 + (j & 3) * 64) * 8;
        l = &Ws[0][0][0] + j * 512;
      }
      gl_lds16(g + lane * 8, l);
    }
    __syncthreads();
    f16x8 af[4], bf[4];
#pragma unroll
    for (int mt = 0; mt < 4; ++mt)
      af[mt] = *(const f16x8*)&As[rsel][mt * 16 + rrow][0];
#pragma unroll
    for (int nt = 0; nt < 4; ++nt)
      bf[nt] = *(const f16x8*)&Ws[rsel][wv * 64 + nt * 16 + rrow][0];
#pragma unroll
    for (int mt = 0; mt < 4; ++mt)
#pragma unroll
      for (int nt = 0; nt < 4; ++nt)
        acc[mt][nt] = __builtin_amdgcn_mfma_f32_16x16x32_f16(af[mt], bf[nt], acc[mt][nt], 0, 0, 0);
    __syncthreads();
  }
#pragma unroll
  for (int mt = 0; mt < 4; ++mt) {
    int r0 = p * 64 + mt * 16 + rsel * 4;
#pragma unroll
    for (int nt = 0; nt < 4; ++nt) {
      int gc = n0 + wv * 64 + nt * 16 + rrow;
#pragma unroll
      for (int j = 0; j < 4; ++j) {
        int row = r0 + j;
        if (row >= N_NODES) continue;
        float v = acc[mt][nt][j];
        if (gc < NL) {
          if (gc < C) xlh[(size_t)row * CSg + gc] = (_Float16)(v + biasl[gc]);
        } else {
          int c2 = gc - NL;
          if (c2 >= 0 && c2 < C) xrh[(size_t)row * CSg + c2] = (_Float16)(v + biasr[c2]);
        }
      }
    }
  }
}

// ---------------- CSR build (once per launch) ---------------------------
__global__ void zero_ints(int* __restrict__ p, int n) {
  int i = blockIdx.x * blockDim.x + threadIdx.x;
  if (i < n) p[i] = 0;
}

__global__ void deg_count(const int* __restrict__ ei, int* __restrict__ deg) {
  int e = blockIdx.x * blockDim.x + threadIdx.x;
  if (e >= E_TOT) return;
  int d = (e < N_EDGES) ? ei[N_EDGES + e] : e - N_EDGES;
  atomicAdd(&deg[d], 1);
}

__global__ void scan1(const int* __restrict__ deg, int* __restrict__ rp,
                      int* __restrict__ bsum) {
  __shared__ int s[256];
  int i = blockIdx.x * 256 + threadIdx.x;
  int v = (i < N_NODES) ? deg[i] : 0;
  s[threadIdx.x] = v;
  __syncthreads();
  for (int off = 1; off < 256; off <<= 1) {
    int t = (threadIdx.x >= off) ? s[threadIdx.x - off] : 0;
    __syncthreads();
    s[threadIdx.x] += t;
    __syncthreads();
  }
  if (i < N_NODES) rp[i] = s[threadIdx.x] - v;
  if (threadIdx.x == 255) bsum[blockIdx.x] = s[255];
}

__global__ void scan2(int* __restrict__ bsum) {
  __shared__ int s[256];
  int v = (threadIdx.x < NB_SCAN) ? bsum[threadIdx.x] : 0;
  s[threadIdx.x] = v;
  __syncthreads();
  for (int off = 1; off < 256; off <<= 1) {
    int t = (threadIdx.x >= off) ? s[threadIdx.x - off] : 0;
    __syncthreads();
    s[threadIdx.x] += t;
    __syncthreads();
  }
  if (threadIdx.x < NB_SCAN) bsum[threadIdx.x] = s[threadIdx.x] - v;
}

__global__ void scan3(int* __restrict__ rp, const int* __restrict__ bsum,
                      int* __restrict__ cursor) {
  int i = blockIdx.x * 256 + threadIdx.x;
  if (i < N_NODES) {
    int v = rp[i] + bsum[blockIdx.x];
    rp[i] = v;
    cursor[i] = v;
  }
  if (i == 0) rp[N_NODES] = E_TOT;
}

__global__ void fill_csr(const int* __restrict__ ei, int* __restrict__ cursor,
                         int* __restrict__ csr_src) {
  int e = blockIdx.x * blockDim.x + threadIdx.x;
  if (e >= E_TOT) return;
  int s, d;
  if (e < N_EDGES) { s = ei[e]; d = ei[N_EDGES + e]; }
  else             { s = d = e - N_EDGES; }
  int pos = atomicAdd(&cursor[d], 1);
  csr_src[pos] = s;
}

// ---- row loader (C=128): one f16x8 per lane -------------------------------
__device__ __forceinline__ void load_row128(f16x2* dst, const _Float16* p) {
  f16x8 t = *(const f16x8*)p;
#pragma unroll
  for (int j = 0; j < 4; ++j) {
    f16x2 r; r[0] = t[2 * j]; r[1] = t[2 * j + 1]; dst[j] = r;
  }
}

// ---- row loader (C=300, chunked map): 16B+16B+8B per lane ------------------
// lane li covers channels [8li,8li+8) u [128+8li,+8) u [256+4li,+4)
__device__ __forceinline__ void load_row300(f16x2* dst, const _Float16* row, int li) {
  f16x8 a = *(const f16x8*)(row + 8 * li);
  f16x8 b = *(const f16x8*)(row + 128 + 8 * li);
  f16x4 c = *(const f16x4*)(row + 256 + 4 * li);
#pragma unroll
  for (int j = 0; j < 4; ++j) {
    f16x2 r; r[0] = a[2 * j]; r[1] = a[2 * j + 1]; dst[j] = r;
  }
#pragma unroll
  for (int j = 0; j < 4; ++j) {
    f16x2 r; r[0] = b[2 * j]; r[1] = b[2 * j + 1]; dst[4 + j] = r;
  }
  {
    f16x2 r; r[0] = c[0]; r[1] = c[1]; dst[8] = r;
    f16x2 r2; r2[0] = c[2]; r2[1] = c[3]; dst[9] = r2;
  }
}

// -------- fused GATv2 aggregation (C=128): 16 lanes/edge, 4 edges in flight,
// deferred-max softmax, fp16 H-panel output ---------------------------------
__global__ __launch_bounds__(256) void gat128(
    const int* __restrict__ rowptr, const int* __restrict__ csr_src,
    const _Float16* __restrict__ xlh, const _Float16* __restrict__ xrh,
    const f16x2* __restrict__ att_h, const float* __restrict__ bias,
    _Float16* __restrict__ Hp) {
  int wid = (int)((blockIdx.x * (size_t)blockDim.x + threadIdx.x) >> 6);
  int lane = threadIdx.x & 63;
  if (wid >= N_NODES) return;
  const int g = lane >> 4, li = lane & 15;
  const int c0 = li * 8;
  int beg = rowptr[wid], end = rowptr[wid + 1];

  f16x2 xri[4], attc[4];
  load_row128(xri, xrh + (size_t)wid * 128 + c0);
#pragma unroll
  for (int j = 0; j < 4; ++j) attc[j] = att_h[(c0 >> 1) + j];

  float acc[8];
#pragma unroll
  for (int k = 0; k < 8; ++k) acc[k] = 0.f;
  float dsum = 0.f;
  const f16x2 slope2 = {(_Float16)SLOPE, (_Float16)SLOPE};
  const f16x2 zero2 = {(_Float16)0.f, (_Float16)0.f};

  int e = beg + g;
  f16x2 nxt[4];
  {
    int s = csr_src[e < end ? e : end - 1];
    load_row128(nxt, xlh + (size_t)s * 128 + c0);
  }
  int nit = (end - beg + 3) >> 2;
  for (int it = 0; it < nit; ++it) {
    f16x2 cur[4];
#pragma unroll
    for (int j = 0; j < 4; ++j) cur[j] = nxt[j];
    bool valid = e < end;
    if (beg + (it + 1) * 4 < end) {        // wave-uniform
      int en = e + 4;
      int s = csr_src[en < end ? en : end - 1];
      load_row128(nxt, xlh + (size_t)s * 128 + c0);
    }
    float v = 0.f;
#pragma unroll
    for (int j = 0; j < 4; ++j) {
      f16x2 m2 = cur[j] + xri[j];
      f16x2 mx = __builtin_elementwise_max(m2, zero2);
      f16x2 mn = __builtin_elementwise_min(m2, zero2);
      f16x2 lr = mx + slope2 * mn;         // leaky_relu
#if __has_builtin(__builtin_amdgcn_fdot2)
      v = __builtin_amdgcn_fdot2(lr, attc[j], v, false);
#else
      v += (float)lr[0] * (float)attc[j][0] + (float)lr[1] * (float)attc[j][1];
#endif
    }
    v += __shfl_xor(v, 1);
    v += __shfl_xor(v, 2);
    v += __shfl_xor(v, 4);
    v += __shfl_xor(v, 8);
    float w = valid ? __expf(v) : 0.f;     // deferred max: |v| small, fp32-safe
    dsum += w;
#pragma unroll
    for (int j = 0; j < 4; ++j) {
      acc[2 * j]     += w * (float)cur[j][0];
      acc[2 * j + 1] += w * (float)cur[j][1];
    }
    e += 4;
  }
#pragma unroll
  for (int k = 0; k < 8; ++k) {
    acc[k] += __shfl_xor(acc[k], 16);
    acc[k] += __shfl_xor(acc[k], 32);
  }
  dsum += __shfl_xor(dsum, 16);
  dsum += __shfl_xor(dsum, 32);
  if (g != 0) return;
  float inv = 1.f / dsum;
  f16x8 hv;
#pragma unroll
  for (int k = 0; k < 8; ++k) {
    float vv = fmaxf(acc[k] * inv + bias[c0 + k], 0.f);
    hv[k] = (_Float16)vv;
  }
  int p = wid >> 6, mrow = wid & 63;
  size_t ce = (((size_t)p * 16 + li) * 64 + mrow) * 8;
  *(f16x8*)&Hp[ce] = hv;
}

// -------- fused GATv2 aggregation (C=300): chunked channel map, wide loads,
// fp16 h output (stride HSTRIDE) --------------------------------------------
__global__ __launch_bounds__(256) void gat300(
    const int* __restrict__ rowptr, const int* __restrict__ csr_src,
    const _Float16* __restrict__ xlh, const _Float16* __restrict__ xrh,
    const f16x2* __restrict__ att_h, const float* __restrict__ bias,
    _Float16* __restrict__ hout) {
  int wid = (int)((blockIdx.x * (size_t)blockDim.x + threadIdx.x) >> 6);
  int lane = threadIdx.x & 63;
  if (wid >= N_NODES) return;
  const int g = lane >> 4, li = lane & 15;
  int beg = rowptr[wid], end = rowptr[wid + 1];

  f16x2 xri[10], attc[10];
  load_row300(xri, xrh + (size_t)wid * 320, li);
#pragma unroll
  for (int j = 0; j < 4; ++j) attc[j] = att_h[4 * li + j];
#pragma unroll
  for (int j = 0; j < 4; ++j) attc[4 + j] = att_h[64 + 4 * li + j];
  attc[8] = att_h[128 + 2 * li];
  attc[9] = att_h[128 + 2 * li + 1];

  float acc[20];
#pragma unroll
  for (int k = 0; k < 20; ++k) acc[k] = 0.f;
  float dsum = 0.f;
  const f16x2 slope2 = {(_Float16)SLOPE, (_Float16)SLOPE};
  const f16x2 zero2 = {(_Float16)0.f, (_Float16)0.f};

  int e = beg + g;
  f16x2 nxt[10];
  {
    int s = csr_src[e < end ? e : end - 1];
    load_row300(nxt, xlh + (size_t)s * 320, li);
  }
  int nit = (end - beg + 3) >> 2;
  for (int it = 0; it < nit; ++it) {
    f16x2 cur[10];
#pragma unroll
    for (int j = 0; j < 10; ++j) cur[j] = nxt[j];
    bool valid = e < end;
    if (beg + (it + 1) * 4 < end) {        // wave-uniform
      int en = e + 4;
      int s = csr_src[en < end ? en : end - 1];
      load_row300(nxt, xlh + (size_t)s * 320, li);
    }
    float v = 0.f;
#pragma unroll
    for (int j = 0; j < 10; ++j) {
      f16x2 m2 = cur[j] + xri[j];
      f16x2 mx = __builtin_elementwise_max(m2, zero2);
      f16x2 mn = __builtin_elementwise_min(m2, zero2);
      f16x2 lr = mx + slope2 * mn;         // leaky_relu
#if __has_builtin(__builtin_amdgcn_fdot2)
      v = __builtin_amdgcn_fdot2(lr, attc[j], v, false);
#else
      v += (float)lr[0] * (float)attc[j][0] + (float)lr[1] * (float)attc[j][1];
#endif
    }
    v += __shfl_xor(v, 1);
    v += __shfl_xor(v, 2);
    v += __shfl_xor(v, 4);
    v += __shfl_xor(v, 8);
    float w = valid ? __expf(v) : 0.f;
    dsum += w;
#pragma unroll
    for (int j = 0; j < 10; ++j) {
      acc[2 * j]     += w * (float)cur[j][0];
      acc[2 * j + 1] += w * (float)cur[j][1];
    }
    e += 4;
  }
#pragma unroll
  for (int k = 0; k < 20; ++k) {
    acc[k] += __shfl_xor(acc[k], 16);
    acc[k] += __shfl_xor(acc[k], 32);
  }
  dsum += __shfl_xor(dsum, 16);
  dsum += __shfl_xor(dsum, 32);
  if (g != 0) return;
  float inv = 1.f / dsum;
  // mapped channels: k<8 -> 8li+k; k<16 -> 128+8li+(k-8); else 256+4li+(k-16)
  f16x8 h1, h2;
  f16x4 h3;
#pragma unroll
  for (int k = 0; k < 8; ++k)
    h1[k] = (_Float16)fmaxf(acc[k] * inv + bias[8 * li + k], 0.f);
#pragma unroll
  for (int k = 0; k < 8; ++k)
    h2[k] = (_Float16)fmaxf(acc[8 + k] * inv + bias[128 + 8 * li + k], 0.f);
  if (li <= 10) {
#pragma unroll
    for (int k = 0; k < 4; ++k)
      h3[k] = (_Float16)fmaxf(acc[16 + k] * inv + bias[256 + 4 * li + k], 0.f);
  }
  _Float16* hr = hout + (size_t)wid * HSTRIDE;
  *(f16x8*)(hr + 8 * li) = h1;
  *(f16x8*)(hr + 128 + 8 * li) = h2;
  if (li <= 10) *(f16x4*)(hr + 256 + 4 * li) = h3;   // ch 300+ skipped
}

// ------------- global mean pool (batch sorted), split + unrolled --------
__device__ int lower_bound_dev(const int* a, int n, int v) {
  int lo = 0, hi = n;
  while (lo < hi) { int mid = (lo + hi) >> 1; if (a[mid] < v) lo = mid + 1; else hi = mid; }
  return lo;
}

__global__ void pool_sum(const _Float16* __restrict__ h, const int* __restrict__ batch,
                         float* __restrict__ gsum) {
  int gi = blockIdx.x;
  int sp = blockIdx.y;
  int c = threadIdx.x;
  if (c >= 300) return;
  int start = lower_bound_dev(batch, N_NODES, gi);
  int end   = lower_bound_dev(batch, N_NODES, gi + 1);
  int len = end - start;
  int chunk = (len + POOL_SPLIT - 1) / POOL_SPLIT;
  int a = start + sp * chunk;
  int b = a + chunk; if (b > end) b = end;
  if (a >= b) return;
  float s0 = 0.f, s1 = 0.f, s2 = 0.f, s3 = 0.f;
  int n = a;
  for (; n + 3 < b; n += 4) {
    s0 += (float)h[(size_t)n * HSTRIDE + c];
    s1 += (float)h[(size_t)(n + 1) * HSTRIDE + c];
    s2 += (float)h[(size_t)(n + 2) * HSTRIDE + c];
    s3 += (float)h[(size_t)(n + 3) * HSTRIDE + c];
  }
  for (; n < b; ++n) s0 += (float)h[(size_t)n * HSTRIDE + c];
  atomicAdd(&gsum[(size_t)gi * 300 + c], (s0 + s1) + (s2 + s3));
}

__global__ void pool_final(float* __restrict__ gsum, const int* __restrict__ batch) {
  int t = blockIdx.x * blockDim.x + threadIdx.x;
  if (t >= N_GRAPHS * 300) return;
  int gi = t / 300;
  int start = lower_bound_dev(batch, N_NODES, gi);
  int end   = lower_bound_dev(batch, N_NODES, gi + 1);
  int cnt = end - start;
  gsum[t] = gsum[t] / (float)(cnt > 0 ? cnt : 1);
}

// ------------- small per-graph FC ---------------------------------------
__global__ void fc_kernel(const float* __restrict__ g, const float* __restrict__ W,
                          const float* __restrict__ b, float* __restrict__ out,
                          int K, int N, int do_relu) {
  __shared__ float row[304];
  int gi = blockIdx.x;
  for (int k = threadIdx.x; k < K; k += blockDim.x) row[k] = g[(size_t)gi * K + k];
  __syncthreads();
  int c = threadIdx.x;
  if (c >= N) return;
  float s = b[c];
  for (int k = 0; k < K; ++k) s += row[k] * W[(size_t)k * N + c];
  if (do_relu) s = fmaxf(s, 0.f);
  out[(size_t)gi * N + c] = s;
}

extern "C" void kernel_launch(void* const* d_in, const int* in_sizes, int n_in,
                              void* d_out, int out_size, void* d_ws, size_t ws_size,
                              hipStream_t stream) {
  const float* x     = (const float*)d_in[0];
  const int*   ei    = (const int*)d_in[1];
  const int*   batch = (const int*)d_in[2];
  const float* Wl[4], *bl[4], *Wr[4], *br[4], *att[4], *bias[4];
  for (int l = 0; l < 4; ++l) {
    Wl[l]   = (const float*)d_in[3 + l * 6 + 0];
    bl[l]   = (const float*)d_in[3 + l * 6 + 1];
    Wr[l]   = (const float*)d_in[3 + l * 6 + 2];
    br[l]   = (const float*)d_in[3 + l * 6 + 3];
    att[l]  = (const float*)d_in[3 + l * 6 + 4];
    bias[l] = (const float*)d_in[3 + l * 6 + 5];
  }
  const float* fc1_W = (const float*)d_in[27];
  const float* fc1_b = (const float*)d_in[28];
  const float* fc2_W = (const float*)d_in[29];
  const float* fc2_b = (const float*)d_in[30];

  char* wsb = (char*)d_ws;
  size_t off = 0;
  auto alloc = [&](size_t bytes) {
    void* p = (void*)(wsb + off);
    off += (bytes + 63) & ~(size_t)63;
    return p;
  };
  // fp16 xl/xr, stride up to 320 (layer 3); layers 0-2 use stride 128
  _Float16* xlh = (_Float16*)alloc((size_t)N_NODES * 320 * 2);
  _Float16* xrh = (_Float16*)alloc((size_t)N_NODES * 320 * 2);
  _Float16* A0  = (_Float16*)alloc((size_t)NPANEL * 40 * 512 * 2);  // 32 MB
  _Float16* Hp  = (_Float16*)alloc((size_t)NPANEL * 16 * 512 * 2);  // 12.8 MB
  _Float16* hbuf = (_Float16*)alloc((size_t)N_NODES * HSTRIDE * 2); // 30.4 MB
  float* gpool  = (float*)alloc((size_t)N_GRAPHS * 300 * 4);
  float* g1     = (float*)alloc((size_t)N_GRAPHS * 300 * 4);
  f16x2* att_h  = (f16x2*)alloc((size_t)4 * 192 * 4);
  const int Kact[4] = {300, 128, 128, 128};
  const int Cdim[4] = {128, 128, 128, 300};
  const int NLv[4]  = {128, 128, 128, 304};
  const int Kpv[4]  = {320, 128, 128, 128};
  const int CSg[4]  = {128, 128, 128, 320};
  _Float16* Wp[4];
  for (int l = 0; l < 4; ++l) {
    int kcn = Kpv[l] >> 3;
    Wp[l] = (_Float16*)alloc((size_t)kcn * WCOLS * 8 * 2);
  }
  int* deg     = (int*)alloc((size_t)N_NODES * 4);
  int* rowptr  = (int*)alloc((size_t)(N_NODES + 1) * 4);
  int* bsum    = (int*)alloc(256 * 4);
  int* cursor  = (int*)alloc((size_t)N_NODES * 4);
  int* csr_src = (int*)alloc((size_t)E_TOT * 4);

  // one-time conversions
  conv_x<<<(NPANEL * 64 * 40 + 255) / 256, 256, 0, stream>>>(x, A0);
  for (int l = 0; l < 4; ++l) {
    int kcn = Kpv[l] >> 3;
    conv_w<<<(kcn * WCOLS + 255) / 256, 256, 0, stream>>>(
        Wl[l], Wr[l], Wp[l], Kact[l], Cdim[l], NLv[l], kcn);
  }
  conv_att<<<3, 256, 0, stream>>>(att[0], att[1], att[2], att[3], att_h);
  zero_pad_H<<<3, 256, 0, stream>>>(Hp);

  // CSR build
  zero_ints<<<(N_NODES + 255) / 256, 256, 0, stream>>>(deg, N_NODES);
  deg_count<<<(E_TOT + 255) / 256, 256, 0, stream>>>(ei, deg);
  scan1<<<NB_SCAN, 256, 0, stream>>>(deg, rowptr, bsum);
  scan2<<<1, 256, 0, stream>>>(bsum);
  scan3<<<NB_SCAN, 256, 0, stream>>>(rowptr, bsum, cursor);
  fill_csr<<<(E_TOT + 255) / 256, 256, 0, stream>>>(ei, cursor, csr_src);
  // zero the pool accumulator early (fp32 zero == all-zero bits)
  zero_ints<<<(N_GRAPHS * 300 + 255) / 256, 256, 0, stream>>>((int*)gpool, N_GRAPHS * 300);

  const int nwave_blocks = (N_NODES + 3) / 4;
  for (int l = 0; l < 4; ++l) {
    const _Float16* Ain = (l == 0) ? A0 : Hp;
    int ny = (2 * NLv[l] + 255) / 256;
    dim3 gg(NPANEL, ny);
    gemm_dual<<<gg, 256, 0, stream>>>(Ain, Wp[l], bl[l], br[l],
                                      xlh, xrh, Kpv[l], Cdim[l], NLv[l], CSg[l]);
    if (l < 3) {
      gat128<<<nwave_blocks, 256, 0, stream>>>(
          rowptr, csr_src, xlh, xrh, att_h + l * 192, bias[l], Hp);
    } else {
      // zero stale cols 300..319 of stride-320 rows (never written by gemm)
      zero_xl_pad<<<(N_NODES * 20 + 255) / 256, 256, 0, stream>>>(xlh, xrh);
      gat300<<<nwave_blocks, 256, 0, stream>>>(
          rowptr, csr_src, xlh, xrh, att_h + l * 192, bias[l], hbuf);
    }
  }
  {
    dim3 pg(N_GRAPHS, POOL_SPLIT);
    pool_sum<<<pg, 320, 0, stream>>>(hbuf, batch, gpool);
    pool_final<<<(N_GRAPHS * 300 + 255) / 256, 256, 0, stream>>>(gpool, batch);
  }
  fc_kernel<<<N_GRAPHS, 320, 0, stream>>>(gpool, fc1_W, fc1_b, g1, 300, 300, 1);
  fc_kernel<<<N_GRAPHS, 768, 0, stream>>>(g1, fc2_W, fc2_b, (float*)d_out, 300, 768, 0);
}

// Round 11
// 582.974 us; speedup vs baseline: 1.8211x; 1.0083x over previous
//
#include <hip/hip_runtime.h>
#include <hip/hip_bf16.h>
#include <math.h>

#define N_NODES 50000
#define N_EDGES 800000
#define E_TOT   (N_EDGES + N_NODES)
#define N_GRAPHS 256
#define SLOPE 0.2f
#define NB_SCAN ((N_NODES + 255) / 256)
#define NPANEL 782            // ceil(50000/64)
#define WCOLS 768             // padded concatenated-W width
#define POOL_SPLIT 8
#define HSTRIDE 304           // fp16 h row stride (608B, 16B-aligned)

typedef __attribute__((ext_vector_type(4))) float f32x4;
typedef _Float16 f16x2 __attribute__((ext_vector_type(2)));
typedef _Float16 f16x4 __attribute__((ext_vector_type(4)));
typedef _Float16 f16x8 __attribute__((ext_vector_type(8)));

__device__ __forceinline__ void gl_lds16(const void* g, void* l) {
  __builtin_amdgcn_global_load_lds(
      (const __attribute__((address_space(1))) unsigned int*)g,
      (__attribute__((address_space(3))) unsigned int*)l, 16, 0, 0);
}

// ---- x -> panel-swizzled fp16 [p][kc=40][m=64][ki=8], zero-padded ----------
__global__ void conv_x(const float* __restrict__ x, _Float16* __restrict__ A) {
  int id = blockIdx.x * blockDim.x + threadIdx.x;
  const int total = NPANEL * 64 * 40;
  if (id >= total) return;
  int kc = id % 40;
  int m  = (id / 40) % 64;
  int p  = id / 2560;
  int n = p * 64 + m;
  f16x8 hv;
#pragma unroll
  for (int i = 0; i < 8; ++i) {
    int k = kc * 8 + i;
    float v = (n < N_NODES && k < 300) ? x[(size_t)n * 300 + k] : 0.f;
    hv[i] = (_Float16)v;
  }
  size_t ce = (((size_t)p * 40 + kc) * 64 + m) * 8;
  *(f16x8*)&A[ce] = hv;
}

// ---- Wl,Wr -> concatenated padded fp16 [kc][WCOLS][8] ----------------------
__global__ void conv_w(const float* __restrict__ Wl, const float* __restrict__ Wr,
                       _Float16* __restrict__ W, int K, int C, int NL, int kcn) {
  int id = blockIdx.x * blockDim.x + threadIdx.x;
  if (id >= kcn * WCOLS) return;
  int n = id % WCOLS, kc = id / WCOLS;
  f16x8 hv;
#pragma unroll
  for (int i = 0; i < 8; ++i) {
    int k = kc * 8 + i;
    float v = 0.f;
    if (k < K) {
      if (n < NL) { if (n < C) v = Wl[(size_t)k * C + n]; }
      else if (n < 2 * NL && (n - NL) < C) v = Wr[(size_t)k * C + (n - NL)];
    }
    hv[i] = (_Float16)v;
  }
  *(f16x8*)&W[(size_t)id * 8] = hv;
}

// ---- att (fp32) -> padded f16x2 tables, 192 entries per layer --------------
__global__ void conv_att(const float* __restrict__ a0, const float* __restrict__ a1,
                         const float* __restrict__ a2, const float* __restrict__ a3,
                         f16x2* __restrict__ att_h) {
  int t = blockIdx.x * blockDim.x + threadIdx.x;
  if (t >= 4 * 192) return;
  int l = t / 192, i = t % 192;
  const float* a = (l == 0) ? a0 : (l == 1) ? a1 : (l == 2) ? a2 : a3;
  int C = (l == 3) ? 300 : 128;
  int c = 2 * i;
  f16x2 r;
  r[0] = (c < C) ? (_Float16)a[c] : (_Float16)0.f;
  r[1] = (c + 1 < C) ? (_Float16)a[c + 1] : (_Float16)0.f;
  att_h[t] = r;
}

// ---- zero pad rows 50000..50047 of H panels (kcn=16) -----------------------
__global__ void zero_pad_H(_Float16* __restrict__ H) {
  int t = blockIdx.x * blockDim.x + threadIdx.x;
  if (t >= 48 * 16) return;
  int m = 16 + (t >> 4), kc = t & 15;
  size_t ce = (((size_t)781 * 16 + kc) * 64 + m) * 8;
  f16x8 z = {};
  *(f16x8*)&H[ce] = z;
}

// ---- zero stale cols 300..319 of the stride-320 layer-3 xl/xr buffers ------
__global__ void zero_xl_pad(_Float16* __restrict__ xlh, _Float16* __restrict__ xrh) {
  int t = blockIdx.x * blockDim.x + threadIdx.x;
  if (t >= N_NODES * 20) return;
  int r = t / 20, k = t % 20;
  size_t o = (size_t)r * 320 + 300 + k;
  xlh[o] = (_Float16)0.f;
  xrh[o] = (_Float16)0.f;
}

// ---- dual-output fp16 MFMA GEMM: [xl|xr] = A @ [Wl|Wr] + bias --------------
__global__ __launch_bounds__(256, 2) void gemm_dual(
    const _Float16* __restrict__ A, const _Float16* __restrict__ W,
    const float* __restrict__ biasl, const float* __restrict__ biasr,
    _Float16* __restrict__ xlh, _Float16* __restrict__ xrh,
    int Kp, int C, int NL, int CSg) {
  __shared__ _Float16 As[4][64][8];     // 4 KB
  __shared__ _Float16 Ws[4][256][8];    // 16 KB
  const int tid = threadIdx.x, wv = tid >> 6, lane = tid & 63;
  const int p = blockIdx.x, n0 = blockIdx.y * 256;
  const int kcn = Kp >> 3, nk = Kp >> 5;
  const size_t abase0 = (size_t)p * kcn * 512;
  const int rsel = lane >> 4, rrow = lane & 15;
  f32x4 z4 = {0.f, 0.f, 0.f, 0.f};
  f32x4 acc[4][4];
#pragma unroll
  for (int a = 0; a < 4; ++a)
#pragma unroll
    for (int b = 0; b < 4; ++b) acc[a][b] = z4;

  for (int s = 0; s < nk; ++s) {
    const size_t abase = abase0 + (size_t)s * 2048;
    for (int q = wv; q < 20; q += 4) {
      const _Float16* g;
      _Float16* l;
      if (q < 4) {
        g = A + abase + q * 512;
        l = &As[0][0][0] + q * 512;
      } else {
        int j = q - 4;                 // 0..15: row j>>2, col-block j&3
        g = W + ((size_t)(s * 4 + (j >> 2)) * WCOLS + n0 + (j & 3) * 64) * 8;
        l = &Ws[0][0][0] + j * 512;
      }
      gl_lds16(g + lane * 8, l);
    }
    __syncthreads();
    f16x8 af[4], bf[4];
#pragma unroll
    for (int mt = 0; mt < 4; ++mt)
      af[mt] = *(const f16x8*)&As[rsel][mt * 16 + rrow][0];
#pragma unroll
    for (int nt = 0; nt < 4; ++nt)
      bf[nt] = *(const f16x8*)&Ws[rsel][wv * 64 + nt * 16 + rrow][0];
#pragma unroll
    for (int mt = 0; mt < 4; ++mt)
#pragma unroll
      for (int nt = 0; nt < 4; ++nt)
        acc[mt][nt] = __builtin_amdgcn_mfma_f32_16x16x32_f16(af[mt], bf[nt], acc[mt][nt], 0, 0, 0);
    __syncthreads();
  }
#pragma unroll
  for (int mt = 0; mt < 4; ++mt) {
    int r0 = p * 64 + mt * 16 + rsel * 4;
#pragma unroll
    for (int nt = 0; nt < 4; ++nt) {
      int gc = n0 + wv * 64 + nt * 16 + rrow;
#pragma unroll
      for (int j = 0; j < 4; ++j) {
        int row = r0 + j;
        if (row >= N_NODES) continue;
        float v = acc[mt][nt][j];
        if (gc < NL) {
          if (gc < C) xlh[(size_t)row * CSg + gc] = (_Float16)(v + biasl[gc]);
        } else {
          int c2 = gc - NL;
          if (c2 >= 0 && c2 < C) xrh[(size_t)row * CSg + c2] = (_Float16)(v + biasr[c2]);
        }
      }
    }
  }
}

// ---------------- CSR build (once per launch) ---------------------------
__global__ void zero_ints(int* __restrict__ p, int n) {
  int i = blockIdx.x * blockDim.x + threadIdx.x;
  if (i < n) p[i] = 0;
}

__global__ void deg_count(const int* __restrict__ ei, int* __restrict__ deg) {
  int e = blockIdx.x * blockDim.x + threadIdx.x;
  if (e >= E_TOT) return;
  int d = (e < N_EDGES) ? ei[N_EDGES + e] : e - N_EDGES;
  atomicAdd(&deg[d], 1);
}

__global__ void scan1(const int* __restrict__ deg, int* __restrict__ rp,
                      int* __restrict__ bsum) {
  __shared__ int s[256];
  int i = blockIdx.x * 256 + threadIdx.x;
  int v = (i < N_NODES) ? deg[i] : 0;
  s[threadIdx.x] = v;
  __syncthreads();
  for (int off = 1; off < 256; off <<= 1) {
    int t = (threadIdx.x >= off) ? s[threadIdx.x - off] : 0;
    __syncthreads();
    s[threadIdx.x] += t;
    __syncthreads();
  }
  if (i < N_NODES) rp[i] = s[threadIdx.x] - v;
  if (threadIdx.x == 255) bsum[blockIdx.x] = s[255];
}

__global__ void scan2(int* __restrict__ bsum) {
  __shared__ int s[256];
  int v = (threadIdx.x < NB_SCAN) ? bsum[threadIdx.x] : 0;
  s[threadIdx.x] = v;
  __syncthreads();
  for (int off = 1; off < 256; off <<= 1) {
    int t = (threadIdx.x >= off) ? s[threadIdx.x - off] : 0;
    __syncthreads();
    s[threadIdx.x] += t;
    __syncthreads();
  }
  if (threadIdx.x < NB_SCAN) bsum[threadIdx.x] = s[threadIdx.x] - v;
}

__global__ void scan3(int* __restrict__ rp, const int* __restrict__ bsum,
                      int* __restrict__ cursor) {
  int i = blockIdx.x * 256 + threadIdx.x;
  if (i < N_NODES) {
    int v = rp[i] + bsum[blockIdx.x];
    rp[i] = v;
    cursor[i] = v;
  }
  if (i == 0) rp[N_NODES] = E_TOT;
}

__global__ void fill_csr(const int* __restrict__ ei, int* __restrict__ cursor,
                         int* __restrict__ csr_src) {
  int e = blockIdx.x * blockDim.x + threadIdx.x;
  if (e >= E_TOT) return;
  int s, d;
  if (e < N_EDGES) { s = ei[e]; d = ei[N_EDGES + e]; }
  else             { s = d = e - N_EDGES; }
  int pos = atomicAdd(&cursor[d], 1);
  csr_src[pos] = s;
}

// ---- row loader (C=128): one f16x8 per lane -------------------------------
__device__ __forceinline__ void load_row128(f16x2* dst, const _Float16* p) {
  f16x8 t = *(const f16x8*)p;
#pragma unroll
  for (int j = 0; j < 4; ++j) {
    f16x2 r; r[0] = t[2 * j]; r[1] = t[2 * j + 1]; dst[j] = r;
  }
}

// ---- row loader (C=300, chunked map): 16B+16B+8B per lane ------------------
// lane li covers channels [8li,8li+8) u [128+8li,+8) u [256+4li,+4)
__device__ __forceinline__ void load_row300(f16x2* dst, const _Float16* row, int li) {
  f16x8 a = *(const f16x8*)(row + 8 * li);
  f16x8 b = *(const f16x8*)(row + 128 + 8 * li);
  f16x4 c = *(const f16x4*)(row + 256 + 4 * li);
#pragma unroll
  for (int j = 0; j < 4; ++j) {
    f16x2 r; r[0] = a[2 * j]; r[1] = a[2 * j + 1]; dst[j] = r;
  }
#pragma unroll
  for (int j = 0; j < 4; ++j) {
    f16x2 r; r[0] = b[2 * j]; r[1] = b[2 * j + 1]; dst[4 + j] = r;
  }
  {
    f16x2 r; r[0] = c[0]; r[1] = c[1]; dst[8] = r;
    f16x2 r2; r2[0] = c[2]; r2[1] = c[3]; dst[9] = r2;
  }
}

// -------- fused GATv2 aggregation (C=128): 16 lanes/edge, 4 edges in flight,
// depth-2 row pipeline, deferred-max softmax, fp16 H-panel output ------------
__global__ __launch_bounds__(256) void gat128(
    const int* __restrict__ rowptr, const int* __restrict__ csr_src,
    const _Float16* __restrict__ xlh, const _Float16* __restrict__ xrh,
    const f16x2* __restrict__ att_h, const float* __restrict__ bias,
    _Float16* __restrict__ Hp) {
  int wid = (int)((blockIdx.x * (size_t)blockDim.x + threadIdx.x) >> 6);
  int lane = threadIdx.x & 63;
  if (wid >= N_NODES) return;
  const int g = lane >> 4, li = lane & 15;
  const int c0 = li * 8;
  int beg = rowptr[wid], end = rowptr[wid + 1];

  f16x2 xri[4], attc[4];
  load_row128(xri, xrh + (size_t)wid * 128 + c0);
#pragma unroll
  for (int j = 0; j < 4; ++j) attc[j] = att_h[(c0 >> 1) + j];

  float acc[8];
#pragma unroll
  for (int k = 0; k < 8; ++k) acc[k] = 0.f;
  float dsum = 0.f;
  const f16x2 slope2 = {(_Float16)SLOPE, (_Float16)SLOPE};
  const f16x2 zero2 = {(_Float16)0.f, (_Float16)0.f};

  int e = beg + g;
  f16x2 bufA[4], bufB[4];
  {
    int e0 = e < end ? e : end - 1;
    load_row128(bufA, xlh + (size_t)csr_src[e0] * 128 + c0);
  }
  {
    int e1 = e + 4 < end ? e + 4 : end - 1;
    load_row128(bufB, xlh + (size_t)csr_src[e1] * 128 + c0);
  }
  int nit = (end - beg + 3) >> 2;

  auto step = [&](f16x2* cur) {
    bool valid = e < end;
    float v = 0.f;
#pragma unroll
    for (int j = 0; j < 4; ++j) {
      f16x2 m2 = cur[j] + xri[j];
      f16x2 mx = __builtin_elementwise_max(m2, zero2);
      f16x2 mn = __builtin_elementwise_min(m2, zero2);
      f16x2 lr = mx + slope2 * mn;         // leaky_relu
#if __has_builtin(__builtin_amdgcn_fdot2)
      v = __builtin_amdgcn_fdot2(lr, attc[j], v, false);
#else
      v += (float)lr[0] * (float)attc[j][0] + (float)lr[1] * (float)attc[j][1];
#endif
    }
    v += __shfl_xor(v, 1);
    v += __shfl_xor(v, 2);
    v += __shfl_xor(v, 4);
    v += __shfl_xor(v, 8);
    float w = valid ? __expf(v) : 0.f;     // deferred max: |v| small, fp32-safe
    dsum += w;
#pragma unroll
    for (int j = 0; j < 4; ++j) {
      acc[2 * j]     += w * (float)cur[j][0];
      acc[2 * j + 1] += w * (float)cur[j][1];
    }
    if (e - g + 8 < end) {                 // wave-uniform prefetch condition
      int en = e + 8; if (en > end - 1) en = end - 1;
      load_row128(cur, xlh + (size_t)csr_src[en] * 128 + c0);
    }
    e += 4;
  };
  for (int it = 0; it < nit; it += 2) {
    step(bufA);
    if (it + 1 < nit) step(bufB);
  }

#pragma unroll
  for (int k = 0; k < 8; ++k) {
    acc[k] += __shfl_xor(acc[k], 16);
    acc[k] += __shfl_xor(acc[k], 32);
  }
  dsum += __shfl_xor(dsum, 16);
  dsum += __shfl_xor(dsum, 32);
  if (g != 0) return;
  float inv = 1.f / dsum;
  f16x8 hv;
#pragma unroll
  for (int k = 0; k < 8; ++k) {
    float vv = fmaxf(acc[k] * inv + bias[c0 + k], 0.f);
    hv[k] = (_Float16)vv;
  }
  int p = wid >> 6, mrow = wid & 63;
  size_t ce = (((size_t)p * 16 + li) * 64 + mrow) * 8;
  *(f16x8*)&Hp[ce] = hv;
}

// -------- fused GATv2 aggregation (C=300): chunked channel map, wide loads,
// depth-2 row pipeline, fp16 h output (stride HSTRIDE) -----------------------
__global__ __launch_bounds__(256) void gat300(
    const int* __restrict__ rowptr, const int* __restrict__ csr_src,
    const _Float16* __restrict__ xlh, const _Float16* __restrict__ xrh,
    const f16x2* __restrict__ att_h, const float* __restrict__ bias,
    _Float16* __restrict__ hout) {
  int wid = (int)((blockIdx.x * (size_t)blockDim.x + threadIdx.x) >> 6);
  int lane = threadIdx.x & 63;
  if (wid >= N_NODES) return;
  const int g = lane >> 4, li = lane & 15;
  int beg = rowptr[wid], end = rowptr[wid + 1];

  f16x2 xri[10], attc[10];
  load_row300(xri, xrh + (size_t)wid * 320, li);
#pragma unroll
  for (int j = 0; j < 4; ++j) attc[j] = att_h[4 * li + j];
#pragma unroll
  for (int j = 0; j < 4; ++j) attc[4 + j] = att_h[64 + 4 * li + j];
  attc[8] = att_h[128 + 2 * li];
  attc[9] = att_h[128 + 2 * li + 1];

  float acc[20];
#pragma unroll
  for (int k = 0; k < 20; ++k) acc[k] = 0.f;
  float dsum = 0.f;
  const f16x2 slope2 = {(_Float16)SLOPE, (_Float16)SLOPE};
  const f16x2 zero2 = {(_Float16)0.f, (_Float16)0.f};

  int e = beg + g;
  f16x2 bufA[10], bufB[10];
  {
    int e0 = e < end ? e : end - 1;
    load_row300(bufA, xlh + (size_t)csr_src[e0] * 320, li);
  }
  {
    int e1 = e + 4 < end ? e + 4 : end - 1;
    load_row300(bufB, xlh + (size_t)csr_src[e1] * 320, li);
  }
  int nit = (end - beg + 3) >> 2;

  auto step = [&](f16x2* cur) {
    bool valid = e < end;
    float v = 0.f;
#pragma unroll
    for (int j = 0; j < 10; ++j) {
      f16x2 m2 = cur[j] + xri[j];
      f16x2 mx = __builtin_elementwise_max(m2, zero2);
      f16x2 mn = __builtin_elementwise_min(m2, zero2);
      f16x2 lr = mx + slope2 * mn;         // leaky_relu
#if __has_builtin(__builtin_amdgcn_fdot2)
      v = __builtin_amdgcn_fdot2(lr, attc[j], v, false);
#else
      v += (float)lr[0] * (float)attc[j][0] + (float)lr[1] * (float)attc[j][1];
#endif
    }
    v += __shfl_xor(v, 1);
    v += __shfl_xor(v, 2);
    v += __shfl_xor(v, 4);
    v += __shfl_xor(v, 8);
    float w = valid ? __expf(v) : 0.f;
    dsum += w;
#pragma unroll
    for (int j = 0; j < 10; ++j) {
      acc[2 * j]     += w * (float)cur[j][0];
      acc[2 * j + 1] += w * (float)cur[j][1];
    }
    if (e - g + 8 < end) {                 // wave-uniform prefetch condition
      int en = e + 8; if (en > end - 1) en = end - 1;
      load_row300(cur, xlh + (size_t)csr_src[en] * 320, li);
    }
    e += 4;
  };
  for (int it = 0; it < nit; it += 2) {
    step(bufA);
    if (it + 1 < nit) step(bufB);
  }

#pragma unroll
  for (int k = 0; k < 20; ++k) {
    acc[k] += __shfl_xor(acc[k], 16);
    acc[k] += __shfl_xor(acc[k], 32);
  }
  dsum += __shfl_xor(dsum, 16);
  dsum += __shfl_xor(dsum, 32);
  if (g != 0) return;
  float inv = 1.f / dsum;
  // mapped channels: k<8 -> 8li+k; k<16 -> 128+8li+(k-8); else 256+4li+(k-16)
  f16x8 h1, h2;
  f16x4 h3;
#pragma unroll
  for (int k = 0; k < 8; ++k)
    h1[k] = (_Float16)fmaxf(acc[k] * inv + bias[8 * li + k], 0.f);
#pragma unroll
  for (int k = 0; k < 8; ++k)
    h2[k] = (_Float16)fmaxf(acc[8 + k] * inv + bias[128 + 8 * li + k], 0.f);
  if (li <= 10) {
#pragma unroll
    for (int k = 0; k < 4; ++k)
      h3[k] = (_Float16)fmaxf(acc[16 + k] * inv + bias[256 + 4 * li + k], 0.f);
  }
  _Float16* hr = hout + (size_t)wid * HSTRIDE;
  *(f16x8*)(hr + 8 * li) = h1;
  *(f16x8*)(hr + 128 + 8 * li) = h2;
  if (li <= 10) *(f16x4*)(hr + 256 + 4 * li) = h3;   // ch 300+ skipped
}

// ------------- global mean pool (batch sorted), split + unrolled --------
__device__ int lower_bound_dev(const int* a, int n, int v) {
  int lo = 0, hi = n;
  while (lo < hi) { int mid = (lo + hi) >> 1; if (a[mid] < v) lo = mid + 1; else hi = mid; }
  return lo;
}

__global__ void pool_sum(const _Float16* __restrict__ h, const int* __restrict__ batch,
                         float* __restrict__ gsum) {
  int gi = blockIdx.x;
  int sp = blockIdx.y;
  int c = threadIdx.x;
  if (c >= 300) return;
  int start = lower_bound_dev(batch, N_NODES, gi);
  int end   = lower_bound_dev(batch, N_NODES, gi + 1);
  int len = end - start;
  int chunk = (len + POOL_SPLIT - 1) / POOL_SPLIT;
  int a = start + sp * chunk;
  int b = a + chunk; if (b > end) b = end;
  if (a >= b) return;
  float s0 = 0.f, s1 = 0.f, s2 = 0.f, s3 = 0.f;
  int n = a;
  for (; n + 3 < b; n += 4) {
    s0 += (float)h[(size_t)n * HSTRIDE + c];
    s1 += (float)h[(size_t)(n + 1) * HSTRIDE + c];
    s2 += (float)h[(size_t)(n + 2) * HSTRIDE + c];
    s3 += (float)h[(size_t)(n + 3) * HSTRIDE + c];
  }
  for (; n < b; ++n) s0 += (float)h[(size_t)n * HSTRIDE + c];
  atomicAdd(&gsum[(size_t)gi * 300 + c], (s0 + s1) + (s2 + s3));
}

__global__ void pool_final(float* __restrict__ gsum, const int* __restrict__ batch) {
  int t = blockIdx.x * blockDim.x + threadIdx.x;
  if (t >= N_GRAPHS * 300) return;
  int gi = t / 300;
  int start = lower_bound_dev(batch, N_NODES, gi);
  int end   = lower_bound_dev(batch, N_NODES, gi + 1);
  int cnt = end - start;
  gsum[t] = gsum[t] / (float)(cnt > 0 ? cnt : 1);
}

// ------------- small per-graph FC ---------------------------------------
__global__ void fc_kernel(const float* __restrict__ g, const float* __restrict__ W,
                          const float* __restrict__ b, float* __restrict__ out,
                          int K, int N, int do_relu) {
  __shared__ float row[304];
  int gi = blockIdx.x;
  for (int k = threadIdx.x; k < K; k += blockDim.x) row[k] = g[(size_t)gi * K + k];
  __syncthreads();
  int c = threadIdx.x;
  if (c >= N) return;
  float s = b[c];
  for (int k = 0; k < K; ++k) s += row[k] * W[(size_t)k * N + c];
  if (do_relu) s = fmaxf(s, 0.f);
  out[(size_t)gi * N + c] = s;
}

extern "C" void kernel_launch(void* const* d_in, const int* in_sizes, int n_in,
                              void* d_out, int out_size, void* d_ws, size_t ws_size,
                              hipStream_t stream) {
  const float* x     = (const float*)d_in[0];
  const int*   ei    = (const int*)d_in[1];
  const int*   batch = (const int*)d_in[2];
  const float* Wl[4], *bl[4], *Wr[4], *br[4], *att[4], *bias[4];
  for (int l = 0; l < 4; ++l) {
    Wl[l]   = (const float*)d_in[3 + l * 6 + 0];
    bl[l]   = (const float*)d_in[3 + l * 6 + 1];
    Wr[l]   = (const float*)d_in[3 + l * 6 + 2];
    br[l]   = (const float*)d_in[3 + l * 6 + 3];
    att[l]  = (const float*)d_in[3 + l * 6 + 4];
    bias[l] = (const float*)d_in[3 + l * 6 + 5];
  }
  const float* fc1_W = (const float*)d_in[27];
  const float* fc1_b = (const float*)d_in[28];
  const float* fc2_W = (const float*)d_in[29];
  const float* fc2_b = (const float*)d_in[30];

  char* wsb = (char*)d_ws;
  size_t off = 0;
  auto alloc = [&](size_t bytes) {
    void* p = (void*)(wsb + off);
    off += (bytes + 63) & ~(size_t)63;
    return p;
  };
  // fp16 xl/xr, stride up to 320 (layer 3); layers 0-2 use stride 128
  _Float16* xlh = (_Float16*)alloc((size_t)N_NODES * 320 * 2);
  _Float16* xrh = (_Float16*)alloc((size_t)N_NODES * 320 * 2);
  _Float16* A0  = (_Float16*)alloc((size_t)NPANEL * 40 * 512 * 2);  // 32 MB
  _Float16* Hp  = (_Float16*)alloc((size_t)NPANEL * 16 * 512 * 2);  // 12.8 MB
  _Float16* hbuf = (_Float16*)alloc((size_t)N_NODES * HSTRIDE * 2); // 30.4 MB
  float* gpool  = (float*)alloc((size_t)N_GRAPHS * 300 * 4);
  float* g1     = (float*)alloc((size_t)N_GRAPHS * 300 * 4);
  f16x2* att_h  = (f16x2*)alloc((size_t)4 * 192 * 4);
  const int Kact[4] = {300, 128, 128, 128};
  const int Cdim[4] = {128, 128, 128, 300};
  const int NLv[4]  = {128, 128, 128, 304};
  const int Kpv[4]  = {320, 128, 128, 128};
  const int CSg[4]  = {128, 128, 128, 320};
  _Float16* Wp[4];
  for (int l = 0; l < 4; ++l) {
    int kcn = Kpv[l] >> 3;
    Wp[l] = (_Float16*)alloc((size_t)kcn * WCOLS * 8 * 2);
  }
  int* deg     = (int*)alloc((size_t)N_NODES * 4);
  int* rowptr  = (int*)alloc((size_t)(N_NODES + 1) * 4);
  int* bsum    = (int*)alloc(256 * 4);
  int* cursor  = (int*)alloc((size_t)N_NODES * 4);
  int* csr_src = (int*)alloc((size_t)E_TOT * 4);

  // one-time conversions
  conv_x<<<(NPANEL * 64 * 40 + 255) / 256, 256, 0, stream>>>(x, A0);
  for (int l = 0; l < 4; ++l) {
    int kcn = Kpv[l] >> 3;
    conv_w<<<(kcn * WCOLS + 255) / 256, 256, 0, stream>>>(
        Wl[l], Wr[l], Wp[l], Kact[l], Cdim[l], NLv[l], kcn);
  }
  conv_att<<<3, 256, 0, stream>>>(att[0], att[1], att[2], att[3], att_h);
  zero_pad_H<<<3, 256, 0, stream>>>(Hp);

  // CSR build
  zero_ints<<<(N_NODES + 255) / 256, 256, 0, stream>>>(deg, N_NODES);
  deg_count<<<(E_TOT + 255) / 256, 256, 0, stream>>>(ei, deg);
  scan1<<<NB_SCAN, 256, 0, stream>>>(deg, rowptr, bsum);
  scan2<<<1, 256, 0, stream>>>(bsum);
  scan3<<<NB_SCAN, 256, 0, stream>>>(rowptr, bsum, cursor);
  fill_csr<<<(E_TOT + 255) / 256, 256, 0, stream>>>(ei, cursor, csr_src);
  // zero the pool accumulator early (fp32 zero == all-zero bits)
  zero_ints<<<(N_GRAPHS * 300 + 255) / 256, 256, 0, stream>>>((int*)gpool, N_GRAPHS * 300);

  const int nwave_blocks = (N_NODES + 3) / 4;
  for (int l = 0; l < 4; ++l) {
    const _Float16* Ain = (l == 0) ? A0 : Hp;
    int ny = (2 * NLv[l] + 255) / 256;
    dim3 gg(NPANEL, ny);
    gemm_dual<<<gg, 256, 0, stream>>>(Ain, Wp[l], bl[l], br[l],
                                      xlh, xrh, Kpv[l], Cdim[l], NLv[l], CSg[l]);
    if (l < 3) {
      gat128<<<nwave_blocks, 256, 0, stream>>>(
          rowptr, csr_src, xlh, xrh, att_h + l * 192, bias[l], Hp);
    } else {
      // zero stale cols 300..319 of stride-320 rows (never written by gemm)
      zero_xl_pad<<<(N_NODES * 20 + 255) / 256, 256, 0, stream>>>(xlh, xrh);
      gat300<<<nwave_blocks, 256, 0, stream>>>(
          rowptr, csr_src, xlh, xrh, att_h + l * 192, bias[l], hbuf);
    }
  }
  {
    dim3 pg(N_GRAPHS, POOL_SPLIT);
    pool_sum<<<pg, 320, 0, stream>>>(hbuf, batch, gpool);
    pool_final<<<(N_GRAPHS * 300 + 255) / 256, 256, 0, stream>>>(gpool, batch);
  }
  fc_kernel<<<N_GRAPHS, 320, 0, stream>>>(gpool, fc1_W, fc1_b, g1, 300, 300, 1);
  fc_kernel<<<N_GRAPHS, 768, 0, stream>>>(g1, fc2_W, fc2_b, (float*)d_out, 300, 768, 0);
}

// Round 12
// 563.421 us; speedup vs baseline: 1.8843x; 1.0347x over previous
//
#include <hip/hip_runtime.h>
#include <hip/hip_bf16.h>
#include <math.h>

#define N_NODES 50000
#define N_EDGES 800000
#define E_TOT   (N_EDGES + N_NODES)
#define N_GRAPHS 256
#define SLOPE 0.2f
#define NB_SCAN ((N_NODES + 255) / 256)
#define NPANEL 782            // ceil(50000/64)
#define WCOLS 768             // padded concatenated-W width
#define POOL_SPLIT 8
#define HSTRIDE 304           // fp16 h row stride (608B, 16B-aligned)

typedef __attribute__((ext_vector_type(4))) float f32x4;
typedef _Float16 f16x2 __attribute__((ext_vector_type(2)));
typedef _Float16 f16x4 __attribute__((ext_vector_type(4)));
typedef _Float16 f16x8 __attribute__((ext_vector_type(8)));

__device__ __forceinline__ void gl_lds16(const void* g, void* l) {
  __builtin_amdgcn_global_load_lds(
      (const __attribute__((address_space(1))) unsigned int*)g,
      (__attribute__((address_space(3))) unsigned int*)l, 16, 0, 0);
}

// ---- x -> panel-swizzled fp16 [p][kc=40][m=64][ki=8], zero-padded ----------
__global__ void conv_x(const float* __restrict__ x, _Float16* __restrict__ A) {
  int id = blockIdx.x * blockDim.x + threadIdx.x;
  const int total = NPANEL * 64 * 40;
  if (id >= total) return;
  int kc = id % 40;
  int m  = (id / 40) % 64;
  int p  = id / 2560;
  int n = p * 64 + m;
  f16x8 hv;
#pragma unroll
  for (int i = 0; i < 8; ++i) {
    int k = kc * 8 + i;
    float v = (n < N_NODES && k < 300) ? x[(size_t)n * 300 + k] : 0.f;
    hv[i] = (_Float16)v;
  }
  size_t ce = (((size_t)p * 40 + kc) * 64 + m) * 8;
  *(f16x8*)&A[ce] = hv;
}

// ---- all layers' Wl,Wr -> one contiguous fp16 buffer [gkc][WCOLS][8] -------
// layer kc bases: l0:[0,40) l1:[40,56) l2:[56,72) l3:[72,88)
__global__ void conv_w_all(const float* __restrict__ W0l, const float* __restrict__ W0r,
                           const float* __restrict__ W1l, const float* __restrict__ W1r,
                           const float* __restrict__ W2l, const float* __restrict__ W2r,
                           const float* __restrict__ W3l, const float* __restrict__ W3r,
                           _Float16* __restrict__ W) {
  int id = blockIdx.x * blockDim.x + threadIdx.x;
  if (id >= 88 * WCOLS) return;
  int n = id % WCOLS, gkc = id / WCOLS;
  int l, kc;
  if (gkc < 40)      { l = 0; kc = gkc; }
  else if (gkc < 56) { l = 1; kc = gkc - 40; }
  else if (gkc < 72) { l = 2; kc = gkc - 56; }
  else               { l = 3; kc = gkc - 72; }
  const float* Wl = (l == 0) ? W0l : (l == 1) ? W1l : (l == 2) ? W2l : W3l;
  const float* Wr = (l == 0) ? W0r : (l == 1) ? W1r : (l == 2) ? W2r : W3r;
  int K = (l == 0) ? 300 : 128;
  int C = (l == 3) ? 300 : 128;
  int NL = (l == 3) ? 304 : 128;
  f16x8 hv;
#pragma unroll
  for (int i = 0; i < 8; ++i) {
    int k = kc * 8 + i;
    float v = 0.f;
    if (k < K) {
      if (n < NL) { if (n < C) v = Wl[(size_t)k * C + n]; }
      else if (n < 2 * NL && (n - NL) < C) v = Wr[(size_t)k * C + (n - NL)];
    }
    hv[i] = (_Float16)v;
  }
  *(f16x8*)&W[(size_t)id * 8] = hv;
}

// ---- att (fp32) -> padded f16x2 tables, 192 entries per layer --------------
__global__ void conv_att(const float* __restrict__ a0, const float* __restrict__ a1,
                         const float* __restrict__ a2, const float* __restrict__ a3,
                         f16x2* __restrict__ att_h) {
  int t = blockIdx.x * blockDim.x + threadIdx.x;
  if (t >= 4 * 192) return;
  int l = t / 192, i = t % 192;
  const float* a = (l == 0) ? a0 : (l == 1) ? a1 : (l == 2) ? a2 : a3;
  int C = (l == 3) ? 300 : 128;
  int c = 2 * i;
  f16x2 r;
  r[0] = (c < C) ? (_Float16)a[c] : (_Float16)0.f;
  r[1] = (c + 1 < C) ? (_Float16)a[c + 1] : (_Float16)0.f;
  att_h[t] = r;
}

// ---- zero pad rows 50000..50047 of H panels (kcn=16) -----------------------
__global__ void zero_pad_H(_Float16* __restrict__ H) {
  int t = blockIdx.x * blockDim.x + threadIdx.x;
  if (t >= 48 * 16) return;
  int m = 16 + (t >> 4), kc = t & 15;
  size_t ce = (((size_t)781 * 16 + kc) * 64 + m) * 8;
  f16x8 z = {};
  *(f16x8*)&H[ce] = z;
}

// ---- zero stale cols 300..319 of the stride-320 layer-3 xl/xr buffers ------
__global__ void zero_xl_pad(_Float16* __restrict__ xlh, _Float16* __restrict__ xrh) {
  int t = blockIdx.x * blockDim.x + threadIdx.x;
  if (t >= N_NODES * 20) return;
  int r = t / 20, k = t % 20;
  size_t o = (size_t)r * 320 + 300 + k;
  xlh[o] = (_Float16)0.f;
  xrh[o] = (_Float16)0.f;
}

// ---- dual-output fp16 MFMA GEMM: [xl|xr] = A @ [Wl|Wr] + bias --------------
__global__ __launch_bounds__(256, 2) void gemm_dual(
    const _Float16* __restrict__ A, const _Float16* __restrict__ W,
    const float* __restrict__ biasl, const float* __restrict__ biasr,
    _Float16* __restrict__ xlh, _Float16* __restrict__ xrh,
    int Kp, int C, int NL, int CSg) {
  __shared__ _Float16 As[4][64][8];     // 4 KB
  __shared__ _Float16 Ws[4][256][8];    // 16 KB
  const int tid = threadIdx.x, wv = tid >> 6, lane = tid & 63;
  const int p = blockIdx.x, n0 = blockIdx.y * 256;
  const int kcn = Kp >> 3, nk = Kp >> 5;
  const size_t abase0 = (size_t)p * kcn * 512;
  const int rsel = lane >> 4, rrow = lane & 15;
  f32x4 z4 = {0.f, 0.f, 0.f, 0.f};
  f32x4 acc[4][4];
#pragma unroll
  for (int a = 0; a < 4; ++a)
#pragma unroll
    for (int b = 0; b < 4; ++b) acc[a][b] = z4;

  for (int s = 0; s < nk; ++s) {
    const size_t abase = abase0 + (size_t)s * 2048;
    for (int q = wv; q < 20; q += 4) {
      const _Float16* g;
      _Float16* l;
      if (q < 4) {
        g = A + abase + q * 512;
        l = &As[0][0][0] + q * 512;
      } else {
        int j = q - 4;                 // 0..15: row j>>2, col-block j&3
        g = W + ((size_t)(s * 4 + (j >> 2)) * WCOLS + n0 + (j & 3) * 64) * 8;
        l = &Ws[0][0][0] + j * 512;
      }
      gl_lds16(g + lane * 8, l);
    }
    __syncthreads();
    f16x8 af[4], bf[4];
#pragma unroll
    for (int mt = 0; mt < 4; ++mt)
      af[mt] = *(const f16x8*)&As[rsel][mt * 16 + rrow][0];
#pragma unroll
    for (int nt = 0; nt < 4; ++nt)
      bf[nt] = *(const f16x8*)&Ws[rsel][wv * 64 + nt * 16 + rrow][0];
#pragma unroll
    for (int mt = 0; mt < 4; ++mt)
#pragma unroll
      for (int nt = 0; nt < 4; ++nt)
        acc[mt][nt] = __builtin_amdgcn_mfma_f32_16x16x32_f16(af[mt], bf[nt], acc[mt][nt], 0, 0, 0);
    __syncthreads();
  }
#pragma unroll
  for (int mt = 0; mt < 4; ++mt) {
    int r0 = p * 64 + mt * 16 + rsel * 4;
#pragma unroll
    for (int nt = 0; nt < 4; ++nt) {
      int gc = n0 + wv * 64 + nt * 16 + rrow;
#pragma unroll
      for (int j = 0; j < 4; ++j) {
        int row = r0 + j;
        if (row >= N_NODES) continue;
        float v = acc[mt][nt][j];
        if (gc < NL) {
          if (gc < C) xlh[(size_t)row * CSg + gc] = (_Float16)(v + biasl[gc]);
        } else {
          int c2 = gc - NL;
          if (c2 >= 0 && c2 < C) xrh[(size_t)row * CSg + c2] = (_Float16)(v + biasr[c2]);
        }
      }
    }
  }
}

// ---------------- CSR build (once per launch) ---------------------------
__global__ void zero_ints(int* __restrict__ p, int n) {
  int i = blockIdx.x * blockDim.x + threadIdx.x;
  if (i < n) p[i] = 0;
}

__global__ void deg_count(const int* __restrict__ ei, int* __restrict__ deg) {
  int e = blockIdx.x * blockDim.x + threadIdx.x;
  if (e >= E_TOT) return;
  int d = (e < N_EDGES) ? ei[N_EDGES + e] : e - N_EDGES;
  atomicAdd(&deg[d], 1);
}

__global__ void scan1(const int* __restrict__ deg, int* __restrict__ rp,
                      int* __restrict__ bsum) {
  __shared__ int s[256];
  int i = blockIdx.x * 256 + threadIdx.x;
  int v = (i < N_NODES) ? deg[i] : 0;
  s[threadIdx.x] = v;
  __syncthreads();
  for (int off = 1; off < 256; off <<= 1) {
    int t = (threadIdx.x >= off) ? s[threadIdx.x - off] : 0;
    __syncthreads();
    s[threadIdx.x] += t;
    __syncthreads();
  }
  if (i < N_NODES) rp[i] = s[threadIdx.x] - v;
  if (threadIdx.x == 255) bsum[blockIdx.x] = s[255];
}

__global__ void scan2(int* __restrict__ bsum) {
  __shared__ int s[256];
  int v = (threadIdx.x < NB_SCAN) ? bsum[threadIdx.x] : 0;
  s[threadIdx.x] = v;
  __syncthreads();
  for (int off = 1; off < 256; off <<= 1) {
    int t = (threadIdx.x >= off) ? s[threadIdx.x - off] : 0;
    __syncthreads();
    s[threadIdx.x] += t;
    __syncthreads();
  }
  if (threadIdx.x < NB_SCAN) bsum[threadIdx.x] = s[threadIdx.x] - v;
}

__global__ void scan3(int* __restrict__ rp, const int* __restrict__ bsum,
                      int* __restrict__ cursor) {
  int i = blockIdx.x * 256 + threadIdx.x;
  if (i < N_NODES) {
    int v = rp[i] + bsum[blockIdx.x];
    rp[i] = v;
    cursor[i] = v;
  }
  if (i == 0) rp[N_NODES] = E_TOT;
}

__global__ void fill_csr(const int* __restrict__ ei, int* __restrict__ cursor,
                         int* __restrict__ csr_src) {
  int e = blockIdx.x * blockDim.x + threadIdx.x;
  if (e >= E_TOT) return;
  int s, d;
  if (e < N_EDGES) { s = ei[e]; d = ei[N_EDGES + e]; }
  else             { s = d = e - N_EDGES; }
  int pos = atomicAdd(&cursor[d], 1);
  csr_src[pos] = s;
}

// ---- row loader (C=128): one f16x8 per lane -------------------------------
__device__ __forceinline__ void load_row128(f16x2* dst, const _Float16* p) {
  f16x8 t = *(const f16x8*)p;
#pragma unroll
  for (int j = 0; j < 4; ++j) {
    f16x2 r; r[0] = t[2 * j]; r[1] = t[2 * j + 1]; dst[j] = r;
  }
}

// ---- row loader (C=300, chunked map): 16B+16B+8B per lane ------------------
// lane li covers channels [8li,8li+8) u [128+8li,+8) u [256+4li,+4)
__device__ __forceinline__ void load_row300(f16x2* dst, const _Float16* row, int li) {
  f16x8 a = *(const f16x8*)(row + 8 * li);
  f16x8 b = *(const f16x8*)(row + 128 + 8 * li);
  f16x4 c = *(const f16x4*)(row + 256 + 4 * li);
#pragma unroll
  for (int j = 0; j < 4; ++j) {
    f16x2 r; r[0] = a[2 * j]; r[1] = a[2 * j + 1]; dst[j] = r;
  }
#pragma unroll
  for (int j = 0; j < 4; ++j) {
    f16x2 r; r[0] = b[2 * j]; r[1] = b[2 * j + 1]; dst[4 + j] = r;
  }
  {
    f16x2 r; r[0] = c[0]; r[1] = c[1]; dst[8] = r;
    f16x2 r2; r2[0] = c[2]; r2[1] = c[3]; dst[9] = r2;
  }
}

// -------- fused GATv2 aggregation (C=128): 16 lanes/edge, 4 edges in flight,
// depth-2 row pipeline, deferred-max softmax, fp16 H-panel output ------------
__global__ __launch_bounds__(256) void gat128(
    const int* __restrict__ rowptr, const int* __restrict__ csr_src,
    const _Float16* __restrict__ xlh, const _Float16* __restrict__ xrh,
    const f16x2* __restrict__ att_h, const float* __restrict__ bias,
    _Float16* __restrict__ Hp) {
  int wid = (int)((blockIdx.x * (size_t)blockDim.x + threadIdx.x) >> 6);
  int lane = threadIdx.x & 63;
  if (wid >= N_NODES) return;
  const int g = lane >> 4, li = lane & 15;
  const int c0 = li * 8;
  int beg = rowptr[wid], end = rowptr[wid + 1];

  f16x2 xri[4], attc[4];
  load_row128(xri, xrh + (size_t)wid * 128 + c0);
#pragma unroll
  for (int j = 0; j < 4; ++j) attc[j] = att_h[(c0 >> 1) + j];

  float acc[8];
#pragma unroll
  for (int k = 0; k < 8; ++k) acc[k] = 0.f;
  float dsum = 0.f;
  const f16x2 slope2 = {(_Float16)SLOPE, (_Float16)SLOPE};
  const f16x2 zero2 = {(_Float16)0.f, (_Float16)0.f};

  int e = beg + g;
  f16x2 bufA[4], bufB[4];
  {
    int e0 = e < end ? e : end - 1;
    load_row128(bufA, xlh + (size_t)csr_src[e0] * 128 + c0);
  }
  {
    int e1 = e + 4 < end ? e + 4 : end - 1;
    load_row128(bufB, xlh + (size_t)csr_src[e1] * 128 + c0);
  }
  int nit = (end - beg + 3) >> 2;

  auto step = [&](f16x2* cur) {
    bool valid = e < end;
    float v = 0.f;
#pragma unroll
    for (int j = 0; j < 4; ++j) {
      f16x2 m2 = cur[j] + xri[j];
      f16x2 mx = __builtin_elementwise_max(m2, zero2);
      f16x2 mn = __builtin_elementwise_min(m2, zero2);
      f16x2 lr = mx + slope2 * mn;         // leaky_relu
#if __has_builtin(__builtin_amdgcn_fdot2)
      v = __builtin_amdgcn_fdot2(lr, attc[j], v, false);
#else
      v += (float)lr[0] * (float)attc[j][0] + (float)lr[1] * (float)attc[j][1];
#endif
    }
    v += __shfl_xor(v, 1);
    v += __shfl_xor(v, 2);
    v += __shfl_xor(v, 4);
    v += __shfl_xor(v, 8);
    float w = valid ? __expf(v) : 0.f;     // deferred max: |v| small, fp32-safe
    dsum += w;
#pragma unroll
    for (int j = 0; j < 4; ++j) {
      acc[2 * j]     += w * (float)cur[j][0];
      acc[2 * j + 1] += w * (float)cur[j][1];
    }
    if (e - g + 8 < end) {                 // wave-uniform prefetch condition
      int en = e + 8; if (en > end - 1) en = end - 1;
      load_row128(cur, xlh + (size_t)csr_src[en] * 128 + c0);
    }
    e += 4;
  };
  for (int it = 0; it < nit; it += 2) {
    step(bufA);
    if (it + 1 < nit) step(bufB);
  }

#pragma unroll
  for (int k = 0; k < 8; ++k) {
    acc[k] += __shfl_xor(acc[k], 16);
    acc[k] += __shfl_xor(acc[k], 32);
  }
  dsum += __shfl_xor(dsum, 16);
  dsum += __shfl_xor(dsum, 32);
  if (g != 0) return;
  float inv = 1.f / dsum;
  f16x8 hv;
#pragma unroll
  for (int k = 0; k < 8; ++k) {
    float vv = fmaxf(acc[k] * inv + bias[c0 + k], 0.f);
    hv[k] = (_Float16)vv;
  }
  int p = wid >> 6, mrow = wid & 63;
  size_t ce = (((size_t)p * 16 + li) * 64 + mrow) * 8;
  *(f16x8*)&Hp[ce] = hv;
}

// -------- fused GATv2 aggregation (C=300): chunked channel map, wide loads,
// depth-1 prefetch (R10-proven), fp16 h output (stride HSTRIDE) --------------
__global__ __launch_bounds__(256) void gat300(
    const int* __restrict__ rowptr, const int* __restrict__ csr_src,
    const _Float16* __restrict__ xlh, const _Float16* __restrict__ xrh,
    const f16x2* __restrict__ att_h, const float* __restrict__ bias,
    _Float16* __restrict__ hout) {
  int wid = (int)((blockIdx.x * (size_t)blockDim.x + threadIdx.x) >> 6);
  int lane = threadIdx.x & 63;
  if (wid >= N_NODES) return;
  const int g = lane >> 4, li = lane & 15;
  int beg = rowptr[wid], end = rowptr[wid + 1];

  f16x2 xri[10], attc[10];
  load_row300(xri, xrh + (size_t)wid * 320, li);
#pragma unroll
  for (int j = 0; j < 4; ++j) attc[j] = att_h[4 * li + j];
#pragma unroll
  for (int j = 0; j < 4; ++j) attc[4 + j] = att_h[64 + 4 * li + j];
  attc[8] = att_h[128 + 2 * li];
  attc[9] = att_h[128 + 2 * li + 1];

  float acc[20];
#pragma unroll
  for (int k = 0; k < 20; ++k) acc[k] = 0.f;
  float dsum = 0.f;
  const f16x2 slope2 = {(_Float16)SLOPE, (_Float16)SLOPE};
  const f16x2 zero2 = {(_Float16)0.f, (_Float16)0.f};

  int e = beg + g;
  f16x2 nxt[10];
  {
    int s = csr_src[e < end ? e : end - 1];
    load_row300(nxt, xlh + (size_t)s * 320, li);
  }
  int nit = (end - beg + 3) >> 2;
  for (int it = 0; it < nit; ++it) {
    f16x2 cur[10];
#pragma unroll
    for (int j = 0; j < 10; ++j) cur[j] = nxt[j];
    bool valid = e < end;
    if (beg + (it + 1) * 4 < end) {        // wave-uniform
      int en = e + 4;
      int s = csr_src[en < end ? en : end - 1];
      load_row300(nxt, xlh + (size_t)s * 320, li);
    }
    float v = 0.f;
#pragma unroll
    for (int j = 0; j < 10; ++j) {
      f16x2 m2 = cur[j] + xri[j];
      f16x2 mx = __builtin_elementwise_max(m2, zero2);
      f16x2 mn = __builtin_elementwise_min(m2, zero2);
      f16x2 lr = mx + slope2 * mn;         // leaky_relu
#if __has_builtin(__builtin_amdgcn_fdot2)
      v = __builtin_amdgcn_fdot2(lr, attc[j], v, false);
#else
      v += (float)lr[0] * (float)attc[j][0] + (float)lr[1] * (float)attc[j][1];
#endif
    }
    v += __shfl_xor(v, 1);
    v += __shfl_xor(v, 2);
    v += __shfl_xor(v, 4);
    v += __shfl_xor(v, 8);
    float w = valid ? __expf(v) : 0.f;
    dsum += w;
#pragma unroll
    for (int j = 0; j < 10; ++j) {
      acc[2 * j]     += w * (float)cur[j][0];
      acc[2 * j + 1] += w * (float)cur[j][1];
    }
    e += 4;
  }
#pragma unroll
  for (int k = 0; k < 20; ++k) {
    acc[k] += __shfl_xor(acc[k], 16);
    acc[k] += __shfl_xor(acc[k], 32);
  }
  dsum += __shfl_xor(dsum, 16);
  dsum += __shfl_xor(dsum, 32);
  if (g != 0) return;
  float inv = 1.f / dsum;
  // mapped channels: k<8 -> 8li+k; k<16 -> 128+8li+(k-8); else 256+4li+(k-16)
  f16x8 h1, h2;
  f16x4 h3;
#pragma unroll
  for (int k = 0; k < 8; ++k)
    h1[k] = (_Float16)fmaxf(acc[k] * inv + bias[8 * li + k], 0.f);
#pragma unroll
  for (int k = 0; k < 8; ++k)
    h2[k] = (_Float16)fmaxf(acc[8 + k] * inv + bias[128 + 8 * li + k], 0.f);
  if (li <= 10) {
#pragma unroll
    for (int k = 0; k < 4; ++k)
      h3[k] = (_Float16)fmaxf(acc[16 + k] * inv + bias[256 + 4 * li + k], 0.f);
  }
  _Float16* hr = hout + (size_t)wid * HSTRIDE;
  *(f16x8*)(hr + 8 * li) = h1;
  *(f16x8*)(hr + 128 + 8 * li) = h2;
  if (li <= 10) *(f16x4*)(hr + 256 + 4 * li) = h3;   // ch 300+ skipped
}

// ------------- global mean pool (batch sorted), split + unrolled --------
__device__ int lower_bound_dev(const int* a, int n, int v) {
  int lo = 0, hi = n;
  while (lo < hi) { int mid = (lo + hi) >> 1; if (a[mid] < v) lo = mid + 1; else hi = mid; }
  return lo;
}

__global__ void pool_sum(const _Float16* __restrict__ h, const int* __restrict__ batch,
                         float* __restrict__ gsum) {
  int gi = blockIdx.x;
  int sp = blockIdx.y;
  int c = threadIdx.x;
  if (c >= 300) return;
  int start = lower_bound_dev(batch, N_NODES, gi);
  int end   = lower_bound_dev(batch, N_NODES, gi + 1);
  int len = end - start;
  int chunk = (len + POOL_SPLIT - 1) / POOL_SPLIT;
  int a = start + sp * chunk;
  int b = a + chunk; if (b > end) b = end;
  if (a >= b) return;
  float s0 = 0.f, s1 = 0.f, s2 = 0.f, s3 = 0.f;
  int n = a;
  for (; n + 3 < b; n += 4) {
    s0 += (float)h[(size_t)n * HSTRIDE + c];
    s1 += (float)h[(size_t)(n + 1) * HSTRIDE + c];
    s2 += (float)h[(size_t)(n + 2) * HSTRIDE + c];
    s3 += (float)h[(size_t)(n + 3) * HSTRIDE + c];
  }
  for (; n < b; ++n) s0 += (float)h[(size_t)n * HSTRIDE + c];
  atomicAdd(&gsum[(size_t)gi * 300 + c], (s0 + s1) + (s2 + s3));
}

__global__ void pool_final(float* __restrict__ gsum, const int* __restrict__ batch) {
  int t = blockIdx.x * blockDim.x + threadIdx.x;
  if (t >= N_GRAPHS * 300) return;
  int gi = t / 300;
  int start = lower_bound_dev(batch, N_NODES, gi);
  int end   = lower_bound_dev(batch, N_NODES, gi + 1);
  int cnt = end - start;
  gsum[t] = gsum[t] / (float)(cnt > 0 ? cnt : 1);
}

// ------------- small per-graph FC ---------------------------------------
__global__ void fc_kernel(const float* __restrict__ g, const float* __restrict__ W,
                          const float* __restrict__ b, float* __restrict__ out,
                          int K, int N, int do_relu) {
  __shared__ float row[304];
  int gi = blockIdx.x;
  for (int k = threadIdx.x; k < K; k += blockDim.x) row[k] = g[(size_t)gi * K + k];
  __syncthreads();
  int c = threadIdx.x;
  if (c >= N) return;
  float s = b[c];
  for (int k = 0; k < K; ++k) s += row[k] * W[(size_t)k * N + c];
  if (do_relu) s = fmaxf(s, 0.f);
  out[(size_t)gi * N + c] = s;
}

extern "C" void kernel_launch(void* const* d_in, const int* in_sizes, int n_in,
                              void* d_out, int out_size, void* d_ws, size_t ws_size,
                              hipStream_t stream) {
  const float* x     = (const float*)d_in[0];
  const int*   ei    = (const int*)d_in[1];
  const int*   batch = (const int*)d_in[2];
  const float* Wl[4], *bl[4], *Wr[4], *br[4], *att[4], *bias[4];
  for (int l = 0; l < 4; ++l) {
    Wl[l]   = (const float*)d_in[3 + l * 6 + 0];
    bl[l]   = (const float*)d_in[3 + l * 6 + 1];
    Wr[l]   = (const float*)d_in[3 + l * 6 + 2];
    br[l]   = (const float*)d_in[3 + l * 6 + 3];
    att[l]  = (const float*)d_in[3 + l * 6 + 4];
    bias[l] = (const float*)d_in[3 + l * 6 + 5];
  }
  const float* fc1_W = (const float*)d_in[27];
  const float* fc1_b = (const float*)d_in[28];
  const float* fc2_W = (const float*)d_in[29];
  const float* fc2_b = (const float*)d_in[30];

  char* wsb = (char*)d_ws;
  size_t off = 0;
  auto alloc = [&](size_t bytes) {
    void* p = (void*)(wsb + off);
    off += (bytes + 63) & ~(size_t)63;
    return p;
  };
  // fp16 xl/xr, stride up to 320 (layer 3); layers 0-2 use stride 128
  _Float16* xlh = (_Float16*)alloc((size_t)N_NODES * 320 * 2);
  _Float16* xrh = (_Float16*)alloc((size_t)N_NODES * 320 * 2);
  _Float16* A0  = (_Float16*)alloc((size_t)NPANEL * 40 * 512 * 2);  // 32 MB
  _Float16* Hp  = (_Float16*)alloc((size_t)NPANEL * 16 * 512 * 2);  // 12.8 MB
  _Float16* hbuf = (_Float16*)alloc((size_t)N_NODES * HSTRIDE * 2); // 30.4 MB
  float* gpool  = (float*)alloc((size_t)N_GRAPHS * 300 * 4);
  float* g1     = (float*)alloc((size_t)N_GRAPHS * 300 * 4);
  f16x2* att_h  = (f16x2*)alloc((size_t)4 * 192 * 4);
  _Float16* Wbuf = (_Float16*)alloc((size_t)88 * WCOLS * 8 * 2);    // 1.1 MB
  const int Cdim[4] = {128, 128, 128, 300};
  const int NLv[4]  = {128, 128, 128, 304};
  const int Kpv[4]  = {320, 128, 128, 128};
  const int CSg[4]  = {128, 128, 128, 320};
  const int Wbase[4] = {0, 40, 56, 72};   // kc offsets in Wbuf
  int* deg     = (int*)alloc((size_t)N_NODES * 4);
  int* rowptr  = (int*)alloc((size_t)(N_NODES + 1) * 4);
  int* bsum    = (int*)alloc(256 * 4);
  int* cursor  = (int*)alloc((size_t)N_NODES * 4);
  int* csr_src = (int*)alloc((size_t)E_TOT * 4);

  // one-time conversions
  conv_x<<<(NPANEL * 64 * 40 + 255) / 256, 256, 0, stream>>>(x, A0);
  conv_w_all<<<(88 * WCOLS + 255) / 256, 256, 0, stream>>>(
      Wl[0], Wr[0], Wl[1], Wr[1], Wl[2], Wr[2], Wl[3], Wr[3], Wbuf);
  conv_att<<<3, 256, 0, stream>>>(att[0], att[1], att[2], att[3], att_h);
  zero_pad_H<<<3, 256, 0, stream>>>(Hp);

  // CSR build
  zero_ints<<<(N_NODES + 255) / 256, 256, 0, stream>>>(deg, N_NODES);
  deg_count<<<(E_TOT + 255) / 256, 256, 0, stream>>>(ei, deg);
  scan1<<<NB_SCAN, 256, 0, stream>>>(deg, rowptr, bsum);
  scan2<<<1, 256, 0, stream>>>(bsum);
  scan3<<<NB_SCAN, 256, 0, stream>>>(rowptr, bsum, cursor);
  fill_csr<<<(E_TOT + 255) / 256, 256, 0, stream>>>(ei, cursor, csr_src);
  // zero the pool accumulator early (fp32 zero == all-zero bits)
  zero_ints<<<(N_GRAPHS * 300 + 255) / 256, 256, 0, stream>>>((int*)gpool, N_GRAPHS * 300);

  const int nwave_blocks = (N_NODES + 3) / 4;
  for (int l = 0; l < 4; ++l) {
    const _Float16* Ain = (l == 0) ? A0 : Hp;
    const _Float16* Wp = Wbuf + (size_t)Wbase[l] * WCOLS * 8;
    int ny = (2 * NLv[l] + 255) / 256;
    dim3 gg(NPANEL, ny);
    gemm_dual<<<gg, 256, 0, stream>>>(Ain, Wp, bl[l], br[l],
                                      xlh, xrh, Kpv[l], Cdim[l], NLv[l], CSg[l]);
    if (l < 3) {
      gat128<<<nwave_blocks, 256, 0, stream>>>(
          rowptr, csr_src, xlh, xrh, att_h + l * 192, bias[l], Hp);
    } else {
      // zero stale cols 300..319 of stride-320 rows (never written by gemm)
      zero_xl_pad<<<(N_NODES * 20 + 255) / 256, 256, 0, stream>>>(xlh, xrh);
      gat300<<<nwave_blocks, 256, 0, stream>>>(
          rowptr, csr_src, xlh, xrh, att_h + l * 192, bias[l], hbuf);
    }
  }
  {
    dim3 pg(N_GRAPHS, POOL_SPLIT);
    pool_sum<<<pg, 320, 0, stream>>>(hbuf, batch, gpool);
    pool_final<<<(N_GRAPHS * 300 + 255) / 256, 256, 0, stream>>>(gpool, batch);
  }
  fc_kernel<<<N_GRAPHS, 320, 0, stream>>>(gpool, fc1_W, fc1_b, g1, 300, 300, 1);
  fc_kernel<<<N_GRAPHS, 768, 0, stream>>>(g1, fc2_W, fc2_b, (float*)d_out, 300, 768, 0);
}

// Round 13
// 560.202 us; speedup vs baseline: 1.8952x; 1.0057x over previous
//
#include <hip/hip_runtime.h>
#include <hip/hip_bf16.h>
#include <math.h>

#define N_NODES 50000
#define N_EDGES 800000
#define E_TOT   (N_EDGES + N_NODES)
#define N_GRAPHS 256
#define SLOPE 0.2f
#define NB_SCAN ((N_NODES + 255) / 256)
#define NPANEL 782            // ceil(50000/64)
#define WCOLS 768             // padded concatenated-W width
#define POOL_SPLIT 8
#define HSTRIDE 304           // fp16 h row stride (608B, 16B-aligned)
#define XSTRIDE 304           // fp16 xl/xr row stride for layer 3

typedef __attribute__((ext_vector_type(4))) float f32x4;
typedef _Float16 f16x2 __attribute__((ext_vector_type(2)));
typedef _Float16 f16x4 __attribute__((ext_vector_type(4)));
typedef _Float16 f16x8 __attribute__((ext_vector_type(8)));

__device__ __forceinline__ void gl_lds16(const void* g, void* l) {
  __builtin_amdgcn_global_load_lds(
      (const __attribute__((address_space(1))) unsigned int*)g,
      (__attribute__((address_space(3))) unsigned int*)l, 16, 0, 0);
}

// ---- x -> panel-swizzled fp16 [p][kc=40][m=64][ki=8], zero-padded ----------
__global__ void conv_x(const float* __restrict__ x, _Float16* __restrict__ A) {
  int id = blockIdx.x * blockDim.x + threadIdx.x;
  const int total = NPANEL * 64 * 40;
  if (id >= total) return;
  int kc = id % 40;
  int m  = (id / 40) % 64;
  int p  = id / 2560;
  int n = p * 64 + m;
  f16x8 hv;
#pragma unroll
  for (int i = 0; i < 8; ++i) {
    int k = kc * 8 + i;
    float v = (n < N_NODES && k < 300) ? x[(size_t)n * 300 + k] : 0.f;
    hv[i] = (_Float16)v;
  }
  size_t ce = (((size_t)p * 40 + kc) * 64 + m) * 8;
  *(f16x8*)&A[ce] = hv;
}

// ---- all layers' Wl,Wr -> one contiguous fp16 buffer [gkc][WCOLS][8] -------
// layer kc bases: l0:[0,40) l1:[40,56) l2:[56,72) l3:[72,88)
__global__ void conv_w_all(const float* __restrict__ W0l, const float* __restrict__ W0r,
                           const float* __restrict__ W1l, const float* __restrict__ W1r,
                           const float* __restrict__ W2l, const float* __restrict__ W2r,
                           const float* __restrict__ W3l, const float* __restrict__ W3r,
                           _Float16* __restrict__ W) {
  int id = blockIdx.x * blockDim.x + threadIdx.x;
  if (id >= 88 * WCOLS) return;
  int n = id % WCOLS, gkc = id / WCOLS;
  int l, kc;
  if (gkc < 40)      { l = 0; kc = gkc; }
  else if (gkc < 56) { l = 1; kc = gkc - 40; }
  else if (gkc < 72) { l = 2; kc = gkc - 56; }
  else               { l = 3; kc = gkc - 72; }
  const float* Wl = (l == 0) ? W0l : (l == 1) ? W1l : (l == 2) ? W2l : W3l;
  const float* Wr = (l == 0) ? W0r : (l == 1) ? W1r : (l == 2) ? W2r : W3r;
  int K = (l == 0) ? 300 : 128;
  int C = (l == 3) ? 300 : 128;
  int NL = (l == 3) ? 304 : 128;
  f16x8 hv;
#pragma unroll
  for (int i = 0; i < 8; ++i) {
    int k = kc * 8 + i;
    float v = 0.f;
    if (k < K) {
      if (n < NL) { if (n < C) v = Wl[(size_t)k * C + n]; }
      else if (n < 2 * NL && (n - NL) < C) v = Wr[(size_t)k * C + (n - NL)];
    }
    hv[i] = (_Float16)v;
  }
  *(f16x8*)&W[(size_t)id * 8] = hv;
}

// ---- att (fp32) -> padded f16x2 tables, 192 entries per layer --------------
__global__ void conv_att(const float* __restrict__ a0, const float* __restrict__ a1,
                         const float* __restrict__ a2, const float* __restrict__ a3,
                         f16x2* __restrict__ att_h) {
  int t = blockIdx.x * blockDim.x + threadIdx.x;
  if (t >= 4 * 192) return;
  int l = t / 192, i = t % 192;
  const float* a = (l == 0) ? a0 : (l == 1) ? a1 : (l == 2) ? a2 : a3;
  int C = (l == 3) ? 300 : 128;
  int c = 2 * i;
  f16x2 r;
  r[0] = (c < C) ? (_Float16)a[c] : (_Float16)0.f;
  r[1] = (c + 1 < C) ? (_Float16)a[c + 1] : (_Float16)0.f;
  att_h[t] = r;
}

// ---- zero pad rows 50000..50047 of H panels (kcn=16) -----------------------
__global__ void zero_pad_H(_Float16* __restrict__ H) {
  int t = blockIdx.x * blockDim.x + threadIdx.x;
  if (t >= 48 * 16) return;
  int m = 16 + (t >> 4), kc = t & 15;
  size_t ce = (((size_t)781 * 16 + kc) * 64 + m) * 8;
  f16x8 z = {};
  *(f16x8*)&H[ce] = z;
}

// ---- dual-output fp16 MFMA GEMM: [xl|xr] = A @ [Wl|Wr] + bias --------------
__global__ __launch_bounds__(256, 2) void gemm_dual(
    const _Float16* __restrict__ A, const _Float16* __restrict__ W,
    const float* __restrict__ biasl, const float* __restrict__ biasr,
    _Float16* __restrict__ xlh, _Float16* __restrict__ xrh,
    int Kp, int C, int NL, int CSg) {
  __shared__ _Float16 As[4][64][8];     // 4 KB
  __shared__ _Float16 Ws[4][256][8];    // 16 KB
  const int tid = threadIdx.x, wv = tid >> 6, lane = tid & 63;
  const int p = blockIdx.x, n0 = blockIdx.y * 256;
  const int kcn = Kp >> 3, nk = Kp >> 5;
  const size_t abase0 = (size_t)p * kcn * 512;
  const int rsel = lane >> 4, rrow = lane & 15;
  f32x4 z4 = {0.f, 0.f, 0.f, 0.f};
  f32x4 acc[4][4];
#pragma unroll
  for (int a = 0; a < 4; ++a)
#pragma unroll
    for (int b = 0; b < 4; ++b) acc[a][b] = z4;

  for (int s = 0; s < nk; ++s) {
    const size_t abase = abase0 + (size_t)s * 2048;
    for (int q = wv; q < 20; q += 4) {
      const _Float16* g;
      _Float16* l;
      if (q < 4) {
        g = A + abase + q * 512;
        l = &As[0][0][0] + q * 512;
      } else {
        int j = q - 4;                 // 0..15: row j>>2, col-block j&3
        g = W + ((size_t)(s * 4 + (j >> 2)) * WCOLS + n0 + (j & 3) * 64) * 8;
        l = &Ws[0][0][0] + j * 512;
      }
      gl_lds16(g + lane * 8, l);
    }
    __syncthreads();
    f16x8 af[4], bf[4];
#pragma unroll
    for (int mt = 0; mt < 4; ++mt)
      af[mt] = *(const f16x8*)&As[rsel][mt * 16 + rrow][0];
#pragma unroll
    for (int nt = 0; nt < 4; ++nt)
      bf[nt] = *(const f16x8*)&Ws[rsel][wv * 64 + nt * 16 + rrow][0];
#pragma unroll
    for (int mt = 0; mt < 4; ++mt)
#pragma unroll
      for (int nt = 0; nt < 4; ++nt)
        acc[mt][nt] = __builtin_amdgcn_mfma_f32_16x16x32_f16(af[mt], bf[nt], acc[mt][nt], 0, 0, 0);
    __syncthreads();
  }
#pragma unroll
  for (int mt = 0; mt < 4; ++mt) {
    int r0 = p * 64 + mt * 16 + rsel * 4;
#pragma unroll
    for (int nt = 0; nt < 4; ++nt) {
      int gc = n0 + wv * 64 + nt * 16 + rrow;
#pragma unroll
      for (int j = 0; j < 4; ++j) {
        int row = r0 + j;
        if (row >= N_NODES) continue;
        float v = acc[mt][nt][j];
        if (gc < NL) {
          if (gc < C) xlh[(size_t)row * CSg + gc] = (_Float16)(v + biasl[gc]);
        } else {
          int c2 = gc - NL;
          if (c2 >= 0 && c2 < C) xrh[(size_t)row * CSg + c2] = (_Float16)(v + biasr[c2]);
        }
      }
    }
  }
}

// ---------------- CSR build (once per launch) ---------------------------
__global__ void zero_ints(int* __restrict__ p, int n) {
  int i = blockIdx.x * blockDim.x + threadIdx.x;
  if (i < n) p[i] = 0;
}

__global__ void deg_count(const int* __restrict__ ei, int* __restrict__ deg) {
  int e = blockIdx.x * blockDim.x + threadIdx.x;
  if (e >= E_TOT) return;
  int d = (e < N_EDGES) ? ei[N_EDGES + e] : e - N_EDGES;
  atomicAdd(&deg[d], 1);
}

__global__ void scan1(const int* __restrict__ deg, int* __restrict__ rp,
                      int* __restrict__ bsum) {
  __shared__ int s[256];
  int i = blockIdx.x * 256 + threadIdx.x;
  int v = (i < N_NODES) ? deg[i] : 0;
  s[threadIdx.x] = v;
  __syncthreads();
  for (int off = 1; off < 256; off <<= 1) {
    int t = (threadIdx.x >= off) ? s[threadIdx.x - off] : 0;
    __syncthreads();
    s[threadIdx.x] += t;
    __syncthreads();
  }
  if (i < N_NODES) rp[i] = s[threadIdx.x] - v;
  if (threadIdx.x == 255) bsum[blockIdx.x] = s[255];
}

__global__ void scan2(int* __restrict__ bsum) {
  __shared__ int s[256];
  int v = (threadIdx.x < NB_SCAN) ? bsum[threadIdx.x] : 0;
  s[threadIdx.x] = v;
  __syncthreads();
  for (int off = 1; off < 256; off <<= 1) {
    int t = (threadIdx.x >= off) ? s[threadIdx.x - off] : 0;
    __syncthreads();
    s[threadIdx.x] += t;
    __syncthreads();
  }
  if (threadIdx.x < NB_SCAN) bsum[threadIdx.x] = s[threadIdx.x] - v;
}

__global__ void scan3(int* __restrict__ rp, const int* __restrict__ bsum,
                      int* __restrict__ cursor) {
  int i = blockIdx.x * 256 + threadIdx.x;
  if (i < N_NODES) {
    int v = rp[i] + bsum[blockIdx.x];
    rp[i] = v;
    cursor[i] = v;
  }
  if (i == 0) rp[N_NODES] = E_TOT;
}

__global__ void fill_csr(const int* __restrict__ ei, int* __restrict__ cursor,
                         int* __restrict__ csr_src) {
  int e = blockIdx.x * blockDim.x + threadIdx.x;
  if (e >= E_TOT) return;
  int s, d;
  if (e < N_EDGES) { s = ei[e]; d = ei[N_EDGES + e]; }
  else             { s = d = e - N_EDGES; }
  int pos = atomicAdd(&cursor[d], 1);
  csr_src[pos] = s;
}

// ---- row loader (C=128): one f16x8 per lane -------------------------------
__device__ __forceinline__ void load_row128(f16x2* dst, const _Float16* p) {
  f16x8 t = *(const f16x8*)p;
#pragma unroll
  for (int j = 0; j < 4; ++j) {
    f16x2 r; r[0] = t[2 * j]; r[1] = t[2 * j + 1]; dst[j] = r;
  }
}

// ---- row loader (C=300, chunked map): 16B+16B+8B per lane ------------------
// lane li covers channels [8li,8li+8) u [128+8li,+8) u [256+4li,+4)
// NOTE (XSTRIDE=304): lanes li>=11 over-read into pad cols 300..303 (stale,
// finite fp16) or the next row's leading channels; att=0 there and the
// corresponding acc slots are never written out, so values are nullified.
__device__ __forceinline__ void load_row300(f16x2* dst, const _Float16* row, int li) {
  f16x8 a = *(const f16x8*)(row + 8 * li);
  f16x8 b = *(const f16x8*)(row + 128 + 8 * li);
  f16x4 c = *(const f16x4*)(row + 256 + 4 * li);
#pragma unroll
  for (int j = 0; j < 4; ++j) {
    f16x2 r; r[0] = a[2 * j]; r[1] = a[2 * j + 1]; dst[j] = r;
  }
#pragma unroll
  for (int j = 0; j < 4; ++j) {
    f16x2 r; r[0] = b[2 * j]; r[1] = b[2 * j + 1]; dst[4 + j] = r;
  }
  {
    f16x2 r; r[0] = c[0]; r[1] = c[1]; dst[8] = r;
    f16x2 r2; r2[0] = c[2]; r2[1] = c[3]; dst[9] = r2;
  }
}

// -------- fused GATv2 aggregation (C=128): 16 lanes/edge, 4 edges in flight,
// depth-2 row pipeline, deferred-max softmax, fp16 H-panel output ------------
__global__ __launch_bounds__(256) void gat128(
    const int* __restrict__ rowptr, const int* __restrict__ csr_src,
    const _Float16* __restrict__ xlh, const _Float16* __restrict__ xrh,
    const f16x2* __restrict__ att_h, const float* __restrict__ bias,
    _Float16* __restrict__ Hp) {
  int wid = (int)((blockIdx.x * (size_t)blockDim.x + threadIdx.x) >> 6);
  int lane = threadIdx.x & 63;
  if (wid >= N_NODES) return;
  const int g = lane >> 4, li = lane & 15;
  const int c0 = li * 8;
  int beg = rowptr[wid], end = rowptr[wid + 1];

  f16x2 xri[4], attc[4];
  load_row128(xri, xrh + (size_t)wid * 128 + c0);
#pragma unroll
  for (int j = 0; j < 4; ++j) attc[j] = att_h[(c0 >> 1) + j];

  float acc[8];
#pragma unroll
  for (int k = 0; k < 8; ++k) acc[k] = 0.f;
  float dsum = 0.f;
  const f16x2 slope2 = {(_Float16)SLOPE, (_Float16)SLOPE};

  int e = beg + g;
  f16x2 bufA[4], bufB[4];
  {
    int e0 = e < end ? e : end - 1;
    load_row128(bufA, xlh + (size_t)csr_src[e0] * 128 + c0);
  }
  {
    int e1 = e + 4 < end ? e + 4 : end - 1;
    load_row128(bufB, xlh + (size_t)csr_src[e1] * 128 + c0);
  }
  int nit = (end - beg + 3) >> 2;

  auto step = [&](f16x2* cur) {
    bool valid = e < end;
    float v = 0.f;
#pragma unroll
    for (int j = 0; j < 4; ++j) {
      f16x2 m2 = cur[j] + xri[j];
      f16x2 lr = __builtin_elementwise_max(m2, slope2 * m2);  // leaky (slope<1)
#if __has_builtin(__builtin_amdgcn_fdot2)
      v = __builtin_amdgcn_fdot2(lr, attc[j], v, false);
#else
      v += (float)lr[0] * (float)attc[j][0] + (float)lr[1] * (float)attc[j][1];
#endif
    }
    v += __shfl_xor(v, 1);
    v += __shfl_xor(v, 2);
    v += __shfl_xor(v, 4);
    v += __shfl_xor(v, 8);
    float w = valid ? __expf(v) : 0.f;     // deferred max: |v| small, fp32-safe
    dsum += w;
#pragma unroll
    for (int j = 0; j < 4; ++j) {
      acc[2 * j]     += w * (float)cur[j][0];
      acc[2 * j + 1] += w * (float)cur[j][1];
    }
    if (e - g + 8 < end) {                 // wave-uniform prefetch condition
      int en = e + 8; if (en > end - 1) en = end - 1;
      load_row128(cur, xlh + (size_t)csr_src[en] * 128 + c0);
    }
    e += 4;
  };
  for (int it = 0; it < nit; it += 2) {
    step(bufA);
    if (it + 1 < nit) step(bufB);
  }

#pragma unroll
  for (int k = 0; k < 8; ++k) {
    acc[k] += __shfl_xor(acc[k], 16);
    acc[k] += __shfl_xor(acc[k], 32);
  }
  dsum += __shfl_xor(dsum, 16);
  dsum += __shfl_xor(dsum, 32);
  if (g != 0) return;
  float inv = 1.f / dsum;
  f16x8 hv;
#pragma unroll
  for (int k = 0; k < 8; ++k) {
    float vv = fmaxf(acc[k] * inv + bias[c0 + k], 0.f);
    hv[k] = (_Float16)vv;
  }
  int p = wid >> 6, mrow = wid & 63;
  size_t ce = (((size_t)p * 16 + li) * 64 + mrow) * 8;
  *(f16x8*)&Hp[ce] = hv;
}

// -------- fused GATv2 aggregation (C=300): chunked channel map, wide loads,
// depth-1 prefetch (R10-proven), fp16 h output (stride HSTRIDE) --------------
__global__ __launch_bounds__(256) void gat300(
    const int* __restrict__ rowptr, const int* __restrict__ csr_src,
    const _Float16* __restrict__ xlh, const _Float16* __restrict__ xrh,
    const f16x2* __restrict__ att_h, const float* __restrict__ bias,
    _Float16* __restrict__ hout) {
  int wid = (int)((blockIdx.x * (size_t)blockDim.x + threadIdx.x) >> 6);
  int lane = threadIdx.x & 63;
  if (wid >= N_NODES) return;
  const int g = lane >> 4, li = lane & 15;
  int beg = rowptr[wid], end = rowptr[wid + 1];

  f16x2 xri[10], attc[10];
  load_row300(xri, xrh + (size_t)wid * XSTRIDE, li);
#pragma unroll
  for (int j = 0; j < 4; ++j) attc[j] = att_h[4 * li + j];
#pragma unroll
  for (int j = 0; j < 4; ++j) attc[4 + j] = att_h[64 + 4 * li + j];
  attc[8] = att_h[128 + 2 * li];
  attc[9] = att_h[128 + 2 * li + 1];

  float acc[20];
#pragma unroll
  for (int k = 0; k < 20; ++k) acc[k] = 0.f;
  float dsum = 0.f;
  const f16x2 slope2 = {(_Float16)SLOPE, (_Float16)SLOPE};

  int e = beg + g;
  f16x2 nxt[10];
  {
    int s = csr_src[e < end ? e : end - 1];
    load_row300(nxt, xlh + (size_t)s * XSTRIDE, li);
  }
  int nit = (end - beg + 3) >> 2;
  for (int it = 0; it < nit; ++it) {
    f16x2 cur[10];
#pragma unroll
    for (int j = 0; j < 10; ++j) cur[j] = nxt[j];
    bool valid = e < end;
    if (beg + (it + 1) * 4 < end) {        // wave-uniform
      int en = e + 4;
      int s = csr_src[en < end ? en : end - 1];
      load_row300(nxt, xlh + (size_t)s * XSTRIDE, li);
    }
    float v = 0.f;
#pragma unroll
    for (int j = 0; j < 10; ++j) {
      f16x2 m2 = cur[j] + xri[j];
      f16x2 lr = __builtin_elementwise_max(m2, slope2 * m2);  // leaky (slope<1)
#if __has_builtin(__builtin_amdgcn_fdot2)
      v = __builtin_amdgcn_fdot2(lr, attc[j], v, false);
#else
      v += (float)lr[0] * (float)attc[j][0] + (float)lr[1] * (float)attc[j][1];
#endif
    }
    v += __shfl_xor(v, 1);
    v += __shfl_xor(v, 2);
    v += __shfl_xor(v, 4);
    v += __shfl_xor(v, 8);
    float w = valid ? __expf(v) : 0.f;
    dsum += w;
#pragma unroll
    for (int j = 0; j < 10; ++j) {
      acc[2 * j]     += w * (float)cur[j][0];
      acc[2 * j + 1] += w * (float)cur[j][1];
    }
    e += 4;
  }
#pragma unroll
  for (int k = 0; k < 20; ++k) {
    acc[k] += __shfl_xor(acc[k], 16);
    acc[k] += __shfl_xor(acc[k], 32);
  }
  dsum += __shfl_xor(dsum, 16);
  dsum += __shfl_xor(dsum, 32);
  if (g != 0) return;
  float inv = 1.f / dsum;
  // mapped channels: k<8 -> 8li+k; k<16 -> 128+8li+(k-8); else 256+4li+(k-16)
  f16x8 h1, h2;
  f16x4 h3;
#pragma unroll
  for (int k = 0; k < 8; ++k)
    h1[k] = (_Float16)fmaxf(acc[k] * inv + bias[8 * li + k], 0.f);
#pragma unroll
  for (int k = 0; k < 8; ++k)
    h2[k] = (_Float16)fmaxf(acc[8 + k] * inv + bias[128 + 8 * li + k], 0.f);
  if (li <= 10) {
#pragma unroll
    for (int k = 0; k < 4; ++k)
      h3[k] = (_Float16)fmaxf(acc[16 + k] * inv + bias[256 + 4 * li + k], 0.f);
  }
  _Float16* hr = hout + (size_t)wid * HSTRIDE;
  *(f16x8*)(hr + 8 * li) = h1;
  *(f16x8*)(hr + 128 + 8 * li) = h2;
  if (li <= 10) *(f16x4*)(hr + 256 + 4 * li) = h3;   // ch 300+ skipped
}

// ------------- global mean pool (batch sorted), split + unrolled --------
__device__ int lower_bound_dev(const int* a, int n, int v) {
  int lo = 0, hi = n;
  while (lo < hi) { int mid = (lo + hi) >> 1; if (a[mid] < v) lo = mid + 1; else hi = mid; }
  return lo;
}

__global__ void pool_sum(const _Float16* __restrict__ h, const int* __restrict__ batch,
                         float* __restrict__ gsum) {
  int gi = blockIdx.x;
  int sp = blockIdx.y;
  int c = threadIdx.x;
  if (c >= 300) return;
  int start = lower_bound_dev(batch, N_NODES, gi);
  int end   = lower_bound_dev(batch, N_NODES, gi + 1);
  int len = end - start;
  int chunk = (len + POOL_SPLIT - 1) / POOL_SPLIT;
  int a = start + sp * chunk;
  int b = a + chunk; if (b > end) b = end;
  if (a >= b) return;
  float s0 = 0.f, s1 = 0.f, s2 = 0.f, s3 = 0.f;
  int n = a;
  for (; n + 3 < b; n += 4) {
    s0 += (float)h[(size_t)n * HSTRIDE + c];
    s1 += (float)h[(size_t)(n + 1) * HSTRIDE + c];
    s2 += (float)h[(size_t)(n + 2) * HSTRIDE + c];
    s3 += (float)h[(size_t)(n + 3) * HSTRIDE + c];
  }
  for (; n < b; ++n) s0 += (float)h[(size_t)n * HSTRIDE + c];
  atomicAdd(&gsum[(size_t)gi * 300 + c], (s0 + s1) + (s2 + s3));
}

__global__ void pool_final(float* __restrict__ gsum, const int* __restrict__ batch) {
  int t = blockIdx.x * blockDim.x + threadIdx.x;
  if (t >= N_GRAPHS * 300) return;
  int gi = t / 300;
  int start = lower_bound_dev(batch, N_NODES, gi);
  int end   = lower_bound_dev(batch, N_NODES, gi + 1);
  int cnt = end - start;
  gsum[t] = gsum[t] / (float)(cnt > 0 ? cnt : 1);
}

// ------------- small per-graph FC ---------------------------------------
__global__ void fc_kernel(const float* __restrict__ g, const float* __restrict__ W,
                          const float* __restrict__ b, float* __restrict__ out,
                          int K, int N, int do_relu) {
  __shared__ float row[304];
  int gi = blockIdx.x;
  for (int k = threadIdx.x; k < K; k += blockDim.x) row[k] = g[(size_t)gi * K + k];
  __syncthreads();
  int c = threadIdx.x;
  if (c >= N) return;
  float s = b[c];
  for (int k = 0; k < K; ++k) s += row[k] * W[(size_t)k * N + c];
  if (do_relu) s = fmaxf(s, 0.f);
  out[(size_t)gi * N + c] = s;
}

extern "C" void kernel_launch(void* const* d_in, const int* in_sizes, int n_in,
                              void* d_out, int out_size, void* d_ws, size_t ws_size,
                              hipStream_t stream) {
  const float* x     = (const float*)d_in[0];
  const int*   ei    = (const int*)d_in[1];
  const int*   batch = (const int*)d_in[2];
  const float* Wl[4], *bl[4], *Wr[4], *br[4], *att[4], *bias[4];
  for (int l = 0; l < 4; ++l) {
    Wl[l]   = (const float*)d_in[3 + l * 6 + 0];
    bl[l]   = (const float*)d_in[3 + l * 6 + 1];
    Wr[l]   = (const float*)d_in[3 + l * 6 + 2];
    br[l]   = (const float*)d_in[3 + l * 6 + 3];
    att[l]  = (const float*)d_in[3 + l * 6 + 4];
    bias[l] = (const float*)d_in[3 + l * 6 + 5];
  }
  const float* fc1_W = (const float*)d_in[27];
  const float* fc1_b = (const float*)d_in[28];
  const float* fc2_W = (const float*)d_in[29];
  const float* fc2_b = (const float*)d_in[30];

  char* wsb = (char*)d_ws;
  size_t off = 0;
  auto alloc = [&](size_t bytes) {
    void* p = (void*)(wsb + off);
    off += (bytes + 63) & ~(size_t)63;
    return p;
  };
  // fp16 xl/xr: stride 304 (layer 3), stride 128 (layers 0-2); +128B over-read pad
  _Float16* xlh = (_Float16*)alloc((size_t)N_NODES * XSTRIDE * 2 + 128);
  _Float16* xrh = (_Float16*)alloc((size_t)N_NODES * XSTRIDE * 2 + 128);
  _Float16* A0  = (_Float16*)alloc((size_t)NPANEL * 40 * 512 * 2);  // 32 MB
  _Float16* Hp  = (_Float16*)alloc((size_t)NPANEL * 16 * 512 * 2);  // 12.8 MB
  _Float16* hbuf = (_Float16*)alloc((size_t)N_NODES * HSTRIDE * 2); // 30.4 MB
  float* gpool  = (float*)alloc((size_t)N_GRAPHS * 300 * 4);
  float* g1     = (float*)alloc((size_t)N_GRAPHS * 300 * 4);
  f16x2* att_h  = (f16x2*)alloc((size_t)4 * 192 * 4);
  _Float16* Wbuf = (_Float16*)alloc((size_t)88 * WCOLS * 8 * 2);    // 1.1 MB
  const int Cdim[4] = {128, 128, 128, 300};
  const int NLv[4]  = {128, 128, 128, 304};
  const int Kpv[4]  = {320, 128, 128, 128};
  const int CSg[4]  = {128, 128, 128, XSTRIDE};
  const int Wbase[4] = {0, 40, 56, 72};   // kc offsets in Wbuf
  int* deg     = (int*)alloc((size_t)N_NODES * 4);
  int* rowptr  = (int*)alloc((size_t)(N_NODES + 1) * 4);
  int* bsum    = (int*)alloc(256 * 4);
  int* cursor  = (int*)alloc((size_t)N_NODES * 4);
  int* csr_src = (int*)alloc((size_t)E_TOT * 4);

  // one-time conversions
  conv_x<<<(NPANEL * 64 * 40 + 255) / 256, 256, 0, stream>>>(x, A0);
  conv_w_all<<<(88 * WCOLS + 255) / 256, 256, 0, stream>>>(
      Wl[0], Wr[0], Wl[1], Wr[1], Wl[2], Wr[2], Wl[3], Wr[3], Wbuf);
  conv_att<<<3, 256, 0, stream>>>(att[0], att[1], att[2], att[3], att_h);
  zero_pad_H<<<3, 256, 0, stream>>>(Hp);

  // CSR build
  zero_ints<<<(N_NODES + 255) / 256, 256, 0, stream>>>(deg, N_NODES);
  deg_count<<<(E_TOT + 255) / 256, 256, 0, stream>>>(ei, deg);
  scan1<<<NB_SCAN, 256, 0, stream>>>(deg, rowptr, bsum);
  scan2<<<1, 256, 0, stream>>>(bsum);
  scan3<<<NB_SCAN, 256, 0, stream>>>(rowptr, bsum, cursor);
  fill_csr<<<(E_TOT + 255) / 256, 256, 0, stream>>>(ei, cursor, csr_src);
  // zero the pool accumulator early (fp32 zero == all-zero bits)
  zero_ints<<<(N_GRAPHS * 300 + 255) / 256, 256, 0, stream>>>((int*)gpool, N_GRAPHS * 300);

  const int nwave_blocks = (N_NODES + 3) / 4;
  for (int l = 0; l < 4; ++l) {
    const _Float16* Ain = (l == 0) ? A0 : Hp;
    const _Float16* Wp = Wbuf + (size_t)Wbase[l] * WCOLS * 8;
    int ny = (2 * NLv[l] + 255) / 256;
    dim3 gg(NPANEL, ny);
    gemm_dual<<<gg, 256, 0, stream>>>(Ain, Wp, bl[l], br[l],
                                      xlh, xrh, Kpv[l], Cdim[l], NLv[l], CSg[l]);
    if (l < 3) {
      gat128<<<nwave_blocks, 256, 0, stream>>>(
          rowptr, csr_src, xlh, xrh, att_h + l * 192, bias[l], Hp);
    } else {
      gat300<<<nwave_blocks, 256, 0, stream>>>(
          rowptr, csr_src, xlh, xrh, att_h + l * 192, bias[l], hbuf);
    }
  }
  {
    dim3 pg(N_GRAPHS, POOL_SPLIT);
    pool_sum<<<pg, 320, 0, stream>>>(hbuf, batch, gpool);
    pool_final<<<(N_GRAPHS * 300 + 255) / 256, 256, 0, stream>>>(gpool, batch);
  }
  fc_kernel<<<N_GRAPHS, 320, 0, stream>>>(gpool, fc1_W, fc1_b, g1, 300, 300, 1);
  fc_kernel<<<N_GRAPHS, 768, 0, stream>>>(g1, fc2_W, fc2_b, (float*)d_out, 300, 768, 0);
}

// Round 14
// 547.056 us; speedup vs baseline: 1.9407x; 1.0240x over previous
//
#include <hip/hip_runtime.h>
#include <hip/hip_bf16.h>
#include <math.h>

#define N_NODES 50000
#define N_EDGES 800000
#define E_TOT   (N_EDGES + N_NODES)
#define N_GRAPHS 256
#define SLOPE 0.2f
#define NB_SCAN ((N_NODES + 255) / 256)
#define NPANEL 782            // ceil(50000/64)
#define WCOLS 768             // padded concatenated-W width
#define POOL_SPLIT 8
#define HSTRIDE 304           // fp16 h row stride (608B, 16B-aligned)
#define XSTRIDE 320           // fp16 xl/xr row stride layer 3 (640B = 10 cache lines)

typedef __attribute__((ext_vector_type(4))) float f32x4;
typedef _Float16 f16x2 __attribute__((ext_vector_type(2)));
typedef _Float16 f16x4 __attribute__((ext_vector_type(4)));
typedef _Float16 f16x8 __attribute__((ext_vector_type(8)));

__device__ __forceinline__ void gl_lds16(const void* g, void* l) {
  __builtin_amdgcn_global_load_lds(
      (const __attribute__((address_space(1))) unsigned int*)g,
      (__attribute__((address_space(3))) unsigned int*)l, 16, 0, 0);
}

// ---- x -> panel-swizzled fp16 [p][kc=40][m=64][ki=8], zero-padded ----------
__global__ void conv_x(const float* __restrict__ x, _Float16* __restrict__ A) {
  int id = blockIdx.x * blockDim.x + threadIdx.x;
  const int total = NPANEL * 64 * 40;
  if (id >= total) return;
  int kc = id % 40;
  int m  = (id / 40) % 64;
  int p  = id / 2560;
  int n = p * 64 + m;
  f16x8 hv;
#pragma unroll
  for (int i = 0; i < 8; ++i) {
    int k = kc * 8 + i;
    float v = (n < N_NODES && k < 300) ? x[(size_t)n * 300 + k] : 0.f;
    hv[i] = (_Float16)v;
  }
  size_t ce = (((size_t)p * 40 + kc) * 64 + m) * 8;
  *(f16x8*)&A[ce] = hv;
}

// ---- all layers' Wl,Wr -> one contiguous fp16 buffer [gkc][WCOLS][8] -------
__global__ void conv_w_all(const float* __restrict__ W0l, const float* __restrict__ W0r,
                           const float* __restrict__ W1l, const float* __restrict__ W1r,
                           const float* __restrict__ W2l, const float* __restrict__ W2r,
                           const float* __restrict__ W3l, const float* __restrict__ W3r,
                           _Float16* __restrict__ W) {
  int id = blockIdx.x * blockDim.x + threadIdx.x;
  if (id >= 88 * WCOLS) return;
  int n = id % WCOLS, gkc = id / WCOLS;
  int l, kc;
  if (gkc < 40)      { l = 0; kc = gkc; }
  else if (gkc < 56) { l = 1; kc = gkc - 40; }
  else if (gkc < 72) { l = 2; kc = gkc - 56; }
  else               { l = 3; kc = gkc - 72; }
  const float* Wl = (l == 0) ? W0l : (l == 1) ? W1l : (l == 2) ? W2l : W3l;
  const float* Wr = (l == 0) ? W0r : (l == 1) ? W1r : (l == 2) ? W2r : W3r;
  int K = (l == 0) ? 300 : 128;
  int C = (l == 3) ? 300 : 128;
  int NL = (l == 3) ? 304 : 128;
  f16x8 hv;
#pragma unroll
  for (int i = 0; i < 8; ++i) {
    int k = kc * 8 + i;
    float v = 0.f;
    if (k < K) {
      if (n < NL) { if (n < C) v = Wl[(size_t)k * C + n]; }
      else if (n < 2 * NL && (n - NL) < C) v = Wr[(size_t)k * C + (n - NL)];
    }
    hv[i] = (_Float16)v;
  }
  *(f16x8*)&W[(size_t)id * 8] = hv;
}

// ---- init_aux: att fp32 -> f16x2 tables (4x192) + zero gpool ---------------
__global__ void init_aux(const float* __restrict__ a0, const float* __restrict__ a1,
                         const float* __restrict__ a2, const float* __restrict__ a3,
                         f16x2* __restrict__ att_h, float* __restrict__ gpool) {
  int t = blockIdx.x * blockDim.x + threadIdx.x;
  if (t < 4 * 192) {
    int l = t / 192, i = t % 192;
    const float* a = (l == 0) ? a0 : (l == 1) ? a1 : (l == 2) ? a2 : a3;
    int C = (l == 3) ? 300 : 128;
    int c = 2 * i;
    f16x2 r;
    r[0] = (c < C) ? (_Float16)a[c] : (_Float16)0.f;
    r[1] = (c + 1 < C) ? (_Float16)a[c + 1] : (_Float16)0.f;
    att_h[t] = r;
  }
  int u = t - 768;
  if (u >= 0 && u < N_GRAPHS * 300) gpool[u] = 0.f;
}

// ---- dual-output fp16 MFMA GEMM: [xl|xr] = A @ [Wl|Wr] + bias --------------
// NOTE: A-panel pad rows (nodes >= 50000) may hold garbage; MFMA rows map 1:1
// to output rows, which are guarded by row < N_NODES. Finite garbage is safe.
__global__ __launch_bounds__(256, 2) void gemm_dual(
    const _Float16* __restrict__ A, const _Float16* __restrict__ W,
    const float* __restrict__ biasl, const float* __restrict__ biasr,
    _Float16* __restrict__ xlh, _Float16* __restrict__ xrh,
    int Kp, int C, int NL, int CSg) {
  __shared__ _Float16 As[4][64][8];     // 4 KB
  __shared__ _Float16 Ws[4][256][8];    // 16 KB
  const int tid = threadIdx.x, wv = tid >> 6, lane = tid & 63;
  const int p = blockIdx.x, n0 = blockIdx.y * 256;
  const int kcn = Kp >> 3, nk = Kp >> 5;
  const size_t abase0 = (size_t)p * kcn * 512;
  const int rsel = lane >> 4, rrow = lane & 15;
  f32x4 z4 = {0.f, 0.f, 0.f, 0.f};
  f32x4 acc[4][4];
#pragma unroll
  for (int a = 0; a < 4; ++a)
#pragma unroll
    for (int b = 0; b < 4; ++b) acc[a][b] = z4;

  for (int s = 0; s < nk; ++s) {
    const size_t abase = abase0 + (size_t)s * 2048;
    for (int q = wv; q < 20; q += 4) {
      const _Float16* g;
      _Float16* l;
      if (q < 4) {
        g = A + abase + q * 512;
        l = &As[0][0][0] + q * 512;
      } else {
        int j = q - 4;                 // 0..15: row j>>2, col-block j&3
        g = W + ((size_t)(s * 4 + (j >> 2)) * WCOLS + n0 + (j & 3) * 64) * 8;
        l = &Ws[0][0][0] + j * 512;
      }
      gl_lds16(g + lane * 8, l);
    }
    __syncthreads();
    f16x8 af[4], bf[4];
#pragma unroll
    for (int mt = 0; mt < 4; ++mt)
      af[mt] = *(const f16x8*)&As[rsel][mt * 16 + rrow][0];
#pragma unroll
    for (int nt = 0; nt < 4; ++nt)
      bf[nt] = *(const f16x8*)&Ws[rsel][wv * 64 + nt * 16 + rrow][0];
#pragma unroll
    for (int mt = 0; mt < 4; ++mt)
#pragma unroll
      for (int nt = 0; nt < 4; ++nt)
        acc[mt][nt] = __builtin_amdgcn_mfma_f32_16x16x32_f16(af[mt], bf[nt], acc[mt][nt], 0, 0, 0);
    __syncthreads();
  }
#pragma unroll
  for (int mt = 0; mt < 4; ++mt) {
    int r0 = p * 64 + mt * 16 + rsel * 4;
#pragma unroll
    for (int nt = 0; nt < 4; ++nt) {
      int gc = n0 + wv * 64 + nt * 16 + rrow;
#pragma unroll
      for (int j = 0; j < 4; ++j) {
        int row = r0 + j;
        if (row >= N_NODES) continue;
        float v = acc[mt][nt][j];
        if (gc < NL) {
          if (gc < C) xlh[(size_t)row * CSg + gc] = (_Float16)(v + biasl[gc]);
        } else {
          int c2 = gc - NL;
          if (c2 >= 0 && c2 < C) xrh[(size_t)row * CSg + c2] = (_Float16)(v + biasr[c2]);
        }
      }
    }
  }
}

// ---------------- CSR build (once per launch) ---------------------------
__global__ void zero_ints(int* __restrict__ p, int n) {
  int i = blockIdx.x * blockDim.x + threadIdx.x;
  if (i < n) p[i] = 0;
}

__global__ void deg_count(const int* __restrict__ ei, int* __restrict__ deg) {
  int e = blockIdx.x * blockDim.x + threadIdx.x;
  if (e >= E_TOT) return;
  int d = (e < N_EDGES) ? ei[N_EDGES + e] : e - N_EDGES;
  atomicAdd(&deg[d], 1);
}

__global__ void scan1(const int* __restrict__ deg, int* __restrict__ rp,
                      int* __restrict__ bsum) {
  __shared__ int s[256];
  int i = blockIdx.x * 256 + threadIdx.x;
  int v = (i < N_NODES) ? deg[i] : 0;
  s[threadIdx.x] = v;
  __syncthreads();
  for (int off = 1; off < 256; off <<= 1) {
    int t = (threadIdx.x >= off) ? s[threadIdx.x - off] : 0;
    __syncthreads();
    s[threadIdx.x] += t;
    __syncthreads();
  }
  if (i < N_NODES) rp[i] = s[threadIdx.x] - v;
  if (threadIdx.x == 255) bsum[blockIdx.x] = s[255];
}

__global__ void scan2(int* __restrict__ bsum) {
  __shared__ int s[256];
  int v = (threadIdx.x < NB_SCAN) ? bsum[threadIdx.x] : 0;
  s[threadIdx.x] = v;
  __syncthreads();
  for (int off = 1; off < 256; off <<= 1) {
    int t = (threadIdx.x >= off) ? s[threadIdx.x - off] : 0;
    __syncthreads();
    s[threadIdx.x] += t;
    __syncthreads();
  }
  if (threadIdx.x < NB_SCAN) bsum[threadIdx.x] = s[threadIdx.x] - v;
}

__global__ void scan3(int* __restrict__ rp, const int* __restrict__ bsum,
                      int* __restrict__ cursor) {
  int i = blockIdx.x * 256 + threadIdx.x;
  if (i < N_NODES) {
    int v = rp[i] + bsum[blockIdx.x];
    rp[i] = v;
    cursor[i] = v;
  }
  if (i == 0) rp[N_NODES] = E_TOT;
}

__global__ void fill_csr(const int* __restrict__ ei, int* __restrict__ cursor,
                         int* __restrict__ csr_src) {
  int e = blockIdx.x * blockDim.x + threadIdx.x;
  if (e >= E_TOT) return;
  int s, d;
  if (e < N_EDGES) { s = ei[e]; d = ei[N_EDGES + e]; }
  else             { s = d = e - N_EDGES; }
  int pos = atomicAdd(&cursor[d], 1);
  csr_src[pos] = s;
}

// ---- row loader (C=128): one f16x8 per lane -------------------------------
__device__ __forceinline__ void load_row128(f16x2* dst, const _Float16* p) {
  f16x8 t = *(const f16x8*)p;
#pragma unroll
  for (int j = 0; j < 4; ++j) {
    f16x2 r; r[0] = t[2 * j]; r[1] = t[2 * j + 1]; dst[j] = r;
  }
}

// ---- row loader (C=300, chunked map): 16B+16B+8B per lane ------------------
// lane li covers channels [8li,8li+8) u [128+8li,+8) u [256+4li,+4)
// Channels 300..319 (lanes li>=11) hold stale finite values; att=0 there and
// those acc slots are never stored, so they contribute exactly zero.
__device__ __forceinline__ void load_row300(f16x2* dst, const _Float16* row, int li) {
  f16x8 a = *(const f16x8*)(row + 8 * li);
  f16x8 b = *(const f16x8*)(row + 128 + 8 * li);
  f16x4 c = *(const f16x4*)(row + 256 + 4 * li);
#pragma unroll
  for (int j = 0; j < 4; ++j) {
    f16x2 r; r[0] = a[2 * j]; r[1] = a[2 * j + 1]; dst[j] = r;
  }
#pragma unroll
  for (int j = 0; j < 4; ++j) {
    f16x2 r; r[0] = b[2 * j]; r[1] = b[2 * j + 1]; dst[4 + j] = r;
  }
  {
    f16x2 r; r[0] = c[0]; r[1] = c[1]; dst[8] = r;
    f16x2 r2; r2[0] = c[2]; r2[1] = c[3]; dst[9] = r2;
  }
}

// -------- fused GATv2 aggregation (C=128): 16 lanes/edge, 4 edges in flight,
// depth-2 row pipeline, deferred-max softmax, fp16 H-panel output ------------
__global__ __launch_bounds__(256) void gat128(
    const int* __restrict__ rowptr, const int* __restrict__ csr_src,
    const _Float16* __restrict__ xlh, const _Float16* __restrict__ xrh,
    const f16x2* __restrict__ att_h, const float* __restrict__ bias,
    _Float16* __restrict__ Hp) {
  int wid = (int)((blockIdx.x * (size_t)blockDim.x + threadIdx.x) >> 6);
  int lane = threadIdx.x & 63;
  if (wid >= N_NODES) return;
  const int g = lane >> 4, li = lane & 15;
  const int c0 = li * 8;
  int beg = rowptr[wid], end = rowptr[wid + 1];

  f16x2 xri[4], attc[4];
  load_row128(xri, xrh + (size_t)wid * 128 + c0);
#pragma unroll
  for (int j = 0; j < 4; ++j) attc[j] = att_h[(c0 >> 1) + j];

  float acc[8];
#pragma unroll
  for (int k = 0; k < 8; ++k) acc[k] = 0.f;
  float dsum = 0.f;
  const f16x2 slope2 = {(_Float16)SLOPE, (_Float16)SLOPE};

  int e = beg + g;
  f16x2 bufA[4], bufB[4];
  {
    int e0 = e < end ? e : end - 1;
    load_row128(bufA, xlh + (size_t)csr_src[e0] * 128 + c0);
  }
  {
    int e1 = e + 4 < end ? e + 4 : end - 1;
    load_row128(bufB, xlh + (size_t)csr_src[e1] * 128 + c0);
  }
  int nit = (end - beg + 3) >> 2;

  auto step = [&](f16x2* cur) {
    bool valid = e < end;
    float v = 0.f;
#pragma unroll
    for (int j = 0; j < 4; ++j) {
      f16x2 m2 = cur[j] + xri[j];
      f16x2 lr = __builtin_elementwise_max(m2, slope2 * m2);  // leaky (slope<1)
#if __has_builtin(__builtin_amdgcn_fdot2)
      v = __builtin_amdgcn_fdot2(lr, attc[j], v, false);
#else
      v += (float)lr[0] * (float)attc[j][0] + (float)lr[1] * (float)attc[j][1];
#endif
    }
    v += __shfl_xor(v, 1);
    v += __shfl_xor(v, 2);
    v += __shfl_xor(v, 4);
    v += __shfl_xor(v, 8);
    float w = valid ? __expf(v) : 0.f;     // deferred max: |v| small, fp32-safe
    dsum += w;
#pragma unroll
    for (int j = 0; j < 4; ++j) {
      acc[2 * j]     += w * (float)cur[j][0];
      acc[2 * j + 1] += w * (float)cur[j][1];
    }
    if (e - g + 8 < end) {                 // wave-uniform prefetch condition
      int en = e + 8; if (en > end - 1) en = end - 1;
      load_row128(cur, xlh + (size_t)csr_src[en] * 128 + c0);
    }
    e += 4;
  };
  for (int it = 0; it < nit; it += 2) {
    step(bufA);
    if (it + 1 < nit) step(bufB);
  }

#pragma unroll
  for (int k = 0; k < 8; ++k) {
    acc[k] += __shfl_xor(acc[k], 16);
    acc[k] += __shfl_xor(acc[k], 32);
  }
  dsum += __shfl_xor(dsum, 16);
  dsum += __shfl_xor(dsum, 32);
  if (g != 0) return;
  float inv = 1.f / dsum;
  f16x8 hv;
#pragma unroll
  for (int k = 0; k < 8; ++k) {
    float vv = fmaxf(acc[k] * inv + bias[c0 + k], 0.f);
    hv[k] = (_Float16)vv;
  }
  int p = wid >> 6, mrow = wid & 63;
  size_t ce = (((size_t)p * 16 + li) * 64 + mrow) * 8;
  *(f16x8*)&Hp[ce] = hv;
}

// -------- fused GATv2 aggregation (C=300): chunked channel map, wide loads,
// depth-1 prefetch (R10-proven), fp16 h output (stride HSTRIDE) --------------
__global__ __launch_bounds__(256) void gat300(
    const int* __restrict__ rowptr, const int* __restrict__ csr_src,
    const _Float16* __restrict__ xlh, const _Float16* __restrict__ xrh,
    const f16x2* __restrict__ att_h, const float* __restrict__ bias,
    _Float16* __restrict__ hout) {
  int wid = (int)((blockIdx.x * (size_t)blockDim.x + threadIdx.x) >> 6);
  int lane = threadIdx.x & 63;
  if (wid >= N_NODES) return;
  const int g = lane >> 4, li = lane & 15;
  int beg = rowptr[wid], end = rowptr[wid + 1];

  f16x2 xri[10], attc[10];
  load_row300(xri, xrh + (size_t)wid * XSTRIDE, li);
#pragma unroll
  for (int j = 0; j < 4; ++j) attc[j] = att_h[4 * li + j];
#pragma unroll
  for (int j = 0; j < 4; ++j) attc[4 + j] = att_h[64 + 4 * li + j];
  attc[8] = att_h[128 + 2 * li];
  attc[9] = att_h[128 + 2 * li + 1];

  float acc[20];
#pragma unroll
  for (int k = 0; k < 20; ++k) acc[k] = 0.f;
  float dsum = 0.f;
  const f16x2 slope2 = {(_Float16)SLOPE, (_Float16)SLOPE};

  int e = beg + g;
  f16x2 nxt[10];
  {
    int s = csr_src[e < end ? e : end - 1];
    load_row300(nxt, xlh + (size_t)s * XSTRIDE, li);
  }
  int nit = (end - beg + 3) >> 2;
  for (int it = 0; it < nit; ++it) {
    f16x2 cur[10];
#pragma unroll
    for (int j = 0; j < 10; ++j) cur[j] = nxt[j];
    bool valid = e < end;
    if (beg + (it + 1) * 4 < end) {        // wave-uniform
      int en = e + 4;
      int s = csr_src[en < end ? en : end - 1];
      load_row300(nxt, xlh + (size_t)s * XSTRIDE, li);
    }
    float v = 0.f;
#pragma unroll
    for (int j = 0; j < 10; ++j) {
      f16x2 m2 = cur[j] + xri[j];
      f16x2 lr = __builtin_elementwise_max(m2, slope2 * m2);  // leaky (slope<1)
#if __has_builtin(__builtin_amdgcn_fdot2)
      v = __builtin_amdgcn_fdot2(lr, attc[j], v, false);
#else
      v += (float)lr[0] * (float)attc[j][0] + (float)lr[1] * (float)attc[j][1];
#endif
    }
    v += __shfl_xor(v, 1);
    v += __shfl_xor(v, 2);
    v += __shfl_xor(v, 4);
    v += __shfl_xor(v, 8);
    float w = valid ? __expf(v) : 0.f;
    dsum += w;
#pragma unroll
    for (int j = 0; j < 10; ++j) {
      acc[2 * j]     += w * (float)cur[j][0];
      acc[2 * j + 1] += w * (float)cur[j][1];
    }
    e += 4;
  }
#pragma unroll
  for (int k = 0; k < 20; ++k) {
    acc[k] += __shfl_xor(acc[k], 16);
    acc[k] += __shfl_xor(acc[k], 32);
  }
  dsum += __shfl_xor(dsum, 16);
  dsum += __shfl_xor(dsum, 32);
  if (g != 0) return;
  float inv = 1.f / dsum;
  // mapped channels: k<8 -> 8li+k; k<16 -> 128+8li+(k-8); else 256+4li+(k-16)
  f16x8 h1, h2;
  f16x4 h3;
#pragma unroll
  for (int k = 0; k < 8; ++k)
    h1[k] = (_Float16)fmaxf(acc[k] * inv + bias[8 * li + k], 0.f);
#pragma unroll
  for (int k = 0; k < 8; ++k)
    h2[k] = (_Float16)fmaxf(acc[8 + k] * inv + bias[128 + 8 * li + k], 0.f);
  if (li <= 10) {
#pragma unroll
    for (int k = 0; k < 4; ++k)
      h3[k] = (_Float16)fmaxf(acc[16 + k] * inv + bias[256 + 4 * li + k], 0.f);
  }
  _Float16* hr = hout + (size_t)wid * HSTRIDE;
  *(f16x8*)(hr + 8 * li) = h1;
  *(f16x8*)(hr + 128 + 8 * li) = h2;
  if (li <= 10) *(f16x4*)(hr + 256 + 4 * li) = h3;   // ch 300+ skipped
}

// ------------- global mean pool (batch sorted), split + unrolled --------
__device__ int lower_bound_dev(const int* a, int n, int v) {
  int lo = 0, hi = n;
  while (lo < hi) { int mid = (lo + hi) >> 1; if (a[mid] < v) lo = mid + 1; else hi = mid; }
  return lo;
}

__global__ void pool_sum(const _Float16* __restrict__ h, const int* __restrict__ batch,
                         float* __restrict__ gsum) {
  int gi = blockIdx.x;
  int sp = blockIdx.y;
  int c = threadIdx.x;
  if (c >= 300) return;
  int start = lower_bound_dev(batch, N_NODES, gi);
  int end   = lower_bound_dev(batch, N_NODES, gi + 1);
  int len = end - start;
  int chunk = (len + POOL_SPLIT - 1) / POOL_SPLIT;
  int a = start + sp * chunk;
  int b = a + chunk; if (b > end) b = end;
  if (a >= b) return;
  float s0 = 0.f, s1 = 0.f, s2 = 0.f, s3 = 0.f;
  int n = a;
  for (; n + 3 < b; n += 4) {
    s0 += (float)h[(size_t)n * HSTRIDE + c];
    s1 += (float)h[(size_t)(n + 1) * HSTRIDE + c];
    s2 += (float)h[(size_t)(n + 2) * HSTRIDE + c];
    s3 += (float)h[(size_t)(n + 3) * HSTRIDE + c];
  }
  for (; n < b; ++n) s0 += (float)h[(size_t)n * HSTRIDE + c];
  atomicAdd(&gsum[(size_t)gi * 300 + c], (s0 + s1) + (s2 + s3));
}

// ------------- small per-graph FC (optionally divides input row by count) ---
__global__ void fc_kernel(const float* __restrict__ g, const float* __restrict__ W,
                          const float* __restrict__ b, float* __restrict__ out,
                          const int* __restrict__ batch,
                          int K, int N, int do_relu, int do_div) {
  __shared__ float row[304];
  int gi = blockIdx.x;
  float scale = 1.f;
  if (do_div) {
    int start = lower_bound_dev(batch, N_NODES, gi);
    int end   = lower_bound_dev(batch, N_NODES, gi + 1);
    int cnt = end - start;
    scale = 1.f / (float)(cnt > 0 ? cnt : 1);
  }
  for (int k = threadIdx.x; k < K; k += blockDim.x) row[k] = g[(size_t)gi * K + k] * scale;
  __syncthreads();
  int c = threadIdx.x;
  if (c >= N) return;
  float s = b[c];
  for (int k = 0; k < K; ++k) s += row[k] * W[(size_t)k * N + c];
  if (do_relu) s = fmaxf(s, 0.f);
  out[(size_t)gi * N + c] = s;
}

extern "C" void kernel_launch(void* const* d_in, const int* in_sizes, int n_in,
                              void* d_out, int out_size, void* d_ws, size_t ws_size,
                              hipStream_t stream) {
  const float* x     = (const float*)d_in[0];
  const int*   ei    = (const int*)d_in[1];
  const int*   batch = (const int*)d_in[2];
  const float* Wl[4], *bl[4], *Wr[4], *br[4], *att[4], *bias[4];
  for (int l = 0; l < 4; ++l) {
    Wl[l]   = (const float*)d_in[3 + l * 6 + 0];
    bl[l]   = (const float*)d_in[3 + l * 6 + 1];
    Wr[l]   = (const float*)d_in[3 + l * 6 + 2];
    br[l]   = (const float*)d_in[3 + l * 6 + 3];
    att[l]  = (const float*)d_in[3 + l * 6 + 4];
    bias[l] = (const float*)d_in[3 + l * 6 + 5];
  }
  const float* fc1_W = (const float*)d_in[27];
  const float* fc1_b = (const float*)d_in[28];
  const float* fc2_W = (const float*)d_in[29];
  const float* fc2_b = (const float*)d_in[30];

  char* wsb = (char*)d_ws;
  size_t off = 0;
  auto alloc = [&](size_t bytes) {
    void* p = (void*)(wsb + off);
    off += (bytes + 63) & ~(size_t)63;
    return p;
  };
  // fp16 xl/xr: stride 320 (layer 3), stride 128 (layers 0-2); +128B over-read pad
  _Float16* xlh = (_Float16*)alloc((size_t)N_NODES * XSTRIDE * 2 + 128);
  _Float16* xrh = (_Float16*)alloc((size_t)N_NODES * XSTRIDE * 2 + 128);
  _Float16* A0  = (_Float16*)alloc((size_t)NPANEL * 40 * 512 * 2);  // 32 MB
  _Float16* Hp  = (_Float16*)alloc((size_t)NPANEL * 16 * 512 * 2);  // 12.8 MB
  _Float16* hbuf = (_Float16*)alloc((size_t)N_NODES * HSTRIDE * 2); // 30.4 MB
  float* gpool  = (float*)alloc((size_t)N_GRAPHS * 300 * 4);
  float* g1     = (float*)alloc((size_t)N_GRAPHS * 300 * 4);
  f16x2* att_h  = (f16x2*)alloc((size_t)4 * 192 * 4);
  _Float16* Wbuf = (_Float16*)alloc((size_t)88 * WCOLS * 8 * 2);    // 1.1 MB
  const int Cdim[4] = {128, 128, 128, 300};
  const int NLv[4]  = {128, 128, 128, 304};
  const int Kpv[4]  = {320, 128, 128, 128};
  const int CSg[4]  = {128, 128, 128, XSTRIDE};
  const int Wbase[4] = {0, 40, 56, 72};   // kc offsets in Wbuf
  int* deg     = (int*)alloc((size_t)N_NODES * 4);
  int* rowptr  = (int*)alloc((size_t)(N_NODES + 1) * 4);
  int* bsum    = (int*)alloc(256 * 4);
  int* cursor  = (int*)alloc((size_t)N_NODES * 4);
  int* csr_src = (int*)alloc((size_t)E_TOT * 4);

  // one-time conversions + aux init (att tables + gpool zero)
  conv_x<<<(NPANEL * 64 * 40 + 255) / 256, 256, 0, stream>>>(x, A0);
  conv_w_all<<<(88 * WCOLS + 255) / 256, 256, 0, stream>>>(
      Wl[0], Wr[0], Wl[1], Wr[1], Wl[2], Wr[2], Wl[3], Wr[3], Wbuf);
  init_aux<<<(768 + N_GRAPHS * 300 + 255) / 256, 256, 0, stream>>>(
      att[0], att[1], att[2], att[3], att_h, gpool);

  // CSR build
  zero_ints<<<(N_NODES + 255) / 256, 256, 0, stream>>>(deg, N_NODES);
  deg_count<<<(E_TOT + 255) / 256, 256, 0, stream>>>(ei, deg);
  scan1<<<NB_SCAN, 256, 0, stream>>>(deg, rowptr, bsum);
  scan2<<<1, 256, 0, stream>>>(bsum);
  scan3<<<NB_SCAN, 256, 0, stream>>>(rowptr, bsum, cursor);
  fill_csr<<<(E_TOT + 255) / 256, 256, 0, stream>>>(ei, cursor, csr_src);

  const int nwave_blocks = (N_NODES + 3) / 4;
  for (int l = 0; l < 4; ++l) {
    const _Float16* Ain = (l == 0) ? A0 : Hp;
    const _Float16* Wp = Wbuf + (size_t)Wbase[l] * WCOLS * 8;
    int ny = (2 * NLv[l] + 255) / 256;
    dim3 gg(NPANEL, ny);
    gemm_dual<<<gg, 256, 0, stream>>>(Ain, Wp, bl[l], br[l],
                                      xlh, xrh, Kpv[l], Cdim[l], NLv[l], CSg[l]);
    if (l < 3) {
      gat128<<<nwave_blocks, 256, 0, stream>>>(
          rowptr, csr_src, xlh, xrh, att_h + l * 192, bias[l], Hp);
    } else {
      gat300<<<nwave_blocks, 256, 0, stream>>>(
          rowptr, csr_src, xlh, xrh, att_h + l * 192, bias[l], hbuf);
    }
  }
  {
    dim3 pg(N_GRAPHS, POOL_SPLIT);
    pool_sum<<<pg, 320, 0, stream>>>(hbuf, batch, gpool);
  }
  fc_kernel<<<N_GRAPHS, 320, 0, stream>>>(gpool, fc1_W, fc1_b, g1, batch, 300, 300, 1, 1);
  fc_kernel<<<N_GRAPHS, 768, 0, stream>>>(g1, fc2_W, fc2_b, (float*)d_out, batch, 300, 768, 0, 0);
}